// Round 8
// baseline (679.389 us; speedup 1.0000x reference)
//
#include <hip/hip_runtime.h>
#include <math.h>

#define N_NODES 4096
#define N_EDGES 131072
#define DIM     256
#define NL      4
#define NENC    2
#define FFD     512
#define NG      128
#define NHEAD   8
#define DKH     32
#define TE2     32

typedef __attribute__((ext_vector_type(8))) short bf16x8;
typedef __attribute__((ext_vector_type(4))) float f32x4;

__device__ __forceinline__ float siluf(float x) { return x / (1.f + __expf(-x)); }
__device__ __forceinline__ float sigmf_(float x) { return 1.f / (1.f + __expf(-x)); }
__device__ __forceinline__ unsigned short f2b(float f) {
    union { float f; unsigned u; } x; x.f = f;
    unsigned r = x.u + 0x7fffu + ((x.u >> 16) & 1u);
    return (unsigned short)(r >> 16);
}
__device__ __forceinline__ float b2f(unsigned short h) {
    union { unsigned u; float f; } x; x.u = (unsigned)h << 16; return x.f;
}
__device__ __forceinline__ unsigned cvtpk(float lo, float hi) {
    unsigned r;
    asm("v_cvt_pk_bf16_f32 %0, %1, %2" : "=v"(r) : "v"(lo), "v"(hi));
    return r;
}

// ---------------- embedding ----------------
__global__ __launch_bounds__(256) void k_embed(const int* __restrict__ z,
                                               const float* __restrict__ emb,
                                               float* __restrict__ h) {
    int i = blockIdx.x * 256 + threadIdx.x;
    int n = i >> 8, d = i & 255;
    h[i] = emb[z[n] * DIM + d];
}

// ---------------- radial ----------------
__global__ __launch_bounds__(256) void k_radial(const float* __restrict__ pos,
                                                const int* __restrict__ ei,
                                                float* __restrict__ radial) {
    int e = blockIdx.x * 256 + threadIdx.x;
    if (e >= N_EDGES) return;
    int r = ei[e], c = ei[N_EDGES + e];
    float dx = pos[r*3+0] - pos[c*3+0];
    float dy = pos[r*3+1] - pos[c*3+1];
    float dz = pos[r*3+2] - pos[c*3+2];
    radial[e] = dx*dx + dy*dy + dz*dz;
}

// ---------------- edge counting sort (by row node) ----------------
__global__ __launch_bounds__(256) void k_hist(const int* __restrict__ ei, int* __restrict__ cnt) {
    int e = blockIdx.x * 256 + threadIdx.x;
    if (e < N_EDGES) atomicAdd(&cnt[ei[e]], 1);
}

__global__ __launch_bounds__(256) void k_scan(const int* __restrict__ cnt, int* __restrict__ pos) {
    __shared__ int s_w[4];
    int t = threadIdx.x, lane = t & 63, wv = t >> 6;
    int loc[16]; int s = 0;
    #pragma unroll
    for (int i = 0; i < 16; ++i) { loc[i] = s; s += cnt[t * 16 + i]; }
    int inc = s;
    #pragma unroll
    for (int off = 1; off < 64; off <<= 1) {
        int v = __shfl_up(inc, off, 64);
        if (lane >= off) inc += v;
    }
    if (lane == 63) s_w[wv] = inc;
    __syncthreads();
    int wbase = 0;
    for (int j = 0; j < wv; ++j) wbase += s_w[j];
    int base = wbase + inc - s;
    #pragma unroll
    for (int i = 0; i < 16; ++i) pos[t * 16 + i] = base + loc[i];
}

__global__ __launch_bounds__(256) void k_scatter(const int* __restrict__ ei,
                                                 const float* __restrict__ radial,
                                                 int* __restrict__ pos,
                                                 int* __restrict__ rows_s,
                                                 int* __restrict__ cols_s,
                                                 float* __restrict__ rad_s) {
    int e = blockIdx.x * 256 + threadIdx.x;
    if (e >= N_EDGES) return;
    int r = ei[e];
    int p = atomicAdd(&pos[r], 1);
    rows_s[p] = r;
    cols_s[p] = ei[N_EDGES + e];
    rad_s[p] = radial[e];
}

// ---------------- W2 -> bf16 MFMA-fragment-linear pack (edge GEMM2) ----------------
__global__ __launch_bounds__(256) void k_conv_w2(const float* __restrict__ ew2,
                                                 unsigned short* __restrict__ W2F) {
    int tid = blockIdx.x * 256 + threadIdx.x;
    int layer = tid >> 13;
    int r = tid & 8191;
    int ks = r >> 10, ntg = (r >> 6) & 15, lane = r & 63;
    const float* W = ew2 + (size_t)layer * 65536;
    unsigned short tmp[8];
    #pragma unroll
    for (int j = 0; j < 8; ++j) {
        int k = ks*32 + 4*(lane>>4) + (j&3) + 16*(j>>2);
        int n = ntg*16 + (lane&15);
        tmp[j] = f2b(W[k*256 + n]);
    }
    *(bf16x8*)&W2F[(size_t)layer*65536 + (size_t)r*8] = *(const bf16x8*)&tmp[0];
}

// ---------------- batched pack of ALL dense weights -> fragment-linear bf16 ----------------
__global__ __launch_bounds__(256) void k_pack_all(
    const float* __restrict__ ew1, const float* __restrict__ nw1, const float* __restrict__ nw2,
    const float* __restrict__ wq, const float* __restrict__ wk, const float* __restrict__ wv,
    const float* __restrict__ wo, const float* __restrict__ fw1, const float* __restrict__ fw2,
    unsigned short* __restrict__ dst)
{
    int f = blockIdx.x * 256 + threadIdx.x;
    int rem, panel, NTG, mode;
    if (f < 65536)       { rem = f;          panel = rem / 16384; rem &= 16383; NTG = 32; mode = 0; }
    else if (f < 131072) { rem = f - 65536;  panel = rem / 16384; rem &= 16383; NTG = 16; mode = 1; }
    else if (f < 163840) { rem = f - 131072; panel = rem / 8192;  rem &= 8191;  NTG = 16; mode = 2; }
    else if (f < 212992) { rem = f - 163840; panel = rem / 24576; rem %= 24576; NTG = 48; mode = 3; }
    else if (f < 229376) { rem = f - 212992; panel = rem / 8192;  rem &= 8191;  NTG = 16; mode = 4; }
    else if (f < 262144) { rem = f - 229376; panel = rem / 16384; rem &= 16383; NTG = 32; mode = 5; }
    else                 { rem = f - 262144; panel = rem / 16384; rem &= 16383; NTG = 16; mode = 6; }
    int ks   = rem / (NTG * 64);
    int ntg  = (rem >> 6) % NTG;
    int lane = rem & 63;
    unsigned short tmp[8];
    #pragma unroll
    for (int j = 0; j < 8; ++j) {
        int k = ks*32 + 4*(lane>>4) + (j&3) + 16*(j>>2);
        int n = ntg*16 + (lane&15);
        float val;
        switch (mode) {
            case 0: val = ew1[(size_t)panel*131328 + (n < 256 ? k*256 + n : (256 + k)*256 + (n - 256))]; break;
            case 1: val = nw1[(size_t)panel*131072 + k*256 + n]; break;
            case 2: val = nw2[(size_t)panel*65536 + k*256 + n]; break;
            case 3: { const float* b = (n < 256) ? wq : ((n < 512) ? wk : wv);
                      val = b[(size_t)panel*65536 + k*256 + (n & 255)]; } break;
            case 4: val = wo[(size_t)panel*65536 + k*256 + n]; break;
            case 5: val = fw1[(size_t)panel*131072 + k*512 + n]; break;
            default: val = fw2[(size_t)panel*131072 + k*256 + n]; break;
        }
        tmp[j] = f2b(val);
    }
    *(bf16x8*)&dst[(size_t)f * 8] = *(const bf16x8*)&tmp[0];
}

// ---------------- generic split-bf16 MFMA GEMM ----------------
// OUTMODE 0: fp32 C. OUTMODE 1 (QKV): q fp32 | kpk frag hi/lo | vpk frag V^T.
// OUTMODE 2: bf16 C (for P12).
template<int NCHUNK, int NC, int NSPLIT, int ACT, int RESID, int OUTMODE>
__global__ __launch_bounds__(256) void k_gemm(
    const float* __restrict__ A0, const float* __restrict__ A1, int lda,
    const unsigned short* __restrict__ Wp,
    const float* __restrict__ b0, const float* __restrict__ b1, const float* __restrict__ b2,
    const float* __restrict__ resid, float* __restrict__ C,
    unsigned short* __restrict__ kpk, unsigned short* __restrict__ vpk)
{
    constexpr int NT  = NC / (64 * NSPLIT);
    constexpr int NTG = NC / 16;
    __shared__ __align__(16) char s_hi[16 * 512];
    __shared__ __align__(16) char s_lo[16 * 512];
    const int t = threadIdx.x, l = t & 63, w = t >> 6;
    const int g = l >> 4, r = l & 15;
    const int mtile  = blockIdx.x % 256;
    const int nchunk = blockIdx.x / 256;
    const int r0 = mtile * 16;

    f32x4 acc[NT];
    #pragma unroll
    for (int nt = 0; nt < NT; ++nt) acc[nt] = (f32x4){0.f, 0.f, 0.f, 0.f};

    const bf16x8* Wf = (const bf16x8*)Wp;
    for (int c = 0; c < NCHUNK; ++c) {
        const float* Ac = (c == 0) ? A0 : A1;
        __syncthreads();
        const int c4 = l * 4;
        #pragma unroll
        for (int it = 0; it < 4; ++it) {
            int row = it * 4 + w;
            float4 v = *(const float4*)&Ac[(size_t)(r0 + row) * lda + c4];
            float vv[4] = {v.x, v.y, v.z, v.w};
            ushort4 h4, l4;
            unsigned short hh;
            hh = f2b(vv[0]); h4.x = hh; l4.x = f2b(vv[0] - b2f(hh));
            hh = f2b(vv[1]); h4.y = hh; l4.y = f2b(vv[1] - b2f(hh));
            hh = f2b(vv[2]); h4.z = hh; l4.z = f2b(vv[2] - b2f(hh));
            hh = f2b(vv[3]); h4.w = hh; l4.w = f2b(vv[3] - b2f(hh));
            int boff = (c4 * 2) ^ (row << 3);
            *(ushort4*)&s_hi[row * 512 + boff] = h4;
            *(ushort4*)&s_lo[row * 512 + boff] = l4;
        }
        __syncthreads();
        #pragma unroll
        for (int ks = 0; ks < 8; ++ks) {
            const int ksg = c * 8 + ks;
            const int x0 = (ks * 64 + 8 * g) ^ (r << 3);
            union { uint2 u[2]; bf16x8 v; } ah, al;
            ah.u[0] = *(const uint2*)&s_hi[r * 512 + x0];
            ah.u[1] = *(const uint2*)&s_hi[r * 512 + (x0 ^ 32)];
            al.u[0] = *(const uint2*)&s_lo[r * 512 + x0];
            al.u[1] = *(const uint2*)&s_lo[r * 512 + (x0 ^ 32)];
            #pragma unroll
            for (int nt = 0; nt < NT; ++nt) {
                int fb = (nchunk * 4 + w) * NT + nt;
                bf16x8 bf_ = Wf[(size_t)(ksg * NTG + fb) * 64 + l];
                acc[nt] = __builtin_amdgcn_mfma_f32_16x16x32_bf16(ah.v, bf_, acc[nt], 0, 0, 0);
                acc[nt] = __builtin_amdgcn_mfma_f32_16x16x32_bf16(al.v, bf_, acc[nt], 0, 0, 0);
            }
        }
    }
    #pragma unroll
    for (int nt = 0; nt < NT; ++nt) {
        int n = ((nchunk * 4 + w) * NT + nt) * 16 + r;
        float bias = 0.f;
        if (b0) {
            const float* bp = (n < 256) ? b0 : ((n < 512) ? b1 : b2);
            bias = bp[n & 255];
        }
        #pragma unroll
        for (int reg = 0; reg < 4; ++reg) {
            int row = r0 + g * 4 + reg;
            float v = acc[nt][reg] + bias;
            if (ACT == 1) v = siluf(v);
            if (RESID) v += resid[(size_t)row * 256 + n];
            if (OUTMODE == 0) {
                C[(size_t)row * NC + n] = v;
            } else if (OUTMODE == 2) {
                ((unsigned short*)C)[(size_t)row * NC + n] = f2b(v);
            } else {
                if (n < 256) {
                    C[(size_t)row * 256 + n] = v;             // q, fp32
                } else if (n < 512) {
                    int hd = (n - 256) >> 5, dm = (n - 256) & 31;
                    int dp = (dm & 3) | (((dm >> 4) & 1) << 2) | (((dm >> 2) & 3) << 3);
                    unsigned short hb = f2b(v);
                    size_t base = ((size_t)hd * N_NODES + row) * 64;
                    kpk[base + dp]      = hb;
                    kpk[base + 32 + dp] = f2b(v - b2f(hb));
                } else {
                    int hd = (n - 512) >> 5, dm = (n - 512) & 31;
                    int s = row & 31;
                    int sp = (s & 3) | (((s >> 4) & 1) << 2) | (((s >> 2) & 3) << 3);
                    int keyp = (row & ~31) | sp;
                    vpk[((size_t)hd * 32 + dm) * N_NODES + keyp] = f2b(v);
                }
            }
        }
    }
}

// ---------------- fused edge kernel (32 edges/block, bf16 P12, vectorized dedup) ----------------
__global__ __launch_bounds__(256) void k_edge_mfma(
    const unsigned short* __restrict__ P12,
    const int* __restrict__ rows_s, const int* __restrict__ cols_s,
    const float* __restrict__ rad_s,
    const float* __restrict__ w1r, const float* __restrict__ b1,
    const unsigned short* __restrict__ W2F, const float* __restrict__ b2,
    const float* __restrict__ aw, const float* __restrict__ ab,
    float* __restrict__ agg)
{
    __shared__ __align__(16) char s_a[20480];   // phase1/2: 16KB A-tile; epilogue: col-major msgs
    __shared__ int   s_row[TE2], s_cn[TE2];
    __shared__ float s_rad[TE2], s_gp[4][TE2], s_gate[TE2];
    const int t = threadIdx.x, l = t & 63, w = t >> 6;
    const int e0 = blockIdx.x * TE2;

    if (t < TE2) {
        s_row[t] = rows_s[e0 + t];
        s_cn[t]  = cols_s[e0 + t];
        s_rad[t] = rad_s[e0 + t];
    }
    __syncthreads();

    const int c4 = l * 4;
    const float4 wr = *(const float4*)&w1r[c4];
    const float4 bb = *(const float4*)&b1[c4];
    #pragma unroll
    for (int it = 0; it < 8; ++it) {
        int e = it * 4 + w;
        ushort4 pa4 = *(const ushort4*)&P12[(size_t)s_row[e] * 512 + c4];
        ushort4 pb4 = *(const ushort4*)&P12[(size_t)s_cn[e] * 512 + 256 + c4];
        float rad = s_rad[e];
        ushort4 pk;
        pk.x = f2b(siluf(b2f(pa4.x) + b2f(pb4.x) + rad * wr.x + bb.x));
        pk.y = f2b(siluf(b2f(pa4.y) + b2f(pb4.y) + rad * wr.y + bb.y));
        pk.z = f2b(siluf(b2f(pa4.z) + b2f(pb4.z) + rad * wr.z + bb.z));
        pk.w = f2b(siluf(b2f(pa4.w) + b2f(pb4.w) + rad * wr.w + bb.w));
        *(ushort4*)&s_a[e * 512 + ((c4 * 2) ^ ((e & 15) << 3))] = pk;
    }
    __syncthreads();

    const int g = l >> 4, r = l & 15;
    f32x4 acc[2][4];
    #pragma unroll
    for (int mt = 0; mt < 2; ++mt)
        #pragma unroll
        for (int nt = 0; nt < 4; ++nt)
            acc[mt][nt] = (f32x4){0.f, 0.f, 0.f, 0.f};

    const bf16x8* Wf = (const bf16x8*)W2F;
    for (int ks = 0; ks < 8; ++ks) {
        bf16x8 af[2], bfr[4];
        #pragma unroll
        for (int mt = 0; mt < 2; ++mt) {
            int rowa = mt * 16 + r;
            int x0 = (ks * 64 + 8 * g) ^ (r << 3);
            uint2 lo = *(const uint2*)&s_a[rowa * 512 + x0];
            uint2 hi = *(const uint2*)&s_a[rowa * 512 + (x0 ^ 32)];
            union { uint2 u[2]; bf16x8 v; } ua;
            ua.u[0] = lo; ua.u[1] = hi;
            af[mt] = ua.v;
        }
        #pragma unroll
        for (int nt = 0; nt < 4; ++nt)
            bfr[nt] = Wf[(ks * 16 + w * 4 + nt) * 64 + l];
        #pragma unroll
        for (int mt = 0; mt < 2; ++mt)
            #pragma unroll
            for (int nt = 0; nt < 4; ++nt)
                acc[mt][nt] = __builtin_amdgcn_mfma_f32_16x16x32_bf16(af[mt], bfr[nt], acc[mt][nt], 0, 0, 0);
    }

    float b2v[4], awv[4];
    #pragma unroll
    for (int nt = 0; nt < 4; ++nt) {
        int col = w * 64 + nt * 16 + r;
        b2v[nt] = b2[col];
        awv[nt] = aw[col];
    }
    float pg[2][4];
    #pragma unroll
    for (int mt = 0; mt < 2; ++mt)
        #pragma unroll
        for (int reg = 0; reg < 4; ++reg) {
            float s = 0.f;
            #pragma unroll
            for (int nt = 0; nt < 4; ++nt) {
                float v = siluf(acc[mt][nt][reg] + b2v[nt]);
                acc[mt][nt][reg] = v;
                s += v * awv[nt];
            }
            pg[mt][reg] = s;
        }
    #pragma unroll
    for (int off = 1; off < 16; off <<= 1)
        #pragma unroll
        for (int mt = 0; mt < 2; ++mt)
            #pragma unroll
            for (int reg = 0; reg < 4; ++reg)
                pg[mt][reg] += __shfl_xor(pg[mt][reg], off, 64);
    if (r == 0) {
        #pragma unroll
        for (int mt = 0; mt < 2; ++mt)
            #pragma unroll
            for (int reg = 0; reg < 4; ++reg)
                s_gp[w][mt * 16 + g * 4 + reg] = pg[mt][reg];
    }
    __syncthreads();
    if (t < TE2)
        s_gate[t] = sigmf_(s_gp[0][t] + s_gp[1][t] + s_gp[2][t] + s_gp[3][t] + ab[0]);
    __syncthreads();

    // gated msgs -> col-major LDS [col][edge], stride 40 shorts
    unsigned short* s_out = (unsigned short*)s_a;
    #pragma unroll
    for (int mt = 0; mt < 2; ++mt) {
        float4 gt4 = *(const float4*)&s_gate[mt * 16 + g * 4];
        #pragma unroll
        for (int nt = 0; nt < 4; ++nt) {
            int col = w * 64 + nt * 16 + r;
            ushort4 o4;
            o4.x = f2b(acc[mt][nt][0] * gt4.x);
            o4.y = f2b(acc[mt][nt][1] * gt4.y);
            o4.z = f2b(acc[mt][nt][2] * gt4.z);
            o4.w = f2b(acc[mt][nt][3] * gt4.w);
            *(ushort4*)&s_out[col * 40 + mt * 16 + g * 4] = o4;
        }
    }
    __syncthreads();
    // dedup reduce: thread t owns column t, reads 32 edges as 4x b128
    float cur = 0.f;
    #pragma unroll
    for (int c = 0; c < 4; ++c) {
        union { uint4 q; unsigned short s[8]; } ch;
        ch.q = *(const uint4*)&s_out[t * 40 + c * 8];
        #pragma unroll
        for (int j = 0; j < 8; ++j) {
            int e = c * 8 + j;
            cur += b2f(ch.s[j]);
            bool flush = (e == TE2 - 1) || (s_row[e + 1] != s_row[e]);
            if (flush) {
                atomicAdd(&agg[(size_t)s_row[e] * DIM + t], cur);
                cur = 0.f;
            }
        }
    }
}

// ---------------- tiny VALU MLP (readout head only, M=128) ----------------
template<int ACT>
__global__ __launch_bounds__(256) void k_mlp_small(
    const float* __restrict__ A1, const float* __restrict__ W,
    const float* __restrict__ bias, float* __restrict__ C)
{
    __shared__ float s_a[16][260];
    const int t  = threadIdx.x;
    const int r0 = blockIdx.x * 16;
    for (int r = 0; r < 16; ++r)
        s_a[r][t] = A1[(size_t)(r0 + r) * DIM + t];
    __syncthreads();
    const int er0 = (t >> 6) * 4;
    const int c0 = (t & 63) * 4;
    float acc[4][4];
    #pragma unroll
    for (int e = 0; e < 4; ++e)
        #pragma unroll
        for (int c = 0; c < 4; ++c) acc[e][c] = 0.f;
    #pragma unroll 2
    for (int k = 0; k < DIM; k += 4) {
        float4 w0 = *(const float4*)&W[(size_t)(k+0)*DIM + c0];
        float4 w1 = *(const float4*)&W[(size_t)(k+1)*DIM + c0];
        float4 w2 = *(const float4*)&W[(size_t)(k+2)*DIM + c0];
        float4 w3 = *(const float4*)&W[(size_t)(k+3)*DIM + c0];
        #pragma unroll
        for (int e = 0; e < 4; ++e) {
            float4 x = *(const float4*)&s_a[er0+e][k];
            acc[e][0] += x.x*w0.x + x.y*w1.x + x.z*w2.x + x.w*w3.x;
            acc[e][1] += x.x*w0.y + x.y*w1.y + x.z*w2.y + x.w*w3.y;
            acc[e][2] += x.x*w0.z + x.y*w1.z + x.z*w2.z + x.w*w3.z;
            acc[e][3] += x.x*w0.w + x.y*w1.w + x.z*w2.w + x.w*w3.w;
        }
    }
    float4 bb = *(const float4*)&bias[c0];
    #pragma unroll
    for (int e = 0; e < 4; ++e) {
        float v0 = acc[e][0] + bb.x, v1 = acc[e][1] + bb.y;
        float v2 = acc[e][2] + bb.z, v3 = acc[e][3] + bb.w;
        if (ACT == 1) { v0 = siluf(v0); v1 = siluf(v1); v2 = siluf(v2); v3 = siluf(v3); }
        float4 o; o.x = v0; o.y = v1; o.z = v2; o.w = v3;
        *(float4*)&C[(size_t)(r0 + er0 + e) * DIM + c0] = o;
    }
}

// ---------------- LayerNorm ----------------
__global__ __launch_bounds__(256) void k_ln(const float* __restrict__ x,
                                            const float* __restrict__ g,
                                            const float* __restrict__ b,
                                            float* __restrict__ out) {
    int t = threadIdx.x, lane = t & 63, w = t >> 6;
    int row = blockIdx.x * 4 + w;
    float4 v = *(const float4*)&x[(size_t)row * DIM + lane * 4];
    float s = v.x + v.y + v.z + v.w;
    #pragma unroll
    for (int off = 32; off; off >>= 1) s += __shfl_xor(s, off, 64);
    float mu = s * (1.f / 256.f);
    float dx = v.x - mu, dy = v.y - mu, dz = v.z - mu, dw = v.w - mu;
    float q = dx*dx + dy*dy + dz*dz + dw*dw;
    #pragma unroll
    for (int off = 32; off; off >>= 1) q += __shfl_xor(q, off, 64);
    float rs = rsqrtf(q * (1.f / 256.f) + 1e-5f);
    float4 gg = *(const float4*)&g[lane * 4];
    float4 bb = *(const float4*)&b[lane * 4];
    float4 o;
    o.x = dx * rs * gg.x + bb.x;
    o.y = dy * rs * gg.y + bb.y;
    o.z = dz * rs * gg.z + bb.z;
    o.w = dw * rs * gg.w + bb.w;
    *(float4*)&out[(size_t)row * DIM + lane * 4] = o;
}

// ---------------- MFMA flash attention v4: exp2 + cvt_pk + defer-max ----------------
__global__ __launch_bounds__(256) void k_attn_mfma(
    const float* __restrict__ q,
    const unsigned short* __restrict__ kpk,
    const unsigned short* __restrict__ vpk,
    float* __restrict__ o)
{
    __shared__ __align__(16) char s_k[2][8192];
    __shared__ __align__(16) char s_v[2][4096];
    const int t = threadIdx.x, lane = t & 63, w = t >> 6;
    const int g = lane >> 4, r = lane & 15;
    const int head = blockIdx.y;
    const int q0 = blockIdx.x * 64;
    const float scale = 0.17677669529663687f * 1.4426950408889634f;  // 1/sqrt(32) * log2(e)

    bf16x8 qh, ql;
    {
        const float* qp = &q[(size_t)(q0 + w*16 + r) * DIM + head*DKH + 4*g];
        float4 f0 = *(const float4*)qp;
        float4 f1 = *(const float4*)(qp + 16);
        float vv[8] = {f0.x, f0.y, f0.z, f0.w, f1.x, f1.y, f1.z, f1.w};
        union { unsigned short s[8]; bf16x8 v; } uh, ul;
        #pragma unroll
        for (int j = 0; j < 8; ++j) {
            float sv = vv[j] * scale;
            unsigned short hb = f2b(sv);
            uh.s[j] = hb;
            ul.s[j] = f2b(sv - b2f(hb));
        }
        qh = uh.v; ql = ul.v;
    }

    const char* kbase = (const char*)(kpk + (size_t)head * N_NODES * 64);
    const unsigned short* vbase = vpk + (size_t)head * 32 * N_NODES;
    const int vrow = t >> 3, vch = t & 7;

    uint4 kr0, kr1, vr0;
    {
        const char* kt = kbase;
        kr0 = *(const uint4*)(kt + t * 16);
        kr1 = *(const uint4*)(kt + 4096 + t * 16);
        vr0 = *(const uint4*)(vbase + (size_t)vrow * N_NODES + vch * 8);
        int key0 = t >> 3, sl0 = t & 7;
        *(uint4*)&s_k[0][key0 * 128 + ((sl0 ^ (key0 & 7)) << 4)] = kr0;
        int c1 = t + 256, key1 = c1 >> 3, sl1 = c1 & 7;
        *(uint4*)&s_k[0][key1 * 128 + ((sl1 ^ (key1 & 7)) << 4)] = kr1;
        *(uint4*)&s_v[0][vrow * 128 + ((vch ^ (vrow & 7)) << 4)] = vr0;
    }
    __syncthreads();

    float m = -1e30f, l = 0.f;
    f32x4 ot0 = (f32x4){0.f,0.f,0.f,0.f}, ot1 = (f32x4){0.f,0.f,0.f,0.f};

    for (int tile = 0; tile < 64; ++tile) {
        const int cur = tile & 1;
        if (tile < 63) {
            const char* kt = kbase + (size_t)(tile + 1) * 8192;
            kr0 = *(const uint4*)(kt + t * 16);
            kr1 = *(const uint4*)(kt + 4096 + t * 16);
            vr0 = *(const uint4*)(vbase + (size_t)vrow * N_NODES + (tile + 1) * 64 + vch * 8);
        }
        bf16x8 kh[4], kl[4];
        #pragma unroll
        for (int kb = 0; kb < 4; ++kb) {
            int key = kb * 16 + r;
            kh[kb] = *(const bf16x8*)&s_k[cur][key * 128 + ((g ^ (r & 7)) << 4)];
            kl[kb] = *(const bf16x8*)&s_k[cur][key * 128 + (((4 + g) ^ (r & 7)) << 4)];
        }
        f32x4 sc[4];
        #pragma unroll
        for (int kb = 0; kb < 4; ++kb) {
            f32x4 a = (f32x4){0.f,0.f,0.f,0.f};
            a = __builtin_amdgcn_mfma_f32_16x16x32_bf16(kh[kb], qh, a, 0, 0, 0);
            a = __builtin_amdgcn_mfma_f32_16x16x32_bf16(kh[kb], ql, a, 0, 0, 0);
            a = __builtin_amdgcn_mfma_f32_16x16x32_bf16(kl[kb], qh, a, 0, 0, 0);
            sc[kb] = a;
        }
        float tm = -1e30f;
        #pragma unroll
        for (int kb = 0; kb < 4; ++kb)
            #pragma unroll
            for (int e = 0; e < 4; ++e) tm = fmaxf(tm, sc[kb][e]);
        tm = fmaxf(tm, __shfl_xor(tm, 16, 64));
        tm = fmaxf(tm, __shfl_xor(tm, 32, 64));
        float nm = fmaxf(m, tm);
        bool grow = tm > m;
        if (__any(grow)) {
            float scf = exp2f(m - nm);   // ==1 for lanes with no growth
            l *= scf;
            ot0[0] *= scf; ot0[1] *= scf; ot0[2] *= scf; ot0[3] *= scf;
            ot1[0] *= scf; ot1[1] *= scf; ot1[2] *= scf; ot1[3] *= scf;
            m = nm;
        }
        float p[16]; float ls = 0.f;
        #pragma unroll
        for (int kb = 0; kb < 4; ++kb)
            #pragma unroll
            for (int e = 0; e < 4; ++e) {
                float pe = exp2f(sc[kb][e] - m);
                p[kb*4+e] = pe; ls += pe;
            }
        ls += __shfl_xor(ls, 16, 64);
        ls += __shfl_xor(ls, 32, 64);
        l += ls;
        union { unsigned u[4]; bf16x8 v; } pk0, pk1;
        pk0.u[0] = cvtpk(p[0], p[1]);  pk0.u[1] = cvtpk(p[2], p[3]);
        pk0.u[2] = cvtpk(p[4], p[5]);  pk0.u[3] = cvtpk(p[6], p[7]);
        pk1.u[0] = cvtpk(p[8], p[9]);  pk1.u[1] = cvtpk(p[10], p[11]);
        pk1.u[2] = cvtpk(p[12], p[13]); pk1.u[3] = cvtpk(p[14], p[15]);
        bf16x8 vf00 = *(const bf16x8*)&s_v[cur][(0*16 + r) * 128 + (((0*4 + g) ^ (r & 7)) << 4)];
        bf16x8 vf01 = *(const bf16x8*)&s_v[cur][(0*16 + r) * 128 + (((1*4 + g) ^ (r & 7)) << 4)];
        bf16x8 vf10 = *(const bf16x8*)&s_v[cur][(1*16 + r) * 128 + (((0*4 + g) ^ (r & 7)) << 4)];
        bf16x8 vf11 = *(const bf16x8*)&s_v[cur][(1*16 + r) * 128 + (((1*4 + g) ^ (r & 7)) << 4)];
        ot0 = __builtin_amdgcn_mfma_f32_16x16x32_bf16(vf00, pk0.v, ot0, 0, 0, 0);
        ot0 = __builtin_amdgcn_mfma_f32_16x16x32_bf16(vf01, pk1.v, ot0, 0, 0, 0);
        ot1 = __builtin_amdgcn_mfma_f32_16x16x32_bf16(vf10, pk0.v, ot1, 0, 0, 0);
        ot1 = __builtin_amdgcn_mfma_f32_16x16x32_bf16(vf11, pk1.v, ot1, 0, 0, 0);

        __syncthreads();
        if (tile < 63) {
            int key0 = t >> 3, sl0 = t & 7;
            *(uint4*)&s_k[cur ^ 1][key0 * 128 + ((sl0 ^ (key0 & 7)) << 4)] = kr0;
            int c1 = t + 256, key1 = c1 >> 3, sl1 = c1 & 7;
            *(uint4*)&s_k[cur ^ 1][key1 * 128 + ((sl1 ^ (key1 & 7)) << 4)] = kr1;
            *(uint4*)&s_v[cur ^ 1][vrow * 128 + ((vch ^ (vrow & 7)) << 4)] = vr0;
        }
        __syncthreads();
    }

    float inv = 1.f / l;
    float* op = &o[(size_t)(q0 + w*16 + r) * DIM + head*DKH];
    *(float4*)(op + 4*g)      = make_float4(ot0[0]*inv, ot0[1]*inv, ot0[2]*inv, ot0[3]*inv);
    *(float4*)(op + 16 + 4*g) = make_float4(ot1[0]*inv, ot1[1]*inv, ot1[2]*inv, ot1[3]*inv);
}

// ---------------- graph readout ----------------
__global__ __launch_bounds__(256) void k_segsum(const float* __restrict__ h,
                                                const int* __restrict__ batch,
                                                float* __restrict__ gbuf) {
    int i = blockIdx.x * 256 + threadIdx.x;
    int n = i >> 8, d = i & 255;
    atomicAdd(&gbuf[batch[n] * DIM + d], h[i]);
}

__global__ __launch_bounds__(256) void k_head2(const float* __restrict__ gmid,
                                               const float* __restrict__ w2,
                                               const float* __restrict__ b2,
                                               float* __restrict__ out) {
    int t = threadIdx.x, lane = t & 63, w = t >> 6;
    int g = blockIdx.x * 4 + w;
    float4 x  = *(const float4*)&gmid[g * DIM + lane * 4];
    float4 ww = *(const float4*)&w2[lane * 4];
    float s = x.x * ww.x + x.y * ww.y + x.z * ww.z + x.w * ww.w;
    #pragma unroll
    for (int off = 32; off; off >>= 1) s += __shfl_xor(s, off, 64);
    if (lane == 0) out[g] = s + b2[0];
}

extern "C" void kernel_launch(void* const* d_in, const int* in_sizes, int n_in,
                              void* d_out, int out_size, void* d_ws, size_t ws_size,
                              hipStream_t stream)
{
    const int*   z     = (const int*)d_in[0];
    const float* pos   = (const float*)d_in[1];
    const int*   batch = (const int*)d_in[2];
    const int*   ei    = (const int*)d_in[3];
    const float* emb   = (const float*)d_in[4];
    const float* ew1   = (const float*)d_in[5];
    const float* eb1   = (const float*)d_in[6];
    const float* ew2   = (const float*)d_in[7];
    const float* eb2   = (const float*)d_in[8];
    const float* nw1   = (const float*)d_in[9];
    const float* nb1   = (const float*)d_in[10];
    const float* nw2   = (const float*)d_in[11];
    const float* nb2   = (const float*)d_in[12];
    const float* aw    = (const float*)d_in[13];
    const float* ab    = (const float*)d_in[14];
    const float* wq    = (const float*)d_in[15];
    const float* bq    = (const float*)d_in[16];
    const float* wk    = (const float*)d_in[17];
    const float* bk    = (const float*)d_in[18];
    const float* wv    = (const float*)d_in[19];
    const float* bv    = (const float*)d_in[20];
    const float* wo    = (const float*)d_in[21];
    const float* bo    = (const float*)d_in[22];
    const float* ln1g  = (const float*)d_in[23];
    const float* ln1b  = (const float*)d_in[24];
    const float* fw1   = (const float*)d_in[25];
    const float* fb1   = (const float*)d_in[26];
    const float* fw2   = (const float*)d_in[27];
    const float* fb2   = (const float*)d_in[28];
    const float* ln2g  = (const float*)d_in[29];
    const float* ln2b  = (const float*)d_in[30];
    const float* fcw1  = (const float*)d_in[31];
    const float* fcb1  = (const float*)d_in[32];
    const float* fcw2  = (const float*)d_in[33];
    const float* fcb2  = (const float*)d_in[34];
    float* out = (float*)d_out;

    float* ws = (float*)d_ws;
    const size_t ND = (size_t)N_NODES * DIM;
    float* h    = ws;
    float* agg  = ws + ND;
    float* A    = ws + 2 * ND;
    float* U    = ws + 3 * ND;        // P12 bf16 [N,512] (EGNN) / q fp32 [N,256] (enc)
    float* Bffn = ws + 6 * ND;        // ffn-mid [N,512]; kpk/vpk alias
    unsigned short* kpk = (unsigned short*)Bffn;
    unsigned short* vpk = kpk + (size_t)NHEAD * N_NODES * 64;
    float* radial = Bffn + (3 * ND) / 2;
    int*   cnt    = (int*)(radial + N_EDGES);
    int*   pcur   = cnt + N_NODES;
    float* gbuf   = ws + 8 * ND;
    float* gmid   = gbuf + (size_t)NG * DIM;
    float* rad_s  = gmid + (size_t)NG * DIM;
    int*   rows_s = (int*)(rad_s + N_EDGES);
    int*   cols_s = rows_s + N_EDGES;
    unsigned short* W2F   = (unsigned short*)(cols_s + N_EDGES);
    unsigned short* packs = W2F + (size_t)NL * 65536;

    unsigned short* PK_W1   = packs;
    unsigned short* PK_NW1  = packs + 524288;
    unsigned short* PK_NW2  = packs + 1048576;
    unsigned short* PK_QKV  = packs + 1310720;
    unsigned short* PK_WO   = packs + 1703936;
    unsigned short* PK_FFN1 = packs + 1835008;
    unsigned short* PK_FFN2 = packs + 2097152;

    dim3 b256(256);

    k_embed<<<N_NODES * DIM / 256, b256, 0, stream>>>(z, emb, h);
    k_radial<<<N_EDGES / 256, b256, 0, stream>>>(pos, ei, radial);
    k_conv_w2<<<NL * 8192 / 256, b256, 0, stream>>>(ew2, W2F);
    k_pack_all<<<1152, b256, 0, stream>>>(ew1, nw1, nw2, wq, wk, wv, wo, fw1, fw2, packs);

    hipMemsetAsync(cnt, 0, N_NODES * sizeof(int), stream);
    k_hist<<<N_EDGES / 256, b256, 0, stream>>>(ei, cnt);
    k_scan<<<1, b256, 0, stream>>>(cnt, pcur);
    k_scatter<<<N_EDGES / 256, b256, 0, stream>>>(ei, radial, pcur, rows_s, cols_s, rad_s);

    for (int l = 0; l < NL; ++l) {
        hipMemsetAsync(agg, 0, ND * sizeof(float), stream);
        const float* W1l = ew1 + (size_t)l * 513 * DIM;
        k_gemm<1,512,2,0,0,2><<<512, b256, 0, stream>>>(h, nullptr, DIM,
            PK_W1 + (size_t)l * 131072, nullptr, nullptr, nullptr, nullptr, U,
            nullptr, nullptr);
        k_edge_mfma<<<N_EDGES / TE2, b256, 0, stream>>>((const unsigned short*)U,
            rows_s, cols_s, rad_s,
            W1l + (size_t)512 * DIM, eb1 + (size_t)l * DIM,
            W2F + (size_t)l * 65536, eb2 + (size_t)l * DIM,
            aw + (size_t)l * DIM, ab + l, agg);
        const float* nb1l = nb1 + (size_t)l * DIM;
        k_gemm<2,256,2,1,0,0><<<512, b256, 0, stream>>>(h, agg, DIM,
            PK_NW1 + (size_t)l * 131072, nb1l, nb1l, nb1l, nullptr, A,
            nullptr, nullptr);
        const float* nb2l = nb2 + (size_t)l * DIM;
        k_gemm<1,256,2,0,1,0><<<512, b256, 0, stream>>>(A, nullptr, DIM,
            PK_NW2 + (size_t)l * 65536, nb2l, nb2l, nb2l, h, h,
            nullptr, nullptr);
    }

    for (int i = 0; i < NENC; ++i) {
        k_gemm<1,768,3,0,0,1><<<768, b256, 0, stream>>>(h, nullptr, DIM,
            PK_QKV + (size_t)i * 196608,
            bq + (size_t)i * DIM, bk + (size_t)i * DIM, bv + (size_t)i * DIM, nullptr, U,
            kpk, vpk);
        dim3 ag(N_NODES / 64, NHEAD);
        k_attn_mfma<<<ag, b256, 0, stream>>>(U, kpk, vpk, A);
        const float* bol = bo + (size_t)i * DIM;
        k_gemm<1,256,2,0,1,0><<<512, b256, 0, stream>>>(A, nullptr, DIM,
            PK_WO + (size_t)i * 65536, bol, bol, bol, h, agg,
            nullptr, nullptr);
        k_ln<<<N_NODES / 4, b256, 0, stream>>>(agg, ln1g + (size_t)i * DIM, ln1b + (size_t)i * DIM, h);
        const float* fb1l = fb1 + (size_t)i * FFD;
        k_gemm<1,512,2,1,0,0><<<512, b256, 0, stream>>>(h, nullptr, DIM,
            PK_FFN1 + (size_t)i * 131072, fb1l, fb1l + 256, nullptr, nullptr, Bffn,
            nullptr, nullptr);
        const float* fb2l = fb2 + (size_t)i * DIM;
        k_gemm<2,256,2,0,1,0><<<512, b256, 0, stream>>>(Bffn, Bffn + 256, FFD,
            PK_FFN2 + (size_t)i * 131072, fb2l, fb2l, fb2l, h, agg,
            nullptr, nullptr);
        k_ln<<<N_NODES / 4, b256, 0, stream>>>(agg, ln2g + (size_t)i * DIM, ln2b + (size_t)i * DIM, h);
    }

    hipMemsetAsync(gbuf, 0, (size_t)NG * DIM * sizeof(float), stream);
    k_segsum<<<N_NODES * DIM / 256, b256, 0, stream>>>(h, batch, gbuf);
    k_mlp_small<1><<<NG / 16, b256, 0, stream>>>(gbuf, fcw1, fcb1, gmid);
    k_head2<<<NG / 4, b256, 0, stream>>>(gmid, fcw2, fcb2, out);
}

// Round 9
// 669.950 us; speedup vs baseline: 1.0141x; 1.0141x over previous
//
#include <hip/hip_runtime.h>
#include <math.h>

#define N_NODES 4096
#define N_EDGES 131072
#define DIM     256
#define NL      4
#define NENC    2
#define FFD     512
#define NG      128
#define NHEAD   8
#define DKH     32
#define TE2     32

typedef __attribute__((ext_vector_type(8))) short bf16x8;
typedef __attribute__((ext_vector_type(4))) float f32x4;

__device__ __forceinline__ float siluf(float x) { return x / (1.f + __expf(-x)); }
__device__ __forceinline__ float sigmf_(float x) { return 1.f / (1.f + __expf(-x)); }
__device__ __forceinline__ unsigned short f2b(float f) {
    union { float f; unsigned u; } x; x.f = f;
    unsigned r = x.u + 0x7fffu + ((x.u >> 16) & 1u);
    return (unsigned short)(r >> 16);
}
__device__ __forceinline__ float b2f(unsigned short h) {
    union { unsigned u; float f; } x; x.u = (unsigned)h << 16; return x.f;
}

// ---------------- embedding ----------------
__global__ __launch_bounds__(256) void k_embed(const int* __restrict__ z,
                                               const float* __restrict__ emb,
                                               float* __restrict__ h) {
    int i = blockIdx.x * 256 + threadIdx.x;
    int n = i >> 8, d = i & 255;
    h[i] = emb[z[n] * DIM + d];
}

// ---------------- radial ----------------
__global__ __launch_bounds__(256) void k_radial(const float* __restrict__ pos,
                                                const int* __restrict__ ei,
                                                float* __restrict__ radial) {
    int e = blockIdx.x * 256 + threadIdx.x;
    if (e >= N_EDGES) return;
    int r = ei[e], c = ei[N_EDGES + e];
    float dx = pos[r*3+0] - pos[c*3+0];
    float dy = pos[r*3+1] - pos[c*3+1];
    float dz = pos[r*3+2] - pos[c*3+2];
    radial[e] = dx*dx + dy*dy + dz*dz;
}

// ---------------- edge counting sort (by row node) ----------------
__global__ __launch_bounds__(256) void k_hist(const int* __restrict__ ei, int* __restrict__ cnt) {
    int e = blockIdx.x * 256 + threadIdx.x;
    if (e < N_EDGES) atomicAdd(&cnt[ei[e]], 1);
}

__global__ __launch_bounds__(256) void k_scan(const int* __restrict__ cnt, int* __restrict__ pos) {
    __shared__ int s_w[4];
    int t = threadIdx.x, lane = t & 63, wv = t >> 6;
    int loc[16]; int s = 0;
    #pragma unroll
    for (int i = 0; i < 16; ++i) { loc[i] = s; s += cnt[t * 16 + i]; }
    int inc = s;
    #pragma unroll
    for (int off = 1; off < 64; off <<= 1) {
        int v = __shfl_up(inc, off, 64);
        if (lane >= off) inc += v;
    }
    if (lane == 63) s_w[wv] = inc;
    __syncthreads();
    int wbase = 0;
    for (int j = 0; j < wv; ++j) wbase += s_w[j];
    int base = wbase + inc - s;
    #pragma unroll
    for (int i = 0; i < 16; ++i) pos[t * 16 + i] = base + loc[i];
}

__global__ __launch_bounds__(256) void k_scatter(const int* __restrict__ ei,
                                                 const float* __restrict__ radial,
                                                 int* __restrict__ pos,
                                                 int* __restrict__ rows_s,
                                                 int* __restrict__ cols_s,
                                                 float* __restrict__ rad_s) {
    int e = blockIdx.x * 256 + threadIdx.x;
    if (e >= N_EDGES) return;
    int r = ei[e];
    int p = atomicAdd(&pos[r], 1);
    rows_s[p] = r;
    cols_s[p] = ei[N_EDGES + e];
    rad_s[p] = radial[e];
}

// ---------------- W2 -> bf16 MFMA-fragment-linear pack (edge GEMM2) ----------------
__global__ __launch_bounds__(256) void k_conv_w2(const float* __restrict__ ew2,
                                                 unsigned short* __restrict__ W2F) {
    int tid = blockIdx.x * 256 + threadIdx.x;
    int layer = tid >> 13;
    int r = tid & 8191;
    int ks = r >> 10, ntg = (r >> 6) & 15, lane = r & 63;
    const float* W = ew2 + (size_t)layer * 65536;
    unsigned short tmp[8];
    #pragma unroll
    for (int j = 0; j < 8; ++j) {
        int k = ks*32 + 4*(lane>>4) + (j&3) + 16*(j>>2);
        int n = ntg*16 + (lane&15);
        tmp[j] = f2b(W[k*256 + n]);
    }
    *(bf16x8*)&W2F[(size_t)layer*65536 + (size_t)r*8] = *(const bf16x8*)&tmp[0];
}

// ---------------- batched pack of ALL dense weights -> fragment-linear bf16 ----------------
__global__ __launch_bounds__(256) void k_pack_all(
    const float* __restrict__ ew1, const float* __restrict__ nw1, const float* __restrict__ nw2,
    const float* __restrict__ wq, const float* __restrict__ wk, const float* __restrict__ wv,
    const float* __restrict__ wo, const float* __restrict__ fw1, const float* __restrict__ fw2,
    unsigned short* __restrict__ dst)
{
    int f = blockIdx.x * 256 + threadIdx.x;
    int rem, panel, NTG, mode;
    if (f < 65536)       { rem = f;          panel = rem / 16384; rem &= 16383; NTG = 32; mode = 0; }
    else if (f < 131072) { rem = f - 65536;  panel = rem / 16384; rem &= 16383; NTG = 16; mode = 1; }
    else if (f < 163840) { rem = f - 131072; panel = rem / 8192;  rem &= 8191;  NTG = 16; mode = 2; }
    else if (f < 212992) { rem = f - 163840; panel = rem / 24576; rem %= 24576; NTG = 48; mode = 3; }
    else if (f < 229376) { rem = f - 212992; panel = rem / 8192;  rem &= 8191;  NTG = 16; mode = 4; }
    else if (f < 262144) { rem = f - 229376; panel = rem / 16384; rem &= 16383; NTG = 32; mode = 5; }
    else                 { rem = f - 262144; panel = rem / 16384; rem &= 16383; NTG = 16; mode = 6; }
    int ks   = rem / (NTG * 64);
    int ntg  = (rem >> 6) % NTG;
    int lane = rem & 63;
    unsigned short tmp[8];
    #pragma unroll
    for (int j = 0; j < 8; ++j) {
        int k = ks*32 + 4*(lane>>4) + (j&3) + 16*(j>>2);
        int n = ntg*16 + (lane&15);
        float val;
        switch (mode) {
            case 0: val = ew1[(size_t)panel*131328 + (n < 256 ? k*256 + n : (256 + k)*256 + (n - 256))]; break;
            case 1: val = nw1[(size_t)panel*131072 + k*256 + n]; break;
            case 2: val = nw2[(size_t)panel*65536 + k*256 + n]; break;
            case 3: { const float* b = (n < 256) ? wq : ((n < 512) ? wk : wv);
                      val = b[(size_t)panel*65536 + k*256 + (n & 255)]; } break;
            case 4: val = wo[(size_t)panel*65536 + k*256 + n]; break;
            case 5: val = fw1[(size_t)panel*131072 + k*512 + n]; break;
            default: val = fw2[(size_t)panel*131072 + k*256 + n]; break;
        }
        tmp[j] = f2b(val);
    }
    *(bf16x8*)&dst[(size_t)f * 8] = *(const bf16x8*)&tmp[0];
}

// ---------------- generic split-bf16 MFMA GEMM ----------------
// OUTMODE 0: fp32 C. OUTMODE 1 (QKV): q fp32 | kpk frag hi/lo | vpk frag V^T.
template<int NCHUNK, int NC, int NSPLIT, int ACT, int RESID, int OUTMODE>
__global__ __launch_bounds__(256) void k_gemm(
    const float* __restrict__ A0, const float* __restrict__ A1, int lda,
    const unsigned short* __restrict__ Wp,
    const float* __restrict__ b0, const float* __restrict__ b1, const float* __restrict__ b2,
    const float* __restrict__ resid, float* __restrict__ C,
    unsigned short* __restrict__ kpk, unsigned short* __restrict__ vpk)
{
    constexpr int NT  = NC / (64 * NSPLIT);
    constexpr int NTG = NC / 16;
    __shared__ __align__(16) char s_hi[16 * 512];
    __shared__ __align__(16) char s_lo[16 * 512];
    const int t = threadIdx.x, l = t & 63, w = t >> 6;
    const int g = l >> 4, r = l & 15;
    const int mtile  = blockIdx.x % 256;
    const int nchunk = blockIdx.x / 256;
    const int r0 = mtile * 16;

    f32x4 acc[NT];
    #pragma unroll
    for (int nt = 0; nt < NT; ++nt) acc[nt] = (f32x4){0.f, 0.f, 0.f, 0.f};

    const bf16x8* Wf = (const bf16x8*)Wp;
    for (int c = 0; c < NCHUNK; ++c) {
        const float* Ac = (c == 0) ? A0 : A1;
        __syncthreads();
        const int c4 = l * 4;
        #pragma unroll
        for (int it = 0; it < 4; ++it) {
            int row = it * 4 + w;
            float4 v = *(const float4*)&Ac[(size_t)(r0 + row) * lda + c4];
            float vv[4] = {v.x, v.y, v.z, v.w};
            ushort4 h4, l4;
            unsigned short hh;
            hh = f2b(vv[0]); h4.x = hh; l4.x = f2b(vv[0] - b2f(hh));
            hh = f2b(vv[1]); h4.y = hh; l4.y = f2b(vv[1] - b2f(hh));
            hh = f2b(vv[2]); h4.z = hh; l4.z = f2b(vv[2] - b2f(hh));
            hh = f2b(vv[3]); h4.w = hh; l4.w = f2b(vv[3] - b2f(hh));
            int boff = (c4 * 2) ^ (row << 3);
            *(ushort4*)&s_hi[row * 512 + boff] = h4;
            *(ushort4*)&s_lo[row * 512 + boff] = l4;
        }
        __syncthreads();
        #pragma unroll
        for (int ks = 0; ks < 8; ++ks) {
            const int ksg = c * 8 + ks;
            const int x0 = (ks * 64 + 8 * g) ^ (r << 3);
            union { uint2 u[2]; bf16x8 v; } ah, al;
            ah.u[0] = *(const uint2*)&s_hi[r * 512 + x0];
            ah.u[1] = *(const uint2*)&s_hi[r * 512 + (x0 ^ 32)];
            al.u[0] = *(const uint2*)&s_lo[r * 512 + x0];
            al.u[1] = *(const uint2*)&s_lo[r * 512 + (x0 ^ 32)];
            #pragma unroll
            for (int nt = 0; nt < NT; ++nt) {
                int fb = (nchunk * 4 + w) * NT + nt;
                bf16x8 bf_ = Wf[(size_t)(ksg * NTG + fb) * 64 + l];
                acc[nt] = __builtin_amdgcn_mfma_f32_16x16x32_bf16(ah.v, bf_, acc[nt], 0, 0, 0);
                acc[nt] = __builtin_amdgcn_mfma_f32_16x16x32_bf16(al.v, bf_, acc[nt], 0, 0, 0);
            }
        }
    }
    #pragma unroll
    for (int nt = 0; nt < NT; ++nt) {
        int n = ((nchunk * 4 + w) * NT + nt) * 16 + r;
        float bias = 0.f;
        if (b0) {
            const float* bp = (n < 256) ? b0 : ((n < 512) ? b1 : b2);
            bias = bp[n & 255];
        }
        #pragma unroll
        for (int reg = 0; reg < 4; ++reg) {
            int row = r0 + g * 4 + reg;
            float v = acc[nt][reg] + bias;
            if (ACT == 1) v = siluf(v);
            if (RESID) v += resid[(size_t)row * 256 + n];
            if (OUTMODE == 0) {
                C[(size_t)row * NC + n] = v;
            } else {
                if (n < 256) {
                    C[(size_t)row * 256 + n] = v;             // q, fp32
                } else if (n < 512) {
                    int hd = (n - 256) >> 5, dm = (n - 256) & 31;
                    int dp = (dm & 3) | (((dm >> 4) & 1) << 2) | (((dm >> 2) & 3) << 3);
                    unsigned short hb = f2b(v);
                    size_t base = ((size_t)hd * N_NODES + row) * 64;
                    kpk[base + dp]      = hb;
                    kpk[base + 32 + dp] = f2b(v - b2f(hb));
                } else {
                    int hd = (n - 512) >> 5, dm = (n - 512) & 31;
                    int s = row & 31;
                    int sp = (s & 3) | (((s >> 4) & 1) << 2) | (((s >> 2) & 3) << 3);
                    int keyp = (row & ~31) | sp;
                    vpk[((size_t)hd * 32 + dm) * N_NODES + keyp] = f2b(v);
                }
            }
        }
    }
}

// ---------------- fused edge kernel (32 edges/block, fp32 P12, vectorized dedup) ----------------
__global__ __launch_bounds__(256) void k_edge_mfma(
    const float* __restrict__ P12,
    const int* __restrict__ rows_s, const int* __restrict__ cols_s,
    const float* __restrict__ rad_s,
    const float* __restrict__ w1r, const float* __restrict__ b1,
    const unsigned short* __restrict__ W2F, const float* __restrict__ b2,
    const float* __restrict__ aw, const float* __restrict__ ab,
    float* __restrict__ agg)
{
    __shared__ __align__(16) char s_a[20480];
    __shared__ int   s_row[TE2], s_cn[TE2];
    __shared__ float s_rad[TE2], s_gp[4][TE2], s_gate[TE2];
    const int t = threadIdx.x, l = t & 63, w = t >> 6;
    const int e0 = blockIdx.x * TE2;

    if (t < TE2) {
        s_row[t] = rows_s[e0 + t];
        s_cn[t]  = cols_s[e0 + t];
        s_rad[t] = rad_s[e0 + t];
    }
    __syncthreads();

    const int c4 = l * 4;
    const float4 wr = *(const float4*)&w1r[c4];
    const float4 bb = *(const float4*)&b1[c4];
    #pragma unroll
    for (int it = 0; it < 8; ++it) {
        int e = it * 4 + w;
        float4 pa = *(const float4*)&P12[(size_t)s_row[e] * 512 + c4];
        float4 pb = *(const float4*)&P12[(size_t)s_cn[e] * 512 + 256 + c4];
        float rad = s_rad[e];
        ushort4 pk;
        pk.x = f2b(siluf(pa.x + pb.x + rad * wr.x + bb.x));
        pk.y = f2b(siluf(pa.y + pb.y + rad * wr.y + bb.y));
        pk.z = f2b(siluf(pa.z + pb.z + rad * wr.z + bb.z));
        pk.w = f2b(siluf(pa.w + pb.w + rad * wr.w + bb.w));
        *(ushort4*)&s_a[e * 512 + ((c4 * 2) ^ ((e & 15) << 3))] = pk;
    }
    __syncthreads();

    const int g = l >> 4, r = l & 15;
    f32x4 acc[2][4];
    #pragma unroll
    for (int mt = 0; mt < 2; ++mt)
        #pragma unroll
        for (int nt = 0; nt < 4; ++nt)
            acc[mt][nt] = (f32x4){0.f, 0.f, 0.f, 0.f};

    const bf16x8* Wf = (const bf16x8*)W2F;
    for (int ks = 0; ks < 8; ++ks) {
        bf16x8 af[2], bfr[4];
        #pragma unroll
        for (int mt = 0; mt < 2; ++mt) {
            int rowa = mt * 16 + r;
            int x0 = (ks * 64 + 8 * g) ^ (r << 3);
            uint2 lo = *(const uint2*)&s_a[rowa * 512 + x0];
            uint2 hi = *(const uint2*)&s_a[rowa * 512 + (x0 ^ 32)];
            union { uint2 u[2]; bf16x8 v; } ua;
            ua.u[0] = lo; ua.u[1] = hi;
            af[mt] = ua.v;
        }
        #pragma unroll
        for (int nt = 0; nt < 4; ++nt)
            bfr[nt] = Wf[(ks * 16 + w * 4 + nt) * 64 + l];
        #pragma unroll
        for (int mt = 0; mt < 2; ++mt)
            #pragma unroll
            for (int nt = 0; nt < 4; ++nt)
                acc[mt][nt] = __builtin_amdgcn_mfma_f32_16x16x32_bf16(af[mt], bfr[nt], acc[mt][nt], 0, 0, 0);
    }

    float b2v[4], awv[4];
    #pragma unroll
    for (int nt = 0; nt < 4; ++nt) {
        int col = w * 64 + nt * 16 + r;
        b2v[nt] = b2[col];
        awv[nt] = aw[col];
    }
    float pg[2][4];
    #pragma unroll
    for (int mt = 0; mt < 2; ++mt)
        #pragma unroll
        for (int reg = 0; reg < 4; ++reg) {
            float s = 0.f;
            #pragma unroll
            for (int nt = 0; nt < 4; ++nt) {
                float v = siluf(acc[mt][nt][reg] + b2v[nt]);
                acc[mt][nt][reg] = v;
                s += v * awv[nt];
            }
            pg[mt][reg] = s;
        }
    #pragma unroll
    for (int off = 1; off < 16; off <<= 1)
        #pragma unroll
        for (int mt = 0; mt < 2; ++mt)
            #pragma unroll
            for (int reg = 0; reg < 4; ++reg)
                pg[mt][reg] += __shfl_xor(pg[mt][reg], off, 64);
    if (r == 0) {
        #pragma unroll
        for (int mt = 0; mt < 2; ++mt)
            #pragma unroll
            for (int reg = 0; reg < 4; ++reg)
                s_gp[w][mt * 16 + g * 4 + reg] = pg[mt][reg];
    }
    __syncthreads();
    if (t < TE2)
        s_gate[t] = sigmf_(s_gp[0][t] + s_gp[1][t] + s_gp[2][t] + s_gp[3][t] + ab[0]);
    __syncthreads();

    // gated msgs -> col-major LDS [col][edge], stride 40 shorts
    unsigned short* s_out = (unsigned short*)s_a;
    #pragma unroll
    for (int mt = 0; mt < 2; ++mt) {
        float4 gt4 = *(const float4*)&s_gate[mt * 16 + g * 4];
        #pragma unroll
        for (int nt = 0; nt < 4; ++nt) {
            int col = w * 64 + nt * 16 + r;
            ushort4 o4;
            o4.x = f2b(acc[mt][nt][0] * gt4.x);
            o4.y = f2b(acc[mt][nt][1] * gt4.y);
            o4.z = f2b(acc[mt][nt][2] * gt4.z);
            o4.w = f2b(acc[mt][nt][3] * gt4.w);
            *(ushort4*)&s_out[col * 40 + mt * 16 + g * 4] = o4;
        }
    }
    __syncthreads();
    float cur = 0.f;
    #pragma unroll
    for (int c = 0; c < 4; ++c) {
        union { uint4 q; unsigned short s[8]; } ch;
        ch.q = *(const uint4*)&s_out[t * 40 + c * 8];
        #pragma unroll
        for (int j = 0; j < 8; ++j) {
            int e = c * 8 + j;
            cur += b2f(ch.s[j]);
            bool flush = (e == TE2 - 1) || (s_row[e + 1] != s_row[e]);
            if (flush) {
                atomicAdd(&agg[(size_t)s_row[e] * DIM + t], cur);
                cur = 0.f;
            }
        }
    }
}

// ---------------- tiny VALU MLP (readout head only, M=128) ----------------
template<int ACT>
__global__ __launch_bounds__(256) void k_mlp_small(
    const float* __restrict__ A1, const float* __restrict__ W,
    const float* __restrict__ bias, float* __restrict__ C)
{
    __shared__ float s_a[16][260];
    const int t  = threadIdx.x;
    const int r0 = blockIdx.x * 16;
    for (int r = 0; r < 16; ++r)
        s_a[r][t] = A1[(size_t)(r0 + r) * DIM + t];
    __syncthreads();
    const int er0 = (t >> 6) * 4;
    const int c0 = (t & 63) * 4;
    float acc[4][4];
    #pragma unroll
    for (int e = 0; e < 4; ++e)
        #pragma unroll
        for (int c = 0; c < 4; ++c) acc[e][c] = 0.f;
    #pragma unroll 2
    for (int k = 0; k < DIM; k += 4) {
        float4 w0 = *(const float4*)&W[(size_t)(k+0)*DIM + c0];
        float4 w1 = *(const float4*)&W[(size_t)(k+1)*DIM + c0];
        float4 w2 = *(const float4*)&W[(size_t)(k+2)*DIM + c0];
        float4 w3 = *(const float4*)&W[(size_t)(k+3)*DIM + c0];
        #pragma unroll
        for (int e = 0; e < 4; ++e) {
            float4 x = *(const float4*)&s_a[er0+e][k];
            acc[e][0] += x.x*w0.x + x.y*w1.x + x.z*w2.x + x.w*w3.x;
            acc[e][1] += x.x*w0.y + x.y*w1.y + x.z*w2.y + x.w*w3.y;
            acc[e][2] += x.x*w0.z + x.y*w1.z + x.z*w2.z + x.w*w3.z;
            acc[e][3] += x.x*w0.w + x.y*w1.w + x.z*w2.w + x.w*w3.w;
        }
    }
    float4 bb = *(const float4*)&bias[c0];
    #pragma unroll
    for (int e = 0; e < 4; ++e) {
        float v0 = acc[e][0] + bb.x, v1 = acc[e][1] + bb.y;
        float v2 = acc[e][2] + bb.z, v3 = acc[e][3] + bb.w;
        if (ACT == 1) { v0 = siluf(v0); v1 = siluf(v1); v2 = siluf(v2); v3 = siluf(v3); }
        float4 o; o.x = v0; o.y = v1; o.z = v2; o.w = v3;
        *(float4*)&C[(size_t)(r0 + er0 + e) * DIM + c0] = o;
    }
}

// ---------------- LayerNorm ----------------
__global__ __launch_bounds__(256) void k_ln(const float* __restrict__ x,
                                            const float* __restrict__ g,
                                            const float* __restrict__ b,
                                            float* __restrict__ out) {
    int t = threadIdx.x, lane = t & 63, w = t >> 6;
    int row = blockIdx.x * 4 + w;
    float4 v = *(const float4*)&x[(size_t)row * DIM + lane * 4];
    float s = v.x + v.y + v.z + v.w;
    #pragma unroll
    for (int off = 32; off; off >>= 1) s += __shfl_xor(s, off, 64);
    float mu = s * (1.f / 256.f);
    float dx = v.x - mu, dy = v.y - mu, dz = v.z - mu, dw = v.w - mu;
    float q = dx*dx + dy*dy + dz*dz + dw*dw;
    #pragma unroll
    for (int off = 32; off; off >>= 1) q += __shfl_xor(q, off, 64);
    float rs = rsqrtf(q * (1.f / 256.f) + 1e-5f);
    float4 gg = *(const float4*)&g[lane * 4];
    float4 bb = *(const float4*)&b[lane * 4];
    float4 o;
    o.x = dx * rs * gg.x + bb.x;
    o.y = dy * rs * gg.y + bb.y;
    o.z = dz * rs * gg.z + bb.z;
    o.w = dw * rs * gg.w + bb.w;
    *(float4*)&out[(size_t)row * DIM + lane * 4] = o;
}

// ---------------- MFMA flash attention v5: key-split x2, LDS dbuf, partial out ----------------
// grid (N/64, H, 2). Block (x,head,split): queries q0..q0+63, keys [split*2048, +2048).
// Writes unnormalized O partial + (m,l) per query; k_attn_merge combines.
__global__ __launch_bounds__(256) void k_attn_mfma(
    const float* __restrict__ q,
    const unsigned short* __restrict__ kpk,
    const unsigned short* __restrict__ vpk,
    float* __restrict__ opart0, float* __restrict__ opart1,
    float* __restrict__ mlbuf)
{
    __shared__ __align__(16) char s_k[2][8192];
    __shared__ __align__(16) char s_v[2][4096];
    const int t = threadIdx.x, lane = t & 63, w = t >> 6;
    const int g = lane >> 4, r = lane & 15;
    const int head = blockIdx.y;
    const int split = blockIdx.z;
    const int q0 = blockIdx.x * 64;
    const float scale = 0.17677669529663687f;

    bf16x8 qh, ql;
    {
        const float* qp = &q[(size_t)(q0 + w*16 + r) * DIM + head*DKH + 4*g];
        float4 f0 = *(const float4*)qp;
        float4 f1 = *(const float4*)(qp + 16);
        float vv[8] = {f0.x, f0.y, f0.z, f0.w, f1.x, f1.y, f1.z, f1.w};
        union { unsigned short s[8]; bf16x8 v; } uh, ul;
        #pragma unroll
        for (int j = 0; j < 8; ++j) {
            float sv = vv[j] * scale;
            unsigned short hb = f2b(sv);
            uh.s[j] = hb;
            ul.s[j] = f2b(sv - b2f(hb));
        }
        qh = uh.v; ql = ul.v;
    }

    const char* kbase = (const char*)(kpk + (size_t)head * N_NODES * 64) + (size_t)split * 32 * 8192;
    const unsigned short* vbase = vpk + (size_t)head * 32 * N_NODES;
    const int koff = split * 2048;
    const int vrow = t >> 3, vch = t & 7;

    uint4 kr0, kr1, vr0;
    {
        const char* kt = kbase;
        kr0 = *(const uint4*)(kt + t * 16);
        kr1 = *(const uint4*)(kt + 4096 + t * 16);
        vr0 = *(const uint4*)(vbase + (size_t)vrow * N_NODES + koff + vch * 8);
        int key0 = t >> 3, sl0 = t & 7;
        *(uint4*)&s_k[0][key0 * 128 + ((sl0 ^ (key0 & 7)) << 4)] = kr0;
        int c1 = t + 256, key1 = c1 >> 3, sl1 = c1 & 7;
        *(uint4*)&s_k[0][key1 * 128 + ((sl1 ^ (key1 & 7)) << 4)] = kr1;
        *(uint4*)&s_v[0][vrow * 128 + ((vch ^ (vrow & 7)) << 4)] = vr0;
    }
    __syncthreads();

    float m = -1e30f, l = 0.f;
    f32x4 ot0 = (f32x4){0.f,0.f,0.f,0.f}, ot1 = (f32x4){0.f,0.f,0.f,0.f};

    for (int tile = 0; tile < 32; ++tile) {
        const int cur = tile & 1;
        if (tile < 31) {
            const char* kt = kbase + (size_t)(tile + 1) * 8192;
            kr0 = *(const uint4*)(kt + t * 16);
            kr1 = *(const uint4*)(kt + 4096 + t * 16);
            vr0 = *(const uint4*)(vbase + (size_t)vrow * N_NODES + koff + (tile + 1) * 64 + vch * 8);
        }
        bf16x8 kh[4], kl[4];
        #pragma unroll
        for (int kb = 0; kb < 4; ++kb) {
            int key = kb * 16 + r;
            kh[kb] = *(const bf16x8*)&s_k[cur][key * 128 + ((g ^ (r & 7)) << 4)];
            kl[kb] = *(const bf16x8*)&s_k[cur][key * 128 + (((4 + g) ^ (r & 7)) << 4)];
        }
        f32x4 sc[4];
        #pragma unroll
        for (int kb = 0; kb < 4; ++kb) {
            f32x4 a = (f32x4){0.f,0.f,0.f,0.f};
            a = __builtin_amdgcn_mfma_f32_16x16x32_bf16(kh[kb], qh, a, 0, 0, 0);
            a = __builtin_amdgcn_mfma_f32_16x16x32_bf16(kh[kb], ql, a, 0, 0, 0);
            a = __builtin_amdgcn_mfma_f32_16x16x32_bf16(kl[kb], qh, a, 0, 0, 0);
            sc[kb] = a;
        }
        float tm = -1e30f;
        #pragma unroll
        for (int kb = 0; kb < 4; ++kb)
            #pragma unroll
            for (int e = 0; e < 4; ++e) tm = fmaxf(tm, sc[kb][e]);
        tm = fmaxf(tm, __shfl_xor(tm, 16, 64));
        tm = fmaxf(tm, __shfl_xor(tm, 32, 64));
        float nm = fmaxf(m, tm);
        float scf = __expf(m - nm);
        m = nm;
        float p[16]; float ls = 0.f;
        #pragma unroll
        for (int kb = 0; kb < 4; ++kb)
            #pragma unroll
            for (int e = 0; e < 4; ++e) {
                float pe = __expf(sc[kb][e] - nm);
                p[kb*4+e] = pe; ls += pe;
            }
        ls += __shfl_xor(ls, 16, 64);
        ls += __shfl_xor(ls, 32, 64);
        l = l * scf + ls;
        ot0[0] *= scf; ot0[1] *= scf; ot0[2] *= scf; ot0[3] *= scf;
        ot1[0] *= scf; ot1[1] *= scf; ot1[2] *= scf; ot1[3] *= scf;
        union { unsigned short s[8]; bf16x8 v; } pk0, pk1;
        #pragma unroll
        for (int j = 0; j < 8; ++j) {
            pk0.s[j] = f2b(p[(j >> 2) * 4 + (j & 3)]);
            pk1.s[j] = f2b(p[(2 + (j >> 2)) * 4 + (j & 3)]);
        }
        bf16x8 vf00 = *(const bf16x8*)&s_v[cur][(0*16 + r) * 128 + (((0*4 + g) ^ (r & 7)) << 4)];
        bf16x8 vf01 = *(const bf16x8*)&s_v[cur][(0*16 + r) * 128 + (((1*4 + g) ^ (r & 7)) << 4)];
        bf16x8 vf10 = *(const bf16x8*)&s_v[cur][(1*16 + r) * 128 + (((0*4 + g) ^ (r & 7)) << 4)];
        bf16x8 vf11 = *(const bf16x8*)&s_v[cur][(1*16 + r) * 128 + (((1*4 + g) ^ (r & 7)) << 4)];
        ot0 = __builtin_amdgcn_mfma_f32_16x16x32_bf16(vf00, pk0.v, ot0, 0, 0, 0);
        ot0 = __builtin_amdgcn_mfma_f32_16x16x32_bf16(vf01, pk1.v, ot0, 0, 0, 0);
        ot1 = __builtin_amdgcn_mfma_f32_16x16x32_bf16(vf10, pk0.v, ot1, 0, 0, 0);
        ot1 = __builtin_amdgcn_mfma_f32_16x16x32_bf16(vf11, pk1.v, ot1, 0, 0, 0);

        __syncthreads();
        if (tile < 31) {
            int key0 = t >> 3, sl0 = t & 7;
            *(uint4*)&s_k[cur ^ 1][key0 * 128 + ((sl0 ^ (key0 & 7)) << 4)] = kr0;
            int c1 = t + 256, key1 = c1 >> 3, sl1 = c1 & 7;
            *(uint4*)&s_k[cur ^ 1][key1 * 128 + ((sl1 ^ (key1 & 7)) << 4)] = kr1;
            *(uint4*)&s_v[cur ^ 1][vrow * 128 + ((vch ^ (vrow & 7)) << 4)] = vr0;
        }
        __syncthreads();
    }

    float* op = (split == 0 ? opart0 : opart1) + (size_t)(q0 + w*16 + r) * DIM + head*DKH;
    *(float4*)(op + 4*g)      = make_float4(ot0[0], ot0[1], ot0[2], ot0[3]);
    *(float4*)(op + 16 + 4*g) = make_float4(ot1[0], ot1[1], ot1[2], ot1[3]);
    if (g == 0) {
        float* mp = &mlbuf[(((size_t)split * NHEAD + head) * N_NODES + q0 + w*16 + r) * 2];
        mp[0] = m; mp[1] = l;
    }
}

// ---------------- attention split merge ----------------
__global__ __launch_bounds__(256) void k_attn_merge(
    const float* __restrict__ o0, const float* __restrict__ o1,
    const float* __restrict__ ml, float* __restrict__ A)
{
    int i = blockIdx.x * 256 + threadIdx.x;
    int qq = i >> 8, head = (i & 255) >> 5;
    const float* p0 = &ml[((size_t)head * N_NODES + qq) * 2];
    const float* p1 = &ml[(((size_t)NHEAD + head) * N_NODES + qq) * 2];
    float m0 = p0[0], l0 = p0[1], m1 = p1[0], l1 = p1[1];
    float mm = fmaxf(m0, m1);
    float e0 = __expf(m0 - mm), e1 = __expf(m1 - mm);
    float inv = 1.f / (e0 * l0 + e1 * l1);
    A[i] = (o0[i] * e0 + o1[i] * e1) * inv;
}

// ---------------- graph readout ----------------
__global__ __launch_bounds__(256) void k_segsum(const float* __restrict__ h,
                                                const int* __restrict__ batch,
                                                float* __restrict__ gbuf) {
    int i = blockIdx.x * 256 + threadIdx.x;
    int n = i >> 8, d = i & 255;
    atomicAdd(&gbuf[batch[n] * DIM + d], h[i]);
}

__global__ __launch_bounds__(256) void k_head2(const float* __restrict__ gmid,
                                               const float* __restrict__ w2,
                                               const float* __restrict__ b2,
                                               float* __restrict__ out) {
    int t = threadIdx.x, lane = t & 63, w = t >> 6;
    int g = blockIdx.x * 4 + w;
    float4 x  = *(const float4*)&gmid[g * DIM + lane * 4];
    float4 ww = *(const float4*)&w2[lane * 4];
    float s = x.x * ww.x + x.y * ww.y + x.z * ww.z + x.w * ww.w;
    #pragma unroll
    for (int off = 32; off; off >>= 1) s += __shfl_xor(s, off, 64);
    if (lane == 0) out[g] = s + b2[0];
}

extern "C" void kernel_launch(void* const* d_in, const int* in_sizes, int n_in,
                              void* d_out, int out_size, void* d_ws, size_t ws_size,
                              hipStream_t stream)
{
    const int*   z     = (const int*)d_in[0];
    const float* pos   = (const float*)d_in[1];
    const int*   batch = (const int*)d_in[2];
    const int*   ei    = (const int*)d_in[3];
    const float* emb   = (const float*)d_in[4];
    const float* ew1   = (const float*)d_in[5];
    const float* eb1   = (const float*)d_in[6];
    const float* ew2   = (const float*)d_in[7];
    const float* eb2   = (const float*)d_in[8];
    const float* nw1   = (const float*)d_in[9];
    const float* nb1   = (const float*)d_in[10];
    const float* nw2   = (const float*)d_in[11];
    const float* nb2   = (const float*)d_in[12];
    const float* aw    = (const float*)d_in[13];
    const float* ab    = (const float*)d_in[14];
    const float* wq    = (const float*)d_in[15];
    const float* bq    = (const float*)d_in[16];
    const float* wk    = (const float*)d_in[17];
    const float* bk    = (const float*)d_in[18];
    const float* wv    = (const float*)d_in[19];
    const float* bv    = (const float*)d_in[20];
    const float* wo    = (const float*)d_in[21];
    const float* bo    = (const float*)d_in[22];
    const float* ln1g  = (const float*)d_in[23];
    const float* ln1b  = (const float*)d_in[24];
    const float* fw1   = (const float*)d_in[25];
    const float* fb1   = (const float*)d_in[26];
    const float* fw2   = (const float*)d_in[27];
    const float* fb2   = (const float*)d_in[28];
    const float* ln2g  = (const float*)d_in[29];
    const float* ln2b  = (const float*)d_in[30];
    const float* fcw1  = (const float*)d_in[31];
    const float* fcb1  = (const float*)d_in[32];
    const float* fcw2  = (const float*)d_in[33];
    const float* fcb2  = (const float*)d_in[34];
    float* out = (float*)d_out;

    float* ws = (float*)d_ws;
    const size_t ND = (size_t)N_NODES * DIM;
    float* h    = ws;
    float* agg  = ws + ND;            // EGNN agg / attn ml partials
    float* A    = ws + 2 * ND;        // attn-out / node-mid
    float* U    = ws + 3 * ND;        // P12 fp32 [N,512] (EGNN) / q fp32 (enc)
    float* op0  = ws + 4 * ND;        // attn O partial split 0 (enc; free half of U region)
    float* op1  = ws + 5 * ND;        // attn O partial split 1
    float* Bffn = ws + 6 * ND;        // ffn-mid [N,512]; kpk/vpk alias
    unsigned short* kpk = (unsigned short*)Bffn;
    unsigned short* vpk = kpk + (size_t)NHEAD * N_NODES * 64;
    float* radial = Bffn + (3 * ND) / 2;
    int*   cnt    = (int*)(radial + N_EDGES);
    int*   pcur   = cnt + N_NODES;
    float* gbuf   = ws + 8 * ND;
    float* gmid   = gbuf + (size_t)NG * DIM;
    float* rad_s  = gmid + (size_t)NG * DIM;
    int*   rows_s = (int*)(rad_s + N_EDGES);
    int*   cols_s = rows_s + N_EDGES;
    unsigned short* W2F   = (unsigned short*)(cols_s + N_EDGES);
    unsigned short* packs = W2F + (size_t)NL * 65536;

    unsigned short* PK_W1   = packs;
    unsigned short* PK_NW1  = packs + 524288;
    unsigned short* PK_NW2  = packs + 1048576;
    unsigned short* PK_QKV  = packs + 1310720;
    unsigned short* PK_WO   = packs + 1703936;
    unsigned short* PK_FFN1 = packs + 1835008;
    unsigned short* PK_FFN2 = packs + 2097152;

    dim3 b256(256);

    k_embed<<<N_NODES * DIM / 256, b256, 0, stream>>>(z, emb, h);
    k_radial<<<N_EDGES / 256, b256, 0, stream>>>(pos, ei, radial);
    k_conv_w2<<<NL * 8192 / 256, b256, 0, stream>>>(ew2, W2F);
    k_pack_all<<<1152, b256, 0, stream>>>(ew1, nw1, nw2, wq, wk, wv, wo, fw1, fw2, packs);

    hipMemsetAsync(cnt, 0, N_NODES * sizeof(int), stream);
    k_hist<<<N_EDGES / 256, b256, 0, stream>>>(ei, cnt);
    k_scan<<<1, b256, 0, stream>>>(cnt, pcur);
    k_scatter<<<N_EDGES / 256, b256, 0, stream>>>(ei, radial, pcur, rows_s, cols_s, rad_s);

    for (int l = 0; l < NL; ++l) {
        hipMemsetAsync(agg, 0, ND * sizeof(float), stream);
        const float* W1l = ew1 + (size_t)l * 513 * DIM;
        k_gemm<1,512,2,0,0,0><<<512, b256, 0, stream>>>(h, nullptr, DIM,
            PK_W1 + (size_t)l * 131072, nullptr, nullptr, nullptr, nullptr, U,
            nullptr, nullptr);
        k_edge_mfma<<<N_EDGES / TE2, b256, 0, stream>>>(U, rows_s, cols_s, rad_s,
            W1l + (size_t)512 * DIM, eb1 + (size_t)l * DIM,
            W2F + (size_t)l * 65536, eb2 + (size_t)l * DIM,
            aw + (size_t)l * DIM, ab + l, agg);
        const float* nb1l = nb1 + (size_t)l * DIM;
        k_gemm<2,256,2,1,0,0><<<512, b256, 0, stream>>>(h, agg, DIM,
            PK_NW1 + (size_t)l * 131072, nb1l, nb1l, nb1l, nullptr, A,
            nullptr, nullptr);
        const float* nb2l = nb2 + (size_t)l * DIM;
        k_gemm<1,256,2,0,1,0><<<512, b256, 0, stream>>>(A, nullptr, DIM,
            PK_NW2 + (size_t)l * 65536, nb2l, nb2l, nb2l, h, h,
            nullptr, nullptr);
    }

    for (int i = 0; i < NENC; ++i) {
        k_gemm<1,768,3,0,0,1><<<768, b256, 0, stream>>>(h, nullptr, DIM,
            PK_QKV + (size_t)i * 196608,
            bq + (size_t)i * DIM, bk + (size_t)i * DIM, bv + (size_t)i * DIM, nullptr, U,
            kpk, vpk);
        dim3 ag(N_NODES / 64, NHEAD, 2);
        k_attn_mfma<<<ag, b256, 0, stream>>>(U, kpk, vpk, op0, op1, agg);
        k_attn_merge<<<N_NODES * DIM / 256, b256, 0, stream>>>(op0, op1, agg, A);
        const float* bol = bo + (size_t)i * DIM;
        k_gemm<1,256,2,0,1,0><<<512, b256, 0, stream>>>(A, nullptr, DIM,
            PK_WO + (size_t)i * 65536, bol, bol, bol, h, agg,
            nullptr, nullptr);
        k_ln<<<N_NODES / 4, b256, 0, stream>>>(agg, ln1g + (size_t)i * DIM, ln1b + (size_t)i * DIM, h);
        const float* fb1l = fb1 + (size_t)i * FFD;
        k_gemm<1,512,2,1,0,0><<<512, b256, 0, stream>>>(h, nullptr, DIM,
            PK_FFN1 + (size_t)i * 131072, fb1l, fb1l + 256, nullptr, nullptr, Bffn,
            nullptr, nullptr);
        const float* fb2l = fb2 + (size_t)i * DIM;
        k_gemm<2,256,2,0,1,0><<<512, b256, 0, stream>>>(Bffn, Bffn + 256, FFD,
            PK_FFN2 + (size_t)i * 131072, fb2l, fb2l, fb2l, h, agg,
            nullptr, nullptr);
        k_ln<<<N_NODES / 4, b256, 0, stream>>>(agg, ln2g + (size_t)i * DIM, ln2b + (size_t)i * DIM, h);
    }

    hipMemsetAsync(gbuf, 0, (size_t)NG * DIM * sizeof(float), stream);
    k_segsum<<<N_NODES * DIM / 256, b256, 0, stream>>>(h, batch, gbuf);
    k_mlp_small<1><<<NG / 16, b256, 0, stream>>>(gbuf, fcw1, fcb1, gmid);
    k_head2<<<NG / 4, b256, 0, stream>>>(gmid, fcw2, fcb2, out);
}

// Round 10
// 667.954 us; speedup vs baseline: 1.0171x; 1.0030x over previous
//
#include <hip/hip_runtime.h>
#include <math.h>

#define N_NODES 4096
#define N_EDGES 131072
#define DIM     256
#define NL      4
#define NENC    2
#define FFD     512
#define NG      128
#define NHEAD   8
#define DKH     32
#define TE2     32
#define NSPLIT_ATT 4

typedef __attribute__((ext_vector_type(8))) short bf16x8;
typedef __attribute__((ext_vector_type(4))) float f32x4;

__device__ __forceinline__ float siluf(float x) { return x / (1.f + __expf(-x)); }
__device__ __forceinline__ float sigmf_(float x) { return 1.f / (1.f + __expf(-x)); }
__device__ __forceinline__ unsigned short f2b(float f) {
    union { float f; unsigned u; } x; x.f = f;
    unsigned r = x.u + 0x7fffu + ((x.u >> 16) & 1u);
    return (unsigned short)(r >> 16);
}
__device__ __forceinline__ float b2f(unsigned short h) {
    union { unsigned u; float f; } x; x.u = (unsigned)h << 16; return x.f;
}

// ---------------- embedding ----------------
__global__ __launch_bounds__(256) void k_embed(const int* __restrict__ z,
                                               const float* __restrict__ emb,
                                               float* __restrict__ h) {
    int i = blockIdx.x * 256 + threadIdx.x;
    int n = i >> 8, d = i & 255;
    h[i] = emb[z[n] * DIM + d];
}

// ---------------- radial ----------------
__global__ __launch_bounds__(256) void k_radial(const float* __restrict__ pos,
                                                const int* __restrict__ ei,
                                                float* __restrict__ radial) {
    int e = blockIdx.x * 256 + threadIdx.x;
    if (e >= N_EDGES) return;
    int r = ei[e], c = ei[N_EDGES + e];
    float dx = pos[r*3+0] - pos[c*3+0];
    float dy = pos[r*3+1] - pos[c*3+1];
    float dz = pos[r*3+2] - pos[c*3+2];
    radial[e] = dx*dx + dy*dy + dz*dz;
}

// ---------------- edge counting sort (by row node) ----------------
__global__ __launch_bounds__(256) void k_hist(const int* __restrict__ ei, int* __restrict__ cnt) {
    int e = blockIdx.x * 256 + threadIdx.x;
    if (e < N_EDGES) atomicAdd(&cnt[ei[e]], 1);
}

__global__ __launch_bounds__(256) void k_scan(const int* __restrict__ cnt, int* __restrict__ pos) {
    __shared__ int s_w[4];
    int t = threadIdx.x, lane = t & 63, wv = t >> 6;
    int loc[16]; int s = 0;
    #pragma unroll
    for (int i = 0; i < 16; ++i) { loc[i] = s; s += cnt[t * 16 + i]; }
    int inc = s;
    #pragma unroll
    for (int off = 1; off < 64; off <<= 1) {
        int v = __shfl_up(inc, off, 64);
        if (lane >= off) inc += v;
    }
    if (lane == 63) s_w[wv] = inc;
    __syncthreads();
    int wbase = 0;
    for (int j = 0; j < wv; ++j) wbase += s_w[j];
    int base = wbase + inc - s;
    #pragma unroll
    for (int i = 0; i < 16; ++i) pos[t * 16 + i] = base + loc[i];
}

__global__ __launch_bounds__(256) void k_scatter(const int* __restrict__ ei,
                                                 const float* __restrict__ radial,
                                                 int* __restrict__ pos,
                                                 int* __restrict__ rows_s,
                                                 int* __restrict__ cols_s,
                                                 float* __restrict__ rad_s) {
    int e = blockIdx.x * 256 + threadIdx.x;
    if (e >= N_EDGES) return;
    int r = ei[e];
    int p = atomicAdd(&pos[r], 1);
    rows_s[p] = r;
    cols_s[p] = ei[N_EDGES + e];
    rad_s[p] = radial[e];
}

// ---------------- W2 -> bf16 MFMA-fragment-linear pack (edge GEMM2) ----------------
__global__ __launch_bounds__(256) void k_conv_w2(const float* __restrict__ ew2,
                                                 unsigned short* __restrict__ W2F) {
    int tid = blockIdx.x * 256 + threadIdx.x;
    int layer = tid >> 13;
    int r = tid & 8191;
    int ks = r >> 10, ntg = (r >> 6) & 15, lane = r & 63;
    const float* W = ew2 + (size_t)layer * 65536;
    unsigned short tmp[8];
    #pragma unroll
    for (int j = 0; j < 8; ++j) {
        int k = ks*32 + 4*(lane>>4) + (j&3) + 16*(j>>2);
        int n = ntg*16 + (lane&15);
        tmp[j] = f2b(W[k*256 + n]);
    }
    *(bf16x8*)&W2F[(size_t)layer*65536 + (size_t)r*8] = *(const bf16x8*)&tmp[0];
}

// ---------------- batched pack of ALL dense weights -> fragment-linear bf16 ----------------
__global__ __launch_bounds__(256) void k_pack_all(
    const float* __restrict__ ew1, const float* __restrict__ nw1, const float* __restrict__ nw2,
    const float* __restrict__ wq, const float* __restrict__ wk, const float* __restrict__ wv,
    const float* __restrict__ wo, const float* __restrict__ fw1, const float* __restrict__ fw2,
    unsigned short* __restrict__ dst)
{
    int f = blockIdx.x * 256 + threadIdx.x;
    int rem, panel, NTG, mode;
    if (f < 65536)       { rem = f;          panel = rem / 16384; rem &= 16383; NTG = 32; mode = 0; }
    else if (f < 131072) { rem = f - 65536;  panel = rem / 16384; rem &= 16383; NTG = 16; mode = 1; }
    else if (f < 163840) { rem = f - 131072; panel = rem / 8192;  rem &= 8191;  NTG = 16; mode = 2; }
    else if (f < 212992) { rem = f - 163840; panel = rem / 24576; rem %= 24576; NTG = 48; mode = 3; }
    else if (f < 229376) { rem = f - 212992; panel = rem / 8192;  rem &= 8191;  NTG = 16; mode = 4; }
    else if (f < 262144) { rem = f - 229376; panel = rem / 16384; rem &= 16383; NTG = 32; mode = 5; }
    else                 { rem = f - 262144; panel = rem / 16384; rem &= 16383; NTG = 16; mode = 6; }
    int ks   = rem / (NTG * 64);
    int ntg  = (rem >> 6) % NTG;
    int lane = rem & 63;
    unsigned short tmp[8];
    #pragma unroll
    for (int j = 0; j < 8; ++j) {
        int k = ks*32 + 4*(lane>>4) + (j&3) + 16*(j>>2);
        int n = ntg*16 + (lane&15);
        float val;
        switch (mode) {
            case 0: val = ew1[(size_t)panel*131328 + (n < 256 ? k*256 + n : (256 + k)*256 + (n - 256))]; break;
            case 1: val = nw1[(size_t)panel*131072 + k*256 + n]; break;
            case 2: val = nw2[(size_t)panel*65536 + k*256 + n]; break;
            case 3: { const float* b = (n < 256) ? wq : ((n < 512) ? wk : wv);
                      val = b[(size_t)panel*65536 + k*256 + (n & 255)]; } break;
            case 4: val = wo[(size_t)panel*65536 + k*256 + n]; break;
            case 5: val = fw1[(size_t)panel*131072 + k*512 + n]; break;
            default: val = fw2[(size_t)panel*131072 + k*256 + n]; break;
        }
        tmp[j] = f2b(val);
    }
    *(bf16x8*)&dst[(size_t)f * 8] = *(const bf16x8*)&tmp[0];
}

// ---------------- generic split-bf16 MFMA GEMM ----------------
// OUTMODE 0: fp32 C. OUTMODE 1 (QKV): q fp32 | kpk frag hi/lo | vpk frag V^T.
template<int NCHUNK, int NC, int NSPLIT, int ACT, int RESID, int OUTMODE>
__global__ __launch_bounds__(256) void k_gemm(
    const float* __restrict__ A0, const float* __restrict__ A1, int lda,
    const unsigned short* __restrict__ Wp,
    const float* __restrict__ b0, const float* __restrict__ b1, const float* __restrict__ b2,
    const float* __restrict__ resid, float* __restrict__ C,
    unsigned short* __restrict__ kpk, unsigned short* __restrict__ vpk)
{
    constexpr int NT  = NC / (64 * NSPLIT);
    constexpr int NTG = NC / 16;
    __shared__ __align__(16) char s_hi[16 * 512];
    __shared__ __align__(16) char s_lo[16 * 512];
    const int t = threadIdx.x, l = t & 63, w = t >> 6;
    const int g = l >> 4, r = l & 15;
    const int mtile  = blockIdx.x % 256;
    const int nchunk = blockIdx.x / 256;
    const int r0 = mtile * 16;

    f32x4 acc[NT];
    #pragma unroll
    for (int nt = 0; nt < NT; ++nt) acc[nt] = (f32x4){0.f, 0.f, 0.f, 0.f};

    const bf16x8* Wf = (const bf16x8*)Wp;
    for (int c = 0; c < NCHUNK; ++c) {
        const float* Ac = (c == 0) ? A0 : A1;
        __syncthreads();
        const int c4 = l * 4;
        #pragma unroll
        for (int it = 0; it < 4; ++it) {
            int row = it * 4 + w;
            float4 v = *(const float4*)&Ac[(size_t)(r0 + row) * lda + c4];
            float vv[4] = {v.x, v.y, v.z, v.w};
            ushort4 h4, l4;
            unsigned short hh;
            hh = f2b(vv[0]); h4.x = hh; l4.x = f2b(vv[0] - b2f(hh));
            hh = f2b(vv[1]); h4.y = hh; l4.y = f2b(vv[1] - b2f(hh));
            hh = f2b(vv[2]); h4.z = hh; l4.z = f2b(vv[2] - b2f(hh));
            hh = f2b(vv[3]); h4.w = hh; l4.w = f2b(vv[3] - b2f(hh));
            int boff = (c4 * 2) ^ (row << 3);
            *(ushort4*)&s_hi[row * 512 + boff] = h4;
            *(ushort4*)&s_lo[row * 512 + boff] = l4;
        }
        __syncthreads();
        #pragma unroll
        for (int ks = 0; ks < 8; ++ks) {
            const int ksg = c * 8 + ks;
            const int x0 = (ks * 64 + 8 * g) ^ (r << 3);
            union { uint2 u[2]; bf16x8 v; } ah, al;
            ah.u[0] = *(const uint2*)&s_hi[r * 512 + x0];
            ah.u[1] = *(const uint2*)&s_hi[r * 512 + (x0 ^ 32)];
            al.u[0] = *(const uint2*)&s_lo[r * 512 + x0];
            al.u[1] = *(const uint2*)&s_lo[r * 512 + (x0 ^ 32)];
            #pragma unroll
            for (int nt = 0; nt < NT; ++nt) {
                int fb = (nchunk * 4 + w) * NT + nt;
                bf16x8 bf_ = Wf[(size_t)(ksg * NTG + fb) * 64 + l];
                acc[nt] = __builtin_amdgcn_mfma_f32_16x16x32_bf16(ah.v, bf_, acc[nt], 0, 0, 0);
                acc[nt] = __builtin_amdgcn_mfma_f32_16x16x32_bf16(al.v, bf_, acc[nt], 0, 0, 0);
            }
        }
    }
    #pragma unroll
    for (int nt = 0; nt < NT; ++nt) {
        int n = ((nchunk * 4 + w) * NT + nt) * 16 + r;
        float bias = 0.f;
        if (b0) {
            const float* bp = (n < 256) ? b0 : ((n < 512) ? b1 : b2);
            bias = bp[n & 255];
        }
        #pragma unroll
        for (int reg = 0; reg < 4; ++reg) {
            int row = r0 + g * 4 + reg;
            float v = acc[nt][reg] + bias;
            if (ACT == 1) v = siluf(v);
            if (RESID) v += resid[(size_t)row * 256 + n];
            if (OUTMODE == 0) {
                C[(size_t)row * NC + n] = v;
            } else {
                if (n < 256) {
                    C[(size_t)row * 256 + n] = v;             // q, fp32
                } else if (n < 512) {
                    int hd = (n - 256) >> 5, dm = (n - 256) & 31;
                    int dp = (dm & 3) | (((dm >> 4) & 1) << 2) | (((dm >> 2) & 3) << 3);
                    unsigned short hb = f2b(v);
                    size_t base = ((size_t)hd * N_NODES + row) * 64;
                    kpk[base + dp]      = hb;
                    kpk[base + 32 + dp] = f2b(v - b2f(hb));
                } else {
                    int hd = (n - 512) >> 5, dm = (n - 512) & 31;
                    int s = row & 31;
                    int sp = (s & 3) | (((s >> 4) & 1) << 2) | (((s >> 2) & 3) << 3);
                    int keyp = (row & ~31) | sp;
                    vpk[((size_t)hd * 32 + dm) * N_NODES + keyp] = f2b(v);
                }
            }
        }
    }
}

// ---------------- fused edge kernel (32 edges/block, fp32 P12, vectorized dedup) ----------------
__global__ __launch_bounds__(256) void k_edge_mfma(
    const float* __restrict__ P12,
    const int* __restrict__ rows_s, const int* __restrict__ cols_s,
    const float* __restrict__ rad_s,
    const float* __restrict__ w1r, const float* __restrict__ b1,
    const unsigned short* __restrict__ W2F, const float* __restrict__ b2,
    const float* __restrict__ aw, const float* __restrict__ ab,
    float* __restrict__ agg)
{
    __shared__ __align__(16) char s_a[20480];
    __shared__ int   s_row[TE2], s_cn[TE2];
    __shared__ float s_rad[TE2], s_gp[4][TE2], s_gate[TE2];
    const int t = threadIdx.x, l = t & 63, w = t >> 6;
    const int e0 = blockIdx.x * TE2;

    if (t < TE2) {
        s_row[t] = rows_s[e0 + t];
        s_cn[t]  = cols_s[e0 + t];
        s_rad[t] = rad_s[e0 + t];
    }
    __syncthreads();

    const int c4 = l * 4;
    const float4 wr = *(const float4*)&w1r[c4];
    const float4 bb = *(const float4*)&b1[c4];
    #pragma unroll
    for (int it = 0; it < 8; ++it) {
        int e = it * 4 + w;
        float4 pa = *(const float4*)&P12[(size_t)s_row[e] * 512 + c4];
        float4 pb = *(const float4*)&P12[(size_t)s_cn[e] * 512 + 256 + c4];
        float rad = s_rad[e];
        ushort4 pk;
        pk.x = f2b(siluf(pa.x + pb.x + rad * wr.x + bb.x));
        pk.y = f2b(siluf(pa.y + pb.y + rad * wr.y + bb.y));
        pk.z = f2b(siluf(pa.z + pb.z + rad * wr.z + bb.z));
        pk.w = f2b(siluf(pa.w + pb.w + rad * wr.w + bb.w));
        *(ushort4*)&s_a[e * 512 + ((c4 * 2) ^ ((e & 15) << 3))] = pk;
    }
    __syncthreads();

    const int g = l >> 4, r = l & 15;
    f32x4 acc[2][4];
    #pragma unroll
    for (int mt = 0; mt < 2; ++mt)
        #pragma unroll
        for (int nt = 0; nt < 4; ++nt)
            acc[mt][nt] = (f32x4){0.f, 0.f, 0.f, 0.f};

    const bf16x8* Wf = (const bf16x8*)W2F;
    for (int ks = 0; ks < 8; ++ks) {
        bf16x8 af[2], bfr[4];
        #pragma unroll
        for (int mt = 0; mt < 2; ++mt) {
            int rowa = mt * 16 + r;
            int x0 = (ks * 64 + 8 * g) ^ (r << 3);
            uint2 lo = *(const uint2*)&s_a[rowa * 512 + x0];
            uint2 hi = *(const uint2*)&s_a[rowa * 512 + (x0 ^ 32)];
            union { uint2 u[2]; bf16x8 v; } ua;
            ua.u[0] = lo; ua.u[1] = hi;
            af[mt] = ua.v;
        }
        #pragma unroll
        for (int nt = 0; nt < 4; ++nt)
            bfr[nt] = Wf[(ks * 16 + w * 4 + nt) * 64 + l];
        #pragma unroll
        for (int mt = 0; mt < 2; ++mt)
            #pragma unroll
            for (int nt = 0; nt < 4; ++nt)
                acc[mt][nt] = __builtin_amdgcn_mfma_f32_16x16x32_bf16(af[mt], bfr[nt], acc[mt][nt], 0, 0, 0);
    }

    float b2v[4], awv[4];
    #pragma unroll
    for (int nt = 0; nt < 4; ++nt) {
        int col = w * 64 + nt * 16 + r;
        b2v[nt] = b2[col];
        awv[nt] = aw[col];
    }
    float pg[2][4];
    #pragma unroll
    for (int mt = 0; mt < 2; ++mt)
        #pragma unroll
        for (int reg = 0; reg < 4; ++reg) {
            float s = 0.f;
            #pragma unroll
            for (int nt = 0; nt < 4; ++nt) {
                float v = siluf(acc[mt][nt][reg] + b2v[nt]);
                acc[mt][nt][reg] = v;
                s += v * awv[nt];
            }
            pg[mt][reg] = s;
        }
    #pragma unroll
    for (int off = 1; off < 16; off <<= 1)
        #pragma unroll
        for (int mt = 0; mt < 2; ++mt)
            #pragma unroll
            for (int reg = 0; reg < 4; ++reg)
                pg[mt][reg] += __shfl_xor(pg[mt][reg], off, 64);
    if (r == 0) {
        #pragma unroll
        for (int mt = 0; mt < 2; ++mt)
            #pragma unroll
            for (int reg = 0; reg < 4; ++reg)
                s_gp[w][mt * 16 + g * 4 + reg] = pg[mt][reg];
    }
    __syncthreads();
    if (t < TE2)
        s_gate[t] = sigmf_(s_gp[0][t] + s_gp[1][t] + s_gp[2][t] + s_gp[3][t] + ab[0]);
    __syncthreads();

    unsigned short* s_out = (unsigned short*)s_a;
    #pragma unroll
    for (int mt = 0; mt < 2; ++mt) {
        float4 gt4 = *(const float4*)&s_gate[mt * 16 + g * 4];
        #pragma unroll
        for (int nt = 0; nt < 4; ++nt) {
            int col = w * 64 + nt * 16 + r;
            ushort4 o4;
            o4.x = f2b(acc[mt][nt][0] * gt4.x);
            o4.y = f2b(acc[mt][nt][1] * gt4.y);
            o4.z = f2b(acc[mt][nt][2] * gt4.z);
            o4.w = f2b(acc[mt][nt][3] * gt4.w);
            *(ushort4*)&s_out[col * 40 + mt * 16 + g * 4] = o4;
        }
    }
    __syncthreads();
    float cur = 0.f;
    #pragma unroll
    for (int c = 0; c < 4; ++c) {
        union { uint4 q; unsigned short s[8]; } ch;
        ch.q = *(const uint4*)&s_out[t * 40 + c * 8];
        #pragma unroll
        for (int j = 0; j < 8; ++j) {
            int e = c * 8 + j;
            cur += b2f(ch.s[j]);
            bool flush = (e == TE2 - 1) || (s_row[e + 1] != s_row[e]);
            if (flush) {
                atomicAdd(&agg[(size_t)s_row[e] * DIM + t], cur);
                cur = 0.f;
            }
        }
    }
}

// ---------------- tiny VALU MLP (readout head only, M=128) ----------------
template<int ACT>
__global__ __launch_bounds__(256) void k_mlp_small(
    const float* __restrict__ A1, const float* __restrict__ W,
    const float* __restrict__ bias, float* __restrict__ C)
{
    __shared__ float s_a[16][260];
    const int t  = threadIdx.x;
    const int r0 = blockIdx.x * 16;
    for (int r = 0; r < 16; ++r)
        s_a[r][t] = A1[(size_t)(r0 + r) * DIM + t];
    __syncthreads();
    const int er0 = (t >> 6) * 4;
    const int c0 = (t & 63) * 4;
    float acc[4][4];
    #pragma unroll
    for (int e = 0; e < 4; ++e)
        #pragma unroll
        for (int c = 0; c < 4; ++c) acc[e][c] = 0.f;
    #pragma unroll 2
    for (int k = 0; k < DIM; k += 4) {
        float4 w0 = *(const float4*)&W[(size_t)(k+0)*DIM + c0];
        float4 w1 = *(const float4*)&W[(size_t)(k+1)*DIM + c0];
        float4 w2 = *(const float4*)&W[(size_t)(k+2)*DIM + c0];
        float4 w3 = *(const float4*)&W[(size_t)(k+3)*DIM + c0];
        #pragma unroll
        for (int e = 0; e < 4; ++e) {
            float4 x = *(const float4*)&s_a[er0+e][k];
            acc[e][0] += x.x*w0.x + x.y*w1.x + x.z*w2.x + x.w*w3.x;
            acc[e][1] += x.x*w0.y + x.y*w1.y + x.z*w2.y + x.w*w3.y;
            acc[e][2] += x.x*w0.z + x.y*w1.z + x.z*w2.z + x.w*w3.z;
            acc[e][3] += x.x*w0.w + x.y*w1.w + x.z*w2.w + x.w*w3.w;
        }
    }
    float4 bb = *(const float4*)&bias[c0];
    #pragma unroll
    for (int e = 0; e < 4; ++e) {
        float v0 = acc[e][0] + bb.x, v1 = acc[e][1] + bb.y;
        float v2 = acc[e][2] + bb.z, v3 = acc[e][3] + bb.w;
        if (ACT == 1) { v0 = siluf(v0); v1 = siluf(v1); v2 = siluf(v2); v3 = siluf(v3); }
        float4 o; o.x = v0; o.y = v1; o.z = v2; o.w = v3;
        *(float4*)&C[(size_t)(r0 + er0 + e) * DIM + c0] = o;
    }
}

// ---------------- LayerNorm ----------------
__global__ __launch_bounds__(256) void k_ln(const float* __restrict__ x,
                                            const float* __restrict__ g,
                                            const float* __restrict__ b,
                                            float* __restrict__ out) {
    int t = threadIdx.x, lane = t & 63, w = t >> 6;
    int row = blockIdx.x * 4 + w;
    float4 v = *(const float4*)&x[(size_t)row * DIM + lane * 4];
    float s = v.x + v.y + v.z + v.w;
    #pragma unroll
    for (int off = 32; off; off >>= 1) s += __shfl_xor(s, off, 64);
    float mu = s * (1.f / 256.f);
    float dx = v.x - mu, dy = v.y - mu, dz = v.z - mu, dw = v.w - mu;
    float q = dx*dx + dy*dy + dz*dz + dw*dw;
    #pragma unroll
    for (int off = 32; off; off >>= 1) q += __shfl_xor(q, off, 64);
    float rs = rsqrtf(q * (1.f / 256.f) + 1e-5f);
    float4 gg = *(const float4*)&g[lane * 4];
    float4 bb = *(const float4*)&b[lane * 4];
    float4 o;
    o.x = dx * rs * gg.x + bb.x;
    o.y = dy * rs * gg.y + bb.y;
    o.z = dz * rs * gg.z + bb.z;
    o.w = dw * rs * gg.w + bb.w;
    *(float4*)&out[(size_t)row * DIM + lane * 4] = o;
}

// ---------------- MFMA flash attention v6: key-split x4, LDS dbuf, partial out ----------------
// grid (N/64, H, 4). Block: queries q0..q0+63, keys [split*1024, +1024) (16 tiles).
__global__ __launch_bounds__(256) void k_attn_mfma(
    const float* __restrict__ q,
    const unsigned short* __restrict__ kpk,
    const unsigned short* __restrict__ vpk,
    float* __restrict__ op0, float* __restrict__ op1,
    float* __restrict__ op2, float* __restrict__ op3,
    float* __restrict__ mlbuf)
{
    __shared__ __align__(16) char s_k[2][8192];
    __shared__ __align__(16) char s_v[2][4096];
    const int t = threadIdx.x, lane = t & 63, w = t >> 6;
    const int g = lane >> 4, r = lane & 15;
    const int head = blockIdx.y;
    const int split = blockIdx.z;
    const int q0 = blockIdx.x * 64;
    const float scale = 0.17677669529663687f;

    bf16x8 qh, ql;
    {
        const float* qp = &q[(size_t)(q0 + w*16 + r) * DIM + head*DKH + 4*g];
        float4 f0 = *(const float4*)qp;
        float4 f1 = *(const float4*)(qp + 16);
        float vv[8] = {f0.x, f0.y, f0.z, f0.w, f1.x, f1.y, f1.z, f1.w};
        union { unsigned short s[8]; bf16x8 v; } uh, ul;
        #pragma unroll
        for (int j = 0; j < 8; ++j) {
            float sv = vv[j] * scale;
            unsigned short hb = f2b(sv);
            uh.s[j] = hb;
            ul.s[j] = f2b(sv - b2f(hb));
        }
        qh = uh.v; ql = ul.v;
    }

    const char* kbase = (const char*)(kpk + (size_t)head * N_NODES * 64) + (size_t)split * 16 * 8192;
    const unsigned short* vbase = vpk + (size_t)head * 32 * N_NODES;
    const int koff = split * 1024;
    const int vrow = t >> 3, vch = t & 7;

    uint4 kr0, kr1, vr0;
    {
        const char* kt = kbase;
        kr0 = *(const uint4*)(kt + t * 16);
        kr1 = *(const uint4*)(kt + 4096 + t * 16);
        vr0 = *(const uint4*)(vbase + (size_t)vrow * N_NODES + koff + vch * 8);
        int key0 = t >> 3, sl0 = t & 7;
        *(uint4*)&s_k[0][key0 * 128 + ((sl0 ^ (key0 & 7)) << 4)] = kr0;
        int c1 = t + 256, key1 = c1 >> 3, sl1 = c1 & 7;
        *(uint4*)&s_k[0][key1 * 128 + ((sl1 ^ (key1 & 7)) << 4)] = kr1;
        *(uint4*)&s_v[0][vrow * 128 + ((vch ^ (vrow & 7)) << 4)] = vr0;
    }
    __syncthreads();

    float m = -1e30f, l = 0.f;
    f32x4 ot0 = (f32x4){0.f,0.f,0.f,0.f}, ot1 = (f32x4){0.f,0.f,0.f,0.f};

    for (int tile = 0; tile < 16; ++tile) {
        const int cur = tile & 1;
        if (tile < 15) {
            const char* kt = kbase + (size_t)(tile + 1) * 8192;
            kr0 = *(const uint4*)(kt + t * 16);
            kr1 = *(const uint4*)(kt + 4096 + t * 16);
            vr0 = *(const uint4*)(vbase + (size_t)vrow * N_NODES + koff + (tile + 1) * 64 + vch * 8);
        }
        bf16x8 kh[4], kl[4];
        #pragma unroll
        for (int kb = 0; kb < 4; ++kb) {
            int key = kb * 16 + r;
            kh[kb] = *(const bf16x8*)&s_k[cur][key * 128 + ((g ^ (r & 7)) << 4)];
            kl[kb] = *(const bf16x8*)&s_k[cur][key * 128 + (((4 + g) ^ (r & 7)) << 4)];
        }
        f32x4 sc[4];
        #pragma unroll
        for (int kb = 0; kb < 4; ++kb) {
            f32x4 a = (f32x4){0.f,0.f,0.f,0.f};
            a = __builtin_amdgcn_mfma_f32_16x16x32_bf16(kh[kb], qh, a, 0, 0, 0);
            a = __builtin_amdgcn_mfma_f32_16x16x32_bf16(kh[kb], ql, a, 0, 0, 0);
            a = __builtin_amdgcn_mfma_f32_16x16x32_bf16(kl[kb], qh, a, 0, 0, 0);
            sc[kb] = a;
        }
        float tm = -1e30f;
        #pragma unroll
        for (int kb = 0; kb < 4; ++kb)
            #pragma unroll
            for (int e = 0; e < 4; ++e) tm = fmaxf(tm, sc[kb][e]);
        tm = fmaxf(tm, __shfl_xor(tm, 16, 64));
        tm = fmaxf(tm, __shfl_xor(tm, 32, 64));
        float nm = fmaxf(m, tm);
        float scf = __expf(m - nm);
        m = nm;
        float p[16]; float ls = 0.f;
        #pragma unroll
        for (int kb = 0; kb < 4; ++kb)
            #pragma unroll
            for (int e = 0; e < 4; ++e) {
                float pe = __expf(sc[kb][e] - nm);
                p[kb*4+e] = pe; ls += pe;
            }
        ls += __shfl_xor(ls, 16, 64);
        ls += __shfl_xor(ls, 32, 64);
        l = l * scf + ls;
        ot0[0] *= scf; ot0[1] *= scf; ot0[2] *= scf; ot0[3] *= scf;
        ot1[0] *= scf; ot1[1] *= scf; ot1[2] *= scf; ot1[3] *= scf;
        union { unsigned short s[8]; bf16x8 v; } pk0, pk1;
        #pragma unroll
        for (int j = 0; j < 8; ++j) {
            pk0.s[j] = f2b(p[(j >> 2) * 4 + (j & 3)]);
            pk1.s[j] = f2b(p[(2 + (j >> 2)) * 4 + (j & 3)]);
        }
        bf16x8 vf00 = *(const bf16x8*)&s_v[cur][(0*16 + r) * 128 + (((0*4 + g) ^ (r & 7)) << 4)];
        bf16x8 vf01 = *(const bf16x8*)&s_v[cur][(0*16 + r) * 128 + (((1*4 + g) ^ (r & 7)) << 4)];
        bf16x8 vf10 = *(const bf16x8*)&s_v[cur][(1*16 + r) * 128 + (((0*4 + g) ^ (r & 7)) << 4)];
        bf16x8 vf11 = *(const bf16x8*)&s_v[cur][(1*16 + r) * 128 + (((1*4 + g) ^ (r & 7)) << 4)];
        ot0 = __builtin_amdgcn_mfma_f32_16x16x32_bf16(vf00, pk0.v, ot0, 0, 0, 0);
        ot0 = __builtin_amdgcn_mfma_f32_16x16x32_bf16(vf01, pk1.v, ot0, 0, 0, 0);
        ot1 = __builtin_amdgcn_mfma_f32_16x16x32_bf16(vf10, pk0.v, ot1, 0, 0, 0);
        ot1 = __builtin_amdgcn_mfma_f32_16x16x32_bf16(vf11, pk1.v, ot1, 0, 0, 0);

        __syncthreads();
        if (tile < 15) {
            int key0 = t >> 3, sl0 = t & 7;
            *(uint4*)&s_k[cur ^ 1][key0 * 128 + ((sl0 ^ (key0 & 7)) << 4)] = kr0;
            int c1 = t + 256, key1 = c1 >> 3, sl1 = c1 & 7;
            *(uint4*)&s_k[cur ^ 1][key1 * 128 + ((sl1 ^ (key1 & 7)) << 4)] = kr1;
            *(uint4*)&s_v[cur ^ 1][vrow * 128 + ((vch ^ (vrow & 7)) << 4)] = vr0;
        }
        __syncthreads();
    }

    float* opsel = (split == 0) ? op0 : (split == 1) ? op1 : (split == 2) ? op2 : op3;
    float* op = opsel + (size_t)(q0 + w*16 + r) * DIM + head*DKH;
    *(float4*)(op + 4*g)      = make_float4(ot0[0], ot0[1], ot0[2], ot0[3]);
    *(float4*)(op + 16 + 4*g) = make_float4(ot1[0], ot1[1], ot1[2], ot1[3]);
    if (g == 0) {
        float* mp = &mlbuf[(((size_t)split * NHEAD + head) * N_NODES + q0 + w*16 + r) * 2];
        mp[0] = m; mp[1] = l;
    }
}

// ---------------- attention split merge (4-way, float4) ----------------
__global__ __launch_bounds__(256) void k_attn_merge(
    const float* __restrict__ o0, const float* __restrict__ o1,
    const float* __restrict__ o2, const float* __restrict__ o3,
    const float* __restrict__ ml, float* __restrict__ A)
{
    int i = blockIdx.x * 256 + threadIdx.x;   // float4 index
    int qq = (i * 4) >> 8;
    int head = ((i * 4) & 255) >> 5;
    float m_[4], l_[4];
    #pragma unroll
    for (int s = 0; s < 4; ++s) {
        const float* p = &ml[(((size_t)s * NHEAD + head) * N_NODES + qq) * 2];
        m_[s] = p[0]; l_[s] = p[1];
    }
    float mm = fmaxf(fmaxf(m_[0], m_[1]), fmaxf(m_[2], m_[3]));
    float e0 = __expf(m_[0] - mm), e1 = __expf(m_[1] - mm);
    float e2 = __expf(m_[2] - mm), e3 = __expf(m_[3] - mm);
    float inv = 1.f / (e0 * l_[0] + e1 * l_[1] + e2 * l_[2] + e3 * l_[3]);
    float4 a0 = ((const float4*)o0)[i];
    float4 a1 = ((const float4*)o1)[i];
    float4 a2 = ((const float4*)o2)[i];
    float4 a3 = ((const float4*)o3)[i];
    float4 o;
    o.x = (a0.x*e0 + a1.x*e1 + a2.x*e2 + a3.x*e3) * inv;
    o.y = (a0.y*e0 + a1.y*e1 + a2.y*e2 + a3.y*e3) * inv;
    o.z = (a0.z*e0 + a1.z*e1 + a2.z*e2 + a3.z*e3) * inv;
    o.w = (a0.w*e0 + a1.w*e1 + a2.w*e2 + a3.w*e3) * inv;
    ((float4*)A)[i] = o;
}

// ---------------- graph readout ----------------
__global__ __launch_bounds__(256) void k_segsum(const float* __restrict__ h,
                                                const int* __restrict__ batch,
                                                float* __restrict__ gbuf) {
    int i = blockIdx.x * 256 + threadIdx.x;
    int n = i >> 8, d = i & 255;
    atomicAdd(&gbuf[batch[n] * DIM + d], h[i]);
}

__global__ __launch_bounds__(256) void k_head2(const float* __restrict__ gmid,
                                               const float* __restrict__ w2,
                                               const float* __restrict__ b2,
                                               float* __restrict__ out) {
    int t = threadIdx.x, lane = t & 63, w = t >> 6;
    int g = blockIdx.x * 4 + w;
    float4 x  = *(const float4*)&gmid[g * DIM + lane * 4];
    float4 ww = *(const float4*)&w2[lane * 4];
    float s = x.x * ww.x + x.y * ww.y + x.z * ww.z + x.w * ww.w;
    #pragma unroll
    for (int off = 32; off; off >>= 1) s += __shfl_xor(s, off, 64);
    if (lane == 0) out[g] = s + b2[0];
}

extern "C" void kernel_launch(void* const* d_in, const int* in_sizes, int n_in,
                              void* d_out, int out_size, void* d_ws, size_t ws_size,
                              hipStream_t stream)
{
    const int*   z     = (const int*)d_in[0];
    const float* pos   = (const float*)d_in[1];
    const int*   batch = (const int*)d_in[2];
    const int*   ei    = (const int*)d_in[3];
    const float* emb   = (const float*)d_in[4];
    const float* ew1   = (const float*)d_in[5];
    const float* eb1   = (const float*)d_in[6];
    const float* ew2   = (const float*)d_in[7];
    const float* eb2   = (const float*)d_in[8];
    const float* nw1   = (const float*)d_in[9];
    const float* nb1   = (const float*)d_in[10];
    const float* nw2   = (const float*)d_in[11];
    const float* nb2   = (const float*)d_in[12];
    const float* aw    = (const float*)d_in[13];
    const float* ab    = (const float*)d_in[14];
    const float* wq    = (const float*)d_in[15];
    const float* bq    = (const float*)d_in[16];
    const float* wk    = (const float*)d_in[17];
    const float* bk    = (const float*)d_in[18];
    const float* wv    = (const float*)d_in[19];
    const float* bv    = (const float*)d_in[20];
    const float* wo    = (const float*)d_in[21];
    const float* bo    = (const float*)d_in[22];
    const float* ln1g  = (const float*)d_in[23];
    const float* ln1b  = (const float*)d_in[24];
    const float* fw1   = (const float*)d_in[25];
    const float* fb1   = (const float*)d_in[26];
    const float* fw2   = (const float*)d_in[27];
    const float* fb2   = (const float*)d_in[28];
    const float* ln2g  = (const float*)d_in[29];
    const float* ln2b  = (const float*)d_in[30];
    const float* fcw1  = (const float*)d_in[31];
    const float* fcb1  = (const float*)d_in[32];
    const float* fcw2  = (const float*)d_in[33];
    const float* fcb2  = (const float*)d_in[34];
    float* out = (float*)d_out;

    float* ws = (float*)d_ws;
    const size_t ND = (size_t)N_NODES * DIM;
    float* h    = ws;
    float* agg  = ws + ND;            // EGNN agg / attn op3 / WO out
    float* A    = ws + 2 * ND;        // node-mid / attn op2 + merge dest
    float* U    = ws + 3 * ND;        // P12 fp32 [N,512] (EGNN) / q fp32 (enc)
    float* op0  = ws + 4 * ND;
    float* op1  = ws + 5 * ND;
    float* Bffn = ws + 6 * ND;        // ffn-mid [N,512]; kpk/vpk alias
    unsigned short* kpk = (unsigned short*)Bffn;
    unsigned short* vpk = kpk + (size_t)NHEAD * N_NODES * 64;
    float* radial = Bffn + (3 * ND) / 2;
    int*   cnt    = (int*)(radial + N_EDGES);
    int*   pcur   = cnt + N_NODES;
    float* gbuf   = ws + 8 * ND;
    float* gmid   = gbuf + (size_t)NG * DIM;
    float* rad_s  = gmid + (size_t)NG * DIM;
    int*   rows_s = (int*)(rad_s + N_EDGES);
    int*   cols_s = rows_s + N_EDGES;
    unsigned short* W2F   = (unsigned short*)(cols_s + N_EDGES);
    unsigned short* packs = W2F + (size_t)NL * 65536;
    float* mlbuf = rad_s;             // dead after EGNN loop; 4*8*4096*2 = 262144 floats

    unsigned short* PK_W1   = packs;
    unsigned short* PK_NW1  = packs + 524288;
    unsigned short* PK_NW2  = packs + 1048576;
    unsigned short* PK_QKV  = packs + 1310720;
    unsigned short* PK_WO   = packs + 1703936;
    unsigned short* PK_FFN1 = packs + 1835008;
    unsigned short* PK_FFN2 = packs + 2097152;

    dim3 b256(256);

    k_embed<<<N_NODES * DIM / 256, b256, 0, stream>>>(z, emb, h);
    k_radial<<<N_EDGES / 256, b256, 0, stream>>>(pos, ei, radial);
    k_conv_w2<<<NL * 8192 / 256, b256, 0, stream>>>(ew2, W2F);
    k_pack_all<<<1152, b256, 0, stream>>>(ew1, nw1, nw2, wq, wk, wv, wo, fw1, fw2, packs);

    hipMemsetAsync(cnt, 0, N_NODES * sizeof(int), stream);
    k_hist<<<N_EDGES / 256, b256, 0, stream>>>(ei, cnt);
    k_scan<<<1, b256, 0, stream>>>(cnt, pcur);
    k_scatter<<<N_EDGES / 256, b256, 0, stream>>>(ei, radial, pcur, rows_s, cols_s, rad_s);

    for (int l = 0; l < NL; ++l) {
        hipMemsetAsync(agg, 0, ND * sizeof(float), stream);
        const float* W1l = ew1 + (size_t)l * 513 * DIM;
        k_gemm<1,512,2,0,0,0><<<512, b256, 0, stream>>>(h, nullptr, DIM,
            PK_W1 + (size_t)l * 131072, nullptr, nullptr, nullptr, nullptr, U,
            nullptr, nullptr);
        k_edge_mfma<<<N_EDGES / TE2, b256, 0, stream>>>(U, rows_s, cols_s, rad_s,
            W1l + (size_t)512 * DIM, eb1 + (size_t)l * DIM,
            W2F + (size_t)l * 65536, eb2 + (size_t)l * DIM,
            aw + (size_t)l * DIM, ab + l, agg);
        const float* nb1l = nb1 + (size_t)l * DIM;
        k_gemm<2,256,2,1,0,0><<<512, b256, 0, stream>>>(h, agg, DIM,
            PK_NW1 + (size_t)l * 131072, nb1l, nb1l, nb1l, nullptr, A,
            nullptr, nullptr);
        const float* nb2l = nb2 + (size_t)l * DIM;
        k_gemm<1,256,2,0,1,0><<<512, b256, 0, stream>>>(A, nullptr, DIM,
            PK_NW2 + (size_t)l * 65536, nb2l, nb2l, nb2l, h, h,
            nullptr, nullptr);
    }

    for (int i = 0; i < NENC; ++i) {
        k_gemm<1,768,3,0,0,1><<<768, b256, 0, stream>>>(h, nullptr, DIM,
            PK_QKV + (size_t)i * 196608,
            bq + (size_t)i * DIM, bk + (size_t)i * DIM, bv + (size_t)i * DIM, nullptr, U,
            kpk, vpk);
        dim3 ag(N_NODES / 64, NHEAD, NSPLIT_ATT);
        k_attn_mfma<<<ag, b256, 0, stream>>>(U, kpk, vpk, op0, op1, A, agg, mlbuf);
        k_attn_merge<<<N_NODES * DIM / 1024, b256, 0, stream>>>(op0, op1, A, agg, mlbuf, A);
        const float* bol = bo + (size_t)i * DIM;
        k_gemm<1,256,2,0,1,0><<<512, b256, 0, stream>>>(A, nullptr, DIM,
            PK_WO + (size_t)i * 65536, bol, bol, bol, h, agg,
            nullptr, nullptr);
        k_ln<<<N_NODES / 4, b256, 0, stream>>>(agg, ln1g + (size_t)i * DIM, ln1b + (size_t)i * DIM, h);
        const float* fb1l = fb1 + (size_t)i * FFD;
        k_gemm<1,512,2,1,0,0><<<512, b256, 0, stream>>>(h, nullptr, DIM,
            PK_FFN1 + (size_t)i * 131072, fb1l, fb1l + 256, nullptr, nullptr, Bffn,
            nullptr, nullptr);
        const float* fb2l = fb2 + (size_t)i * DIM;
        k_gemm<2,256,2,0,1,0><<<512, b256, 0, stream>>>(Bffn, Bffn + 256, FFD,
            PK_FFN2 + (size_t)i * 131072, fb2l, fb2l, fb2l, h, agg,
            nullptr, nullptr);
        k_ln<<<N_NODES / 4, b256, 0, stream>>>(agg, ln2g + (size_t)i * DIM, ln2b + (size_t)i * DIM, h);
    }

    hipMemsetAsync(gbuf, 0, (size_t)NG * DIM * sizeof(float), stream);
    k_segsum<<<N_NODES * DIM / 256, b256, 0, stream>>>(h, batch, gbuf);
    k_mlp_small<1><<<NG / 16, b256, 0, stream>>>(gbuf, fcw1, fcb1, gmid);
    k_head2<<<NG / 4, b256, 0, stream>>>(gmid, fcw2, fcb2, out);
}

// Round 11
// 655.147 us; speedup vs baseline: 1.0370x; 1.0195x over previous
//
#include <hip/hip_runtime.h>
#include <math.h>

#define N_NODES 4096
#define N_EDGES 131072
#define DIM     256
#define NL      4
#define NENC    2
#define FFD     512
#define NG      128
#define NHEAD   8
#define DKH     32
#define TE2     32
#define NSPLIT_ATT 4

typedef __attribute__((ext_vector_type(8))) short bf16x8;
typedef __attribute__((ext_vector_type(4))) float f32x4;

__device__ __forceinline__ float siluf(float x) { return x / (1.f + __expf(-x)); }
__device__ __forceinline__ float sigmf_(float x) { return 1.f / (1.f + __expf(-x)); }
__device__ __forceinline__ unsigned short f2b(float f) {
    union { float f; unsigned u; } x; x.f = f;
    unsigned r = x.u + 0x7fffu + ((x.u >> 16) & 1u);
    return (unsigned short)(r >> 16);
}
__device__ __forceinline__ float b2f(unsigned short h) {
    union { unsigned u; float f; } x; x.u = (unsigned)h << 16; return x.f;
}

// ---------------- embedding ----------------
__global__ __launch_bounds__(256) void k_embed(const int* __restrict__ z,
                                               const float* __restrict__ emb,
                                               float* __restrict__ h) {
    int i = blockIdx.x * 256 + threadIdx.x;
    int n = i >> 8, d = i & 255;
    h[i] = emb[z[n] * DIM + d];
}

// ---------------- radial ----------------
__global__ __launch_bounds__(256) void k_radial(const float* __restrict__ pos,
                                                const int* __restrict__ ei,
                                                float* __restrict__ radial) {
    int e = blockIdx.x * 256 + threadIdx.x;
    if (e >= N_EDGES) return;
    int r = ei[e], c = ei[N_EDGES + e];
    float dx = pos[r*3+0] - pos[c*3+0];
    float dy = pos[r*3+1] - pos[c*3+1];
    float dz = pos[r*3+2] - pos[c*3+2];
    radial[e] = dx*dx + dy*dy + dz*dz;
}

// ---------------- edge counting sort (by row node) ----------------
__global__ __launch_bounds__(256) void k_hist(const int* __restrict__ ei, int* __restrict__ cnt) {
    int e = blockIdx.x * 256 + threadIdx.x;
    if (e < N_EDGES) atomicAdd(&cnt[ei[e]], 1);
}

__global__ __launch_bounds__(256) void k_scan(const int* __restrict__ cnt, int* __restrict__ pos) {
    __shared__ int s_w[4];
    int t = threadIdx.x, lane = t & 63, wv = t >> 6;
    int loc[16]; int s = 0;
    #pragma unroll
    for (int i = 0; i < 16; ++i) { loc[i] = s; s += cnt[t * 16 + i]; }
    int inc = s;
    #pragma unroll
    for (int off = 1; off < 64; off <<= 1) {
        int v = __shfl_up(inc, off, 64);
        if (lane >= off) inc += v;
    }
    if (lane == 63) s_w[wv] = inc;
    __syncthreads();
    int wbase = 0;
    for (int j = 0; j < wv; ++j) wbase += s_w[j];
    int base = wbase + inc - s;
    #pragma unroll
    for (int i = 0; i < 16; ++i) pos[t * 16 + i] = base + loc[i];
}

__global__ __launch_bounds__(256) void k_scatter(const int* __restrict__ ei,
                                                 const float* __restrict__ radial,
                                                 int* __restrict__ pos,
                                                 int* __restrict__ rows_s,
                                                 int* __restrict__ cols_s,
                                                 float* __restrict__ rad_s) {
    int e = blockIdx.x * 256 + threadIdx.x;
    if (e >= N_EDGES) return;
    int r = ei[e];
    int p = atomicAdd(&pos[r], 1);
    rows_s[p] = r;
    cols_s[p] = ei[N_EDGES + e];
    rad_s[p] = radial[e];
}

// ---------------- W2 -> bf16 MFMA-fragment-linear pack (edge GEMM2) ----------------
__global__ __launch_bounds__(256) void k_conv_w2(const float* __restrict__ ew2,
                                                 unsigned short* __restrict__ W2F) {
    int tid = blockIdx.x * 256 + threadIdx.x;
    int layer = tid >> 13;
    int r = tid & 8191;
    int ks = r >> 10, ntg = (r >> 6) & 15, lane = r & 63;
    const float* W = ew2 + (size_t)layer * 65536;
    unsigned short tmp[8];
    #pragma unroll
    for (int j = 0; j < 8; ++j) {
        int k = ks*32 + 4*(lane>>4) + (j&3) + 16*(j>>2);
        int n = ntg*16 + (lane&15);
        tmp[j] = f2b(W[k*256 + n]);
    }
    *(bf16x8*)&W2F[(size_t)layer*65536 + (size_t)r*8] = *(const bf16x8*)&tmp[0];
}

// ---------------- batched pack of ALL dense weights -> fragment-linear bf16 ----------------
__global__ __launch_bounds__(256) void k_pack_all(
    const float* __restrict__ ew1, const float* __restrict__ nw1, const float* __restrict__ nw2,
    const float* __restrict__ wq, const float* __restrict__ wk, const float* __restrict__ wv,
    const float* __restrict__ wo, const float* __restrict__ fw1, const float* __restrict__ fw2,
    unsigned short* __restrict__ dst)
{
    int f = blockIdx.x * 256 + threadIdx.x;
    int rem, panel, NTG, mode;
    if (f < 65536)       { rem = f;          panel = rem / 16384; rem &= 16383; NTG = 32; mode = 0; }
    else if (f < 131072) { rem = f - 65536;  panel = rem / 16384; rem &= 16383; NTG = 16; mode = 1; }
    else if (f < 163840) { rem = f - 131072; panel = rem / 8192;  rem &= 8191;  NTG = 16; mode = 2; }
    else if (f < 212992) { rem = f - 163840; panel = rem / 24576; rem %= 24576; NTG = 48; mode = 3; }
    else if (f < 229376) { rem = f - 212992; panel = rem / 8192;  rem &= 8191;  NTG = 16; mode = 4; }
    else if (f < 262144) { rem = f - 229376; panel = rem / 16384; rem &= 16383; NTG = 32; mode = 5; }
    else                 { rem = f - 262144; panel = rem / 16384; rem &= 16383; NTG = 16; mode = 6; }
    int ks   = rem / (NTG * 64);
    int ntg  = (rem >> 6) % NTG;
    int lane = rem & 63;
    unsigned short tmp[8];
    #pragma unroll
    for (int j = 0; j < 8; ++j) {
        int k = ks*32 + 4*(lane>>4) + (j&3) + 16*(j>>2);
        int n = ntg*16 + (lane&15);
        float val;
        switch (mode) {
            case 0: val = ew1[(size_t)panel*131328 + (n < 256 ? k*256 + n : (256 + k)*256 + (n - 256))]; break;
            case 1: val = nw1[(size_t)panel*131072 + k*256 + n]; break;
            case 2: val = nw2[(size_t)panel*65536 + k*256 + n]; break;
            case 3: { const float* b = (n < 256) ? wq : ((n < 512) ? wk : wv);
                      val = b[(size_t)panel*65536 + k*256 + (n & 255)]; } break;
            case 4: val = wo[(size_t)panel*65536 + k*256 + n]; break;
            case 5: val = fw1[(size_t)panel*131072 + k*512 + n]; break;
            default: val = fw2[(size_t)panel*131072 + k*256 + n]; break;
        }
        tmp[j] = f2b(val);
    }
    *(bf16x8*)&dst[(size_t)f * 8] = *(const bf16x8*)&tmp[0];
}

// ---------------- generic split-bf16 MFMA GEMM ----------------
// OUTMODE 0: fp32 C. OUTMODE 1 (QKV): q fp32 | kpk frag hi/lo | vpk frag V^T.
// AMODE 0: A from A0/A1. AMODE 1: A = merge of 4 attn partials (A0,A1,am2,am3 + aml).
template<int NCHUNK, int NC, int NSPLIT, int ACT, int RESID, int OUTMODE, int AMODE>
__global__ __launch_bounds__(256) void k_gemm(
    const float* __restrict__ A0, const float* __restrict__ A1, int lda,
    const unsigned short* __restrict__ Wp,
    const float* __restrict__ b0, const float* __restrict__ b1, const float* __restrict__ b2,
    const float* __restrict__ resid, float* __restrict__ C,
    unsigned short* __restrict__ kpk, unsigned short* __restrict__ vpk,
    const float* __restrict__ am2, const float* __restrict__ am3,
    const float* __restrict__ aml)
{
    constexpr int NT  = NC / (64 * NSPLIT);
    constexpr int NTG = NC / 16;
    __shared__ __align__(16) char s_hi[16 * 512];
    __shared__ __align__(16) char s_lo[16 * 512];
    const int t = threadIdx.x, l = t & 63, w = t >> 6;
    const int g = l >> 4, r = l & 15;
    const int mtile  = blockIdx.x % 256;
    const int nchunk = blockIdx.x / 256;
    const int r0 = mtile * 16;

    f32x4 acc[NT];
    #pragma unroll
    for (int nt = 0; nt < NT; ++nt) acc[nt] = (f32x4){0.f, 0.f, 0.f, 0.f};

    const bf16x8* Wf = (const bf16x8*)Wp;
    for (int c = 0; c < NCHUNK; ++c) {
        const float* Ac = (c == 0) ? A0 : A1;
        __syncthreads();
        const int c4 = l * 4;
        #pragma unroll
        for (int it = 0; it < 4; ++it) {
            int row = it * 4 + w;
            float4 v;
            if (AMODE == 0) {
                v = *(const float4*)&Ac[(size_t)(r0 + row) * lda + c4];
            } else {
                const int head = l >> 3;
                float m_[4], l_[4];
                #pragma unroll
                for (int s = 0; s < 4; ++s) {
                    const float* p = &aml[(((size_t)s * NHEAD + head) * N_NODES + (r0 + row)) * 2];
                    m_[s] = p[0]; l_[s] = p[1];
                }
                float mm = fmaxf(fmaxf(m_[0], m_[1]), fmaxf(m_[2], m_[3]));
                float e0 = __expf(m_[0] - mm), e1 = __expf(m_[1] - mm);
                float e2 = __expf(m_[2] - mm), e3 = __expf(m_[3] - mm);
                float inv = 1.f / (e0 * l_[0] + e1 * l_[1] + e2 * l_[2] + e3 * l_[3]);
                size_t off = (size_t)(r0 + row) * 256 + c4;
                float4 a0 = *(const float4*)&A0[off];
                float4 a1 = *(const float4*)&A1[off];
                float4 a2 = *(const float4*)&am2[off];
                float4 a3 = *(const float4*)&am3[off];
                v.x = (a0.x*e0 + a1.x*e1 + a2.x*e2 + a3.x*e3) * inv;
                v.y = (a0.y*e0 + a1.y*e1 + a2.y*e2 + a3.y*e3) * inv;
                v.z = (a0.z*e0 + a1.z*e1 + a2.z*e2 + a3.z*e3) * inv;
                v.w = (a0.w*e0 + a1.w*e1 + a2.w*e2 + a3.w*e3) * inv;
            }
            float vv[4] = {v.x, v.y, v.z, v.w};
            ushort4 h4, l4;
            unsigned short hh;
            hh = f2b(vv[0]); h4.x = hh; l4.x = f2b(vv[0] - b2f(hh));
            hh = f2b(vv[1]); h4.y = hh; l4.y = f2b(vv[1] - b2f(hh));
            hh = f2b(vv[2]); h4.z = hh; l4.z = f2b(vv[2] - b2f(hh));
            hh = f2b(vv[3]); h4.w = hh; l4.w = f2b(vv[3] - b2f(hh));
            int boff = (c4 * 2) ^ (row << 3);
            *(ushort4*)&s_hi[row * 512 + boff] = h4;
            *(ushort4*)&s_lo[row * 512 + boff] = l4;
        }
        __syncthreads();
        #pragma unroll
        for (int ks = 0; ks < 8; ++ks) {
            const int ksg = c * 8 + ks;
            const int x0 = (ks * 64 + 8 * g) ^ (r << 3);
            union { uint2 u[2]; bf16x8 v; } ah, al;
            ah.u[0] = *(const uint2*)&s_hi[r * 512 + x0];
            ah.u[1] = *(const uint2*)&s_hi[r * 512 + (x0 ^ 32)];
            al.u[0] = *(const uint2*)&s_lo[r * 512 + x0];
            al.u[1] = *(const uint2*)&s_lo[r * 512 + (x0 ^ 32)];
            #pragma unroll
            for (int nt = 0; nt < NT; ++nt) {
                int fb = (nchunk * 4 + w) * NT + nt;
                bf16x8 bf_ = Wf[(size_t)(ksg * NTG + fb) * 64 + l];
                acc[nt] = __builtin_amdgcn_mfma_f32_16x16x32_bf16(ah.v, bf_, acc[nt], 0, 0, 0);
                acc[nt] = __builtin_amdgcn_mfma_f32_16x16x32_bf16(al.v, bf_, acc[nt], 0, 0, 0);
            }
        }
    }
    #pragma unroll
    for (int nt = 0; nt < NT; ++nt) {
        int n = ((nchunk * 4 + w) * NT + nt) * 16 + r;
        float bias = 0.f;
        if (b0) {
            const float* bp = (n < 256) ? b0 : ((n < 512) ? b1 : b2);
            bias = bp[n & 255];
        }
        #pragma unroll
        for (int reg = 0; reg < 4; ++reg) {
            int row = r0 + g * 4 + reg;
            float v = acc[nt][reg] + bias;
            if (ACT == 1) v = siluf(v);
            if (RESID) v += resid[(size_t)row * 256 + n];
            if (OUTMODE == 0) {
                C[(size_t)row * NC + n] = v;
            } else {
                if (n < 256) {
                    C[(size_t)row * 256 + n] = v;             // q, fp32
                } else if (n < 512) {
                    int hd = (n - 256) >> 5, dm = (n - 256) & 31;
                    int dp = (dm & 3) | (((dm >> 4) & 1) << 2) | (((dm >> 2) & 3) << 3);
                    unsigned short hb = f2b(v);
                    size_t base = ((size_t)hd * N_NODES + row) * 64;
                    kpk[base + dp]      = hb;
                    kpk[base + 32 + dp] = f2b(v - b2f(hb));
                } else {
                    int hd = (n - 512) >> 5, dm = (n - 512) & 31;
                    int s = row & 31;
                    int sp = (s & 3) | (((s >> 4) & 1) << 2) | (((s >> 2) & 3) << 3);
                    int keyp = (row & ~31) | sp;
                    vpk[((size_t)hd * 32 + dm) * N_NODES + keyp] = f2b(v);
                }
            }
        }
    }
}

// ---------------- fused edge kernel (scalarized addressing, ballot flush mask) ----------------
__global__ __launch_bounds__(256) void k_edge_mfma(
    const float* __restrict__ P12,
    const int* __restrict__ rows_s, const int* __restrict__ cols_s,
    const float* __restrict__ rad_s,
    const float* __restrict__ w1r, const float* __restrict__ b1,
    const unsigned short* __restrict__ W2F, const float* __restrict__ b2,
    const float* __restrict__ aw, const float* __restrict__ ab,
    float* __restrict__ agg)
{
    __shared__ __align__(16) char s_a[20480];
    __shared__ int   s_row[TE2], s_cn[TE2];
    __shared__ float s_rad[TE2], s_gp[4][TE2], s_gate[TE2];
    __shared__ unsigned s_mask;
    const int t = threadIdx.x, l = t & 63, w = t >> 6;
    const int e0 = blockIdx.x * TE2;

    if (t < TE2) {
        s_row[t] = rows_s[e0 + t];
        s_cn[t]  = cols_s[e0 + t];
        s_rad[t] = rad_s[e0 + t];
    }
    __syncthreads();

    // flush mask (wave 0): bit e set where run of equal rows ends
    if (t < 64) {
        bool flag = (t < TE2) && ((t == TE2 - 1) || (s_row[t + 1] != s_row[t]));
        unsigned long long bm = __ballot(flag);
        if (t == 0) s_mask = (unsigned)bm;
    }

    const int c4 = l * 4;
    const float4 wr = *(const float4*)&w1r[c4];
    const float4 bb = *(const float4*)&b1[c4];
    #pragma unroll
    for (int it = 0; it < 8; ++it) {
        int e = it * 4 + w;   // wave-uniform
        int rowu = __builtin_amdgcn_readfirstlane(s_row[e]);
        int cnu  = __builtin_amdgcn_readfirstlane(s_cn[e]);
        float rad = __int_as_float(__builtin_amdgcn_readfirstlane(__float_as_int(s_rad[e])));
        float4 pa = *(const float4*)&P12[(size_t)rowu * 512 + c4];
        float4 pb = *(const float4*)&P12[(size_t)cnu * 512 + 256 + c4];
        ushort4 pk;
        pk.x = f2b(siluf(pa.x + pb.x + rad * wr.x + bb.x));
        pk.y = f2b(siluf(pa.y + pb.y + rad * wr.y + bb.y));
        pk.z = f2b(siluf(pa.z + pb.z + rad * wr.z + bb.z));
        pk.w = f2b(siluf(pa.w + pb.w + rad * wr.w + bb.w));
        *(ushort4*)&s_a[e * 512 + ((c4 * 2) ^ ((e & 15) << 3))] = pk;
    }
    __syncthreads();

    const int g = l >> 4, r = l & 15;
    f32x4 acc[2][4];
    #pragma unroll
    for (int mt = 0; mt < 2; ++mt)
        #pragma unroll
        for (int nt = 0; nt < 4; ++nt)
            acc[mt][nt] = (f32x4){0.f, 0.f, 0.f, 0.f};

    const bf16x8* Wf = (const bf16x8*)W2F;
    for (int ks = 0; ks < 8; ++ks) {
        bf16x8 af[2], bfr[4];
        #pragma unroll
        for (int mt = 0; mt < 2; ++mt) {
            int rowa = mt * 16 + r;
            int x0 = (ks * 64 + 8 * g) ^ (r << 3);
            uint2 lo = *(const uint2*)&s_a[rowa * 512 + x0];
            uint2 hi = *(const uint2*)&s_a[rowa * 512 + (x0 ^ 32)];
            union { uint2 u[2]; bf16x8 v; } ua;
            ua.u[0] = lo; ua.u[1] = hi;
            af[mt] = ua.v;
        }
        #pragma unroll
        for (int nt = 0; nt < 4; ++nt)
            bfr[nt] = Wf[(ks * 16 + w * 4 + nt) * 64 + l];
        #pragma unroll
        for (int mt = 0; mt < 2; ++mt)
            #pragma unroll
            for (int nt = 0; nt < 4; ++nt)
                acc[mt][nt] = __builtin_amdgcn_mfma_f32_16x16x32_bf16(af[mt], bfr[nt], acc[mt][nt], 0, 0, 0);
    }

    float b2v[4], awv[4];
    #pragma unroll
    for (int nt = 0; nt < 4; ++nt) {
        int col = w * 64 + nt * 16 + r;
        b2v[nt] = b2[col];
        awv[nt] = aw[col];
    }
    float pg[2][4];
    #pragma unroll
    for (int mt = 0; mt < 2; ++mt)
        #pragma unroll
        for (int reg = 0; reg < 4; ++reg) {
            float s = 0.f;
            #pragma unroll
            for (int nt = 0; nt < 4; ++nt) {
                float v = siluf(acc[mt][nt][reg] + b2v[nt]);
                acc[mt][nt][reg] = v;
                s += v * awv[nt];
            }
            pg[mt][reg] = s;
        }
    #pragma unroll
    for (int off = 1; off < 16; off <<= 1)
        #pragma unroll
        for (int mt = 0; mt < 2; ++mt)
            #pragma unroll
            for (int reg = 0; reg < 4; ++reg)
                pg[mt][reg] += __shfl_xor(pg[mt][reg], off, 64);
    if (r == 0) {
        #pragma unroll
        for (int mt = 0; mt < 2; ++mt)
            #pragma unroll
            for (int reg = 0; reg < 4; ++reg)
                s_gp[w][mt * 16 + g * 4 + reg] = pg[mt][reg];
    }
    __syncthreads();
    if (t < TE2)
        s_gate[t] = sigmf_(s_gp[0][t] + s_gp[1][t] + s_gp[2][t] + s_gp[3][t] + ab[0]);
    __syncthreads();

    unsigned short* s_out = (unsigned short*)s_a;
    #pragma unroll
    for (int mt = 0; mt < 2; ++mt) {
        float4 gt4 = *(const float4*)&s_gate[mt * 16 + g * 4];
        #pragma unroll
        for (int nt = 0; nt < 4; ++nt) {
            int col = w * 64 + nt * 16 + r;
            ushort4 o4;
            o4.x = f2b(acc[mt][nt][0] * gt4.x);
            o4.y = f2b(acc[mt][nt][1] * gt4.y);
            o4.z = f2b(acc[mt][nt][2] * gt4.z);
            o4.w = f2b(acc[mt][nt][3] * gt4.w);
            *(ushort4*)&s_out[col * 40 + mt * 16 + g * 4] = o4;
        }
    }
    __syncthreads();
    const unsigned fmask = s_mask;
    float cur = 0.f;
    #pragma unroll
    for (int c = 0; c < 4; ++c) {
        union { uint4 q; unsigned short s[8]; } ch;
        ch.q = *(const uint4*)&s_out[t * 40 + c * 8];
        #pragma unroll
        for (int j = 0; j < 8; ++j) {
            int e = c * 8 + j;
            cur += b2f(ch.s[j]);
            if ((fmask >> e) & 1u) {
                int rowu = __builtin_amdgcn_readfirstlane(s_row[e]);
                atomicAdd(&agg[(size_t)rowu * DIM + t], cur);
                cur = 0.f;
            }
        }
    }
}

// ---------------- tiny VALU MLP (readout head only, M=128) ----------------
template<int ACT>
__global__ __launch_bounds__(256) void k_mlp_small(
    const float* __restrict__ A1, const float* __restrict__ W,
    const float* __restrict__ bias, float* __restrict__ C)
{
    __shared__ float s_a[16][260];
    const int t  = threadIdx.x;
    const int r0 = blockIdx.x * 16;
    for (int r = 0; r < 16; ++r)
        s_a[r][t] = A1[(size_t)(r0 + r) * DIM + t];
    __syncthreads();
    const int er0 = (t >> 6) * 4;
    const int c0 = (t & 63) * 4;
    float acc[4][4];
    #pragma unroll
    for (int e = 0; e < 4; ++e)
        #pragma unroll
        for (int c = 0; c < 4; ++c) acc[e][c] = 0.f;
    #pragma unroll 2
    for (int k = 0; k < DIM; k += 4) {
        float4 w0 = *(const float4*)&W[(size_t)(k+0)*DIM + c0];
        float4 w1 = *(const float4*)&W[(size_t)(k+1)*DIM + c0];
        float4 w2 = *(const float4*)&W[(size_t)(k+2)*DIM + c0];
        float4 w3 = *(const float4*)&W[(size_t)(k+3)*DIM + c0];
        #pragma unroll
        for (int e = 0; e < 4; ++e) {
            float4 x = *(const float4*)&s_a[er0+e][k];
            acc[e][0] += x.x*w0.x + x.y*w1.x + x.z*w2.x + x.w*w3.x;
            acc[e][1] += x.x*w0.y + x.y*w1.y + x.z*w2.y + x.w*w3.y;
            acc[e][2] += x.x*w0.z + x.y*w1.z + x.z*w2.z + x.w*w3.z;
            acc[e][3] += x.x*w0.w + x.y*w1.w + x.z*w2.w + x.w*w3.w;
        }
    }
    float4 bb = *(const float4*)&bias[c0];
    #pragma unroll
    for (int e = 0; e < 4; ++e) {
        float v0 = acc[e][0] + bb.x, v1 = acc[e][1] + bb.y;
        float v2 = acc[e][2] + bb.z, v3 = acc[e][3] + bb.w;
        if (ACT == 1) { v0 = siluf(v0); v1 = siluf(v1); v2 = siluf(v2); v3 = siluf(v3); }
        float4 o; o.x = v0; o.y = v1; o.z = v2; o.w = v3;
        *(float4*)&C[(size_t)(r0 + er0 + e) * DIM + c0] = o;
    }
}

// ---------------- LayerNorm ----------------
__global__ __launch_bounds__(256) void k_ln(const float* __restrict__ x,
                                            const float* __restrict__ g,
                                            const float* __restrict__ b,
                                            float* __restrict__ out) {
    int t = threadIdx.x, lane = t & 63, w = t >> 6;
    int row = blockIdx.x * 4 + w;
    float4 v = *(const float4*)&x[(size_t)row * DIM + lane * 4];
    float s = v.x + v.y + v.z + v.w;
    #pragma unroll
    for (int off = 32; off; off >>= 1) s += __shfl_xor(s, off, 64);
    float mu = s * (1.f / 256.f);
    float dx = v.x - mu, dy = v.y - mu, dz = v.z - mu, dw = v.w - mu;
    float q = dx*dx + dy*dy + dz*dz + dw*dw;
    #pragma unroll
    for (int off = 32; off; off >>= 1) q += __shfl_xor(q, off, 64);
    float rs = rsqrtf(q * (1.f / 256.f) + 1e-5f);
    float4 gg = *(const float4*)&g[lane * 4];
    float4 bb = *(const float4*)&b[lane * 4];
    float4 o;
    o.x = dx * rs * gg.x + bb.x;
    o.y = dy * rs * gg.y + bb.y;
    o.z = dz * rs * gg.z + bb.z;
    o.w = dw * rs * gg.w + bb.w;
    *(float4*)&out[(size_t)row * DIM + lane * 4] = o;
}

// ---------------- MFMA flash attention: key-split x4, LDS dbuf, partial out ----------------
__global__ __launch_bounds__(256) void k_attn_mfma(
    const float* __restrict__ q,
    const unsigned short* __restrict__ kpk,
    const unsigned short* __restrict__ vpk,
    float* __restrict__ op0, float* __restrict__ op1,
    float* __restrict__ op2, float* __restrict__ op3,
    float* __restrict__ mlbuf)
{
    __shared__ __align__(16) char s_k[2][8192];
    __shared__ __align__(16) char s_v[2][4096];
    const int t = threadIdx.x, lane = t & 63, w = t >> 6;
    const int g = lane >> 4, r = lane & 15;
    const int head = blockIdx.y;
    const int split = blockIdx.z;
    const int q0 = blockIdx.x * 64;
    const float scale = 0.17677669529663687f;

    bf16x8 qh, ql;
    {
        const float* qp = &q[(size_t)(q0 + w*16 + r) * DIM + head*DKH + 4*g];
        float4 f0 = *(const float4*)qp;
        float4 f1 = *(const float4*)(qp + 16);
        float vv[8] = {f0.x, f0.y, f0.z, f0.w, f1.x, f1.y, f1.z, f1.w};
        union { unsigned short s[8]; bf16x8 v; } uh, ul;
        #pragma unroll
        for (int j = 0; j < 8; ++j) {
            float sv = vv[j] * scale;
            unsigned short hb = f2b(sv);
            uh.s[j] = hb;
            ul.s[j] = f2b(sv - b2f(hb));
        }
        qh = uh.v; ql = ul.v;
    }

    const char* kbase = (const char*)(kpk + (size_t)head * N_NODES * 64) + (size_t)split * 16 * 8192;
    const unsigned short* vbase = vpk + (size_t)head * 32 * N_NODES;
    const int koff = split * 1024;
    const int vrow = t >> 3, vch = t & 7;

    uint4 kr0, kr1, vr0;
    {
        const char* kt = kbase;
        kr0 = *(const uint4*)(kt + t * 16);
        kr1 = *(const uint4*)(kt + 4096 + t * 16);
        vr0 = *(const uint4*)(vbase + (size_t)vrow * N_NODES + koff + vch * 8);
        int key0 = t >> 3, sl0 = t & 7;
        *(uint4*)&s_k[0][key0 * 128 + ((sl0 ^ (key0 & 7)) << 4)] = kr0;
        int c1 = t + 256, key1 = c1 >> 3, sl1 = c1 & 7;
        *(uint4*)&s_k[0][key1 * 128 + ((sl1 ^ (key1 & 7)) << 4)] = kr1;
        *(uint4*)&s_v[0][vrow * 128 + ((vch ^ (vrow & 7)) << 4)] = vr0;
    }
    __syncthreads();

    float m = -1e30f, l = 0.f;
    f32x4 ot0 = (f32x4){0.f,0.f,0.f,0.f}, ot1 = (f32x4){0.f,0.f,0.f,0.f};

    for (int tile = 0; tile < 16; ++tile) {
        const int cur = tile & 1;
        if (tile < 15) {
            const char* kt = kbase + (size_t)(tile + 1) * 8192;
            kr0 = *(const uint4*)(kt + t * 16);
            kr1 = *(const uint4*)(kt + 4096 + t * 16);
            vr0 = *(const uint4*)(vbase + (size_t)vrow * N_NODES + koff + (tile + 1) * 64 + vch * 8);
        }
        bf16x8 kh[4], kl[4];
        #pragma unroll
        for (int kb = 0; kb < 4; ++kb) {
            int key = kb * 16 + r;
            kh[kb] = *(const bf16x8*)&s_k[cur][key * 128 + ((g ^ (r & 7)) << 4)];
            kl[kb] = *(const bf16x8*)&s_k[cur][key * 128 + (((4 + g) ^ (r & 7)) << 4)];
        }
        f32x4 sc[4];
        #pragma unroll
        for (int kb = 0; kb < 4; ++kb) {
            f32x4 a = (f32x4){0.f,0.f,0.f,0.f};
            a = __builtin_amdgcn_mfma_f32_16x16x32_bf16(kh[kb], qh, a, 0, 0, 0);
            a = __builtin_amdgcn_mfma_f32_16x16x32_bf16(kh[kb], ql, a, 0, 0, 0);
            a = __builtin_amdgcn_mfma_f32_16x16x32_bf16(kl[kb], qh, a, 0, 0, 0);
            sc[kb] = a;
        }
        float tm = -1e30f;
        #pragma unroll
        for (int kb = 0; kb < 4; ++kb)
            #pragma unroll
            for (int e = 0; e < 4; ++e) tm = fmaxf(tm, sc[kb][e]);
        tm = fmaxf(tm, __shfl_xor(tm, 16, 64));
        tm = fmaxf(tm, __shfl_xor(tm, 32, 64));
        float nm = fmaxf(m, tm);
        float scf = __expf(m - nm);
        m = nm;
        float p[16]; float ls = 0.f;
        #pragma unroll
        for (int kb = 0; kb < 4; ++kb)
            #pragma unroll
            for (int e = 0; e < 4; ++e) {
                float pe = __expf(sc[kb][e] - nm);
                p[kb*4+e] = pe; ls += pe;
            }
        ls += __shfl_xor(ls, 16, 64);
        ls += __shfl_xor(ls, 32, 64);
        l = l * scf + ls;
        ot0[0] *= scf; ot0[1] *= scf; ot0[2] *= scf; ot0[3] *= scf;
        ot1[0] *= scf; ot1[1] *= scf; ot1[2] *= scf; ot1[3] *= scf;
        union { unsigned short s[8]; bf16x8 v; } pk0, pk1;
        #pragma unroll
        for (int j = 0; j < 8; ++j) {
            pk0.s[j] = f2b(p[(j >> 2) * 4 + (j & 3)]);
            pk1.s[j] = f2b(p[(2 + (j >> 2)) * 4 + (j & 3)]);
        }
        bf16x8 vf00 = *(const bf16x8*)&s_v[cur][(0*16 + r) * 128 + (((0*4 + g) ^ (r & 7)) << 4)];
        bf16x8 vf01 = *(const bf16x8*)&s_v[cur][(0*16 + r) * 128 + (((1*4 + g) ^ (r & 7)) << 4)];
        bf16x8 vf10 = *(const bf16x8*)&s_v[cur][(1*16 + r) * 128 + (((0*4 + g) ^ (r & 7)) << 4)];
        bf16x8 vf11 = *(const bf16x8*)&s_v[cur][(1*16 + r) * 128 + (((1*4 + g) ^ (r & 7)) << 4)];
        ot0 = __builtin_amdgcn_mfma_f32_16x16x32_bf16(vf00, pk0.v, ot0, 0, 0, 0);
        ot0 = __builtin_amdgcn_mfma_f32_16x16x32_bf16(vf01, pk1.v, ot0, 0, 0, 0);
        ot1 = __builtin_amdgcn_mfma_f32_16x16x32_bf16(vf10, pk0.v, ot1, 0, 0, 0);
        ot1 = __builtin_amdgcn_mfma_f32_16x16x32_bf16(vf11, pk1.v, ot1, 0, 0, 0);

        __syncthreads();
        if (tile < 15) {
            int key0 = t >> 3, sl0 = t & 7;
            *(uint4*)&s_k[cur ^ 1][key0 * 128 + ((sl0 ^ (key0 & 7)) << 4)] = kr0;
            int c1 = t + 256, key1 = c1 >> 3, sl1 = c1 & 7;
            *(uint4*)&s_k[cur ^ 1][key1 * 128 + ((sl1 ^ (key1 & 7)) << 4)] = kr1;
            *(uint4*)&s_v[cur ^ 1][vrow * 128 + ((vch ^ (vrow & 7)) << 4)] = vr0;
        }
        __syncthreads();
    }

    float* opsel = (split == 0) ? op0 : (split == 1) ? op1 : (split == 2) ? op2 : op3;
    float* op = opsel + (size_t)(q0 + w*16 + r) * DIM + head*DKH;
    *(float4*)(op + 4*g)      = make_float4(ot0[0], ot0[1], ot0[2], ot0[3]);
    *(float4*)(op + 16 + 4*g) = make_float4(ot1[0], ot1[1], ot1[2], ot1[3]);
    if (g == 0) {
        float* mp = &mlbuf[(((size_t)split * NHEAD + head) * N_NODES + q0 + w*16 + r) * 2];
        mp[0] = m; mp[1] = l;
    }
}

// ---------------- graph readout ----------------
__global__ __launch_bounds__(256) void k_segsum(const float* __restrict__ h,
                                                const int* __restrict__ batch,
                                                float* __restrict__ gbuf) {
    int i = blockIdx.x * 256 + threadIdx.x;
    int n = i >> 8, d = i & 255;
    atomicAdd(&gbuf[batch[n] * DIM + d], h[i]);
}

__global__ __launch_bounds__(256) void k_head2(const float* __restrict__ gmid,
                                               const float* __restrict__ w2,
                                               const float* __restrict__ b2,
                                               float* __restrict__ out) {
    int t = threadIdx.x, lane = t & 63, w = t >> 6;
    int g = blockIdx.x * 4 + w;
    float4 x  = *(const float4*)&gmid[g * DIM + lane * 4];
    float4 ww = *(const float4*)&w2[lane * 4];
    float s = x.x * ww.x + x.y * ww.y + x.z * ww.z + x.w * ww.w;
    #pragma unroll
    for (int off = 32; off; off >>= 1) s += __shfl_xor(s, off, 64);
    if (lane == 0) out[g] = s + b2[0];
}

extern "C" void kernel_launch(void* const* d_in, const int* in_sizes, int n_in,
                              void* d_out, int out_size, void* d_ws, size_t ws_size,
                              hipStream_t stream)
{
    const int*   z     = (const int*)d_in[0];
    const float* pos   = (const float*)d_in[1];
    const int*   batch = (const int*)d_in[2];
    const int*   ei    = (const int*)d_in[3];
    const float* emb   = (const float*)d_in[4];
    const float* ew1   = (const float*)d_in[5];
    const float* eb1   = (const float*)d_in[6];
    const float* ew2   = (const float*)d_in[7];
    const float* eb2   = (const float*)d_in[8];
    const float* nw1   = (const float*)d_in[9];
    const float* nb1   = (const float*)d_in[10];
    const float* nw2   = (const float*)d_in[11];
    const float* nb2   = (const float*)d_in[12];
    const float* aw    = (const float*)d_in[13];
    const float* ab    = (const float*)d_in[14];
    const float* wq    = (const float*)d_in[15];
    const float* bq    = (const float*)d_in[16];
    const float* wk    = (const float*)d_in[17];
    const float* bk    = (const float*)d_in[18];
    const float* wv    = (const float*)d_in[19];
    const float* bv    = (const float*)d_in[20];
    const float* wo    = (const float*)d_in[21];
    const float* bo    = (const float*)d_in[22];
    const float* ln1g  = (const float*)d_in[23];
    const float* ln1b  = (const float*)d_in[24];
    const float* fw1   = (const float*)d_in[25];
    const float* fb1   = (const float*)d_in[26];
    const float* fw2   = (const float*)d_in[27];
    const float* fb2   = (const float*)d_in[28];
    const float* ln2g  = (const float*)d_in[29];
    const float* ln2b  = (const float*)d_in[30];
    const float* fcw1  = (const float*)d_in[31];
    const float* fcb1  = (const float*)d_in[32];
    const float* fcw2  = (const float*)d_in[33];
    const float* fcb2  = (const float*)d_in[34];
    float* out = (float*)d_out;

    float* ws = (float*)d_ws;
    const size_t ND = (size_t)N_NODES * DIM;
    float* h    = ws;
    float* agg  = ws + ND;            // EGNN agg / WO out
    float* A    = ws + 2 * ND;        // node-mid / attn op2
    float* U    = ws + 3 * ND;        // P12 fp32 [N,512] (EGNN) / q fp32 (enc)
    float* op0  = ws + 4 * ND;
    float* op1  = ws + 5 * ND;
    float* Bffn = ws + 6 * ND;        // ffn-mid [N,512]; kpk/vpk alias
    unsigned short* kpk = (unsigned short*)Bffn;
    unsigned short* vpk = kpk + (size_t)NHEAD * N_NODES * 64;
    float* radial = Bffn + (3 * ND) / 2;
    int*   cnt    = (int*)(radial + N_EDGES);
    int*   pcur   = cnt + N_NODES;
    float* gbuf   = ws + 8 * ND;
    float* gmid   = gbuf + (size_t)NG * DIM;
    float* rad_s  = gmid + (size_t)NG * DIM;
    int*   rows_s = (int*)(rad_s + N_EDGES);
    int*   cols_s = rows_s + N_EDGES;
    unsigned short* W2F   = (unsigned short*)(cols_s + N_EDGES);
    unsigned short* packs = W2F + (size_t)NL * 65536;
    float* mlbuf = rad_s;                         // dead after EGNN loop
    float* op3buf = (float*)(packs + 2359296);    // after packs end; 1 ND floats

    unsigned short* PK_W1   = packs;
    unsigned short* PK_NW1  = packs + 524288;
    unsigned short* PK_NW2  = packs + 1048576;
    unsigned short* PK_QKV  = packs + 1310720;
    unsigned short* PK_WO   = packs + 1703936;
    unsigned short* PK_FFN1 = packs + 1835008;
    unsigned short* PK_FFN2 = packs + 2097152;

    dim3 b256(256);

    k_embed<<<N_NODES * DIM / 256, b256, 0, stream>>>(z, emb, h);
    k_radial<<<N_EDGES / 256, b256, 0, stream>>>(pos, ei, radial);
    k_conv_w2<<<NL * 8192 / 256, b256, 0, stream>>>(ew2, W2F);
    k_pack_all<<<1152, b256, 0, stream>>>(ew1, nw1, nw2, wq, wk, wv, wo, fw1, fw2, packs);

    hipMemsetAsync(cnt, 0, N_NODES * sizeof(int), stream);
    k_hist<<<N_EDGES / 256, b256, 0, stream>>>(ei, cnt);
    k_scan<<<1, b256, 0, stream>>>(cnt, pcur);
    k_scatter<<<N_EDGES / 256, b256, 0, stream>>>(ei, radial, pcur, rows_s, cols_s, rad_s);

    for (int l = 0; l < NL; ++l) {
        hipMemsetAsync(agg, 0, ND * sizeof(float), stream);
        const float* W1l = ew1 + (size_t)l * 513 * DIM;
        k_gemm<1,512,2,0,0,0,0><<<512, b256, 0, stream>>>(h, nullptr, DIM,
            PK_W1 + (size_t)l * 131072, nullptr, nullptr, nullptr, nullptr, U,
            nullptr, nullptr, nullptr, nullptr, nullptr);
        k_edge_mfma<<<N_EDGES / TE2, b256, 0, stream>>>(U, rows_s, cols_s, rad_s,
            W1l + (size_t)512 * DIM, eb1 + (size_t)l * DIM,
            W2F + (size_t)l * 65536, eb2 + (size_t)l * DIM,
            aw + (size_t)l * DIM, ab + l, agg);
        const float* nb1l = nb1 + (size_t)l * DIM;
        k_gemm<2,256,2,1,0,0,0><<<512, b256, 0, stream>>>(h, agg, DIM,
            PK_NW1 + (size_t)l * 131072, nb1l, nb1l, nb1l, nullptr, A,
            nullptr, nullptr, nullptr, nullptr, nullptr);
        const float* nb2l = nb2 + (size_t)l * DIM;
        k_gemm<1,256,2,0,1,0,0><<<512, b256, 0, stream>>>(A, nullptr, DIM,
            PK_NW2 + (size_t)l * 65536, nb2l, nb2l, nb2l, h, h,
            nullptr, nullptr, nullptr, nullptr, nullptr);
    }

    for (int i = 0; i < NENC; ++i) {
        k_gemm<1,768,3,0,0,1,0><<<768, b256, 0, stream>>>(h, nullptr, DIM,
            PK_QKV + (size_t)i * 196608,
            bq + (size_t)i * DIM, bk + (size_t)i * DIM, bv + (size_t)i * DIM, nullptr, U,
            kpk, vpk, nullptr, nullptr, nullptr);
        dim3 ag(N_NODES / 64, NHEAD, NSPLIT_ATT);
        k_attn_mfma<<<ag, b256, 0, stream>>>(U, kpk, vpk, op0, op1, A, op3buf, mlbuf);
        const float* bol = bo + (size_t)i * DIM;
        // WO gemm with fused 4-way attention merge in A-staging
        k_gemm<1,256,2,0,1,0,1><<<512, b256, 0, stream>>>(op0, op1, 256,
            PK_WO + (size_t)i * 65536, bol, bol, bol, h, agg,
            nullptr, nullptr, A, op3buf, mlbuf);
        k_ln<<<N_NODES / 4, b256, 0, stream>>>(agg, ln1g + (size_t)i * DIM, ln1b + (size_t)i * DIM, h);
        const float* fb1l = fb1 + (size_t)i * FFD;
        k_gemm<1,512,2,1,0,0,0><<<512, b256, 0, stream>>>(h, nullptr, DIM,
            PK_FFN1 + (size_t)i * 131072, fb1l, fb1l + 256, nullptr, nullptr, Bffn,
            nullptr, nullptr, nullptr, nullptr, nullptr);
        const float* fb2l = fb2 + (size_t)i * DIM;
        k_gemm<2,256,2,0,1,0,0><<<512, b256, 0, stream>>>(Bffn, Bffn + 256, FFD,
            PK_FFN2 + (size_t)i * 131072, fb2l, fb2l, fb2l, h, agg,
            nullptr, nullptr, nullptr, nullptr, nullptr);
        k_ln<<<N_NODES / 4, b256, 0, stream>>>(agg, ln2g + (size_t)i * DIM, ln2b + (size_t)i * DIM, h);
    }

    hipMemsetAsync(gbuf, 0, (size_t)NG * DIM * sizeof(float), stream);
    k_segsum<<<N_NODES * DIM / 256, b256, 0, stream>>>(h, batch, gbuf);
    k_mlp_small<1><<<NG / 16, b256, 0, stream>>>(gbuf, fcw1, fcb1, gmid);
    k_head2<<<NG / 4, b256, 0, stream>>>(gmid, fcw2, fcb2, out);
}

// Round 12
// 619.728 us; speedup vs baseline: 1.0963x; 1.0572x over previous
//
#include <hip/hip_runtime.h>
#include <math.h>

#define N_NODES 4096
#define N_EDGES 131072
#define DIM     256
#define NL      4
#define NENC    2
#define FFD     512
#define NG      128
#define NHEAD   8
#define DKH     32
#define TE2     32
#define NSPLIT_ATT 4

typedef __attribute__((ext_vector_type(8))) short bf16x8;
typedef __attribute__((ext_vector_type(4))) float f32x4;

__device__ __forceinline__ float siluf(float x) { return x / (1.f + __expf(-x)); }
__device__ __forceinline__ float sigmf_(float x) { return 1.f / (1.f + __expf(-x)); }
__device__ __forceinline__ unsigned short f2b(float f) {
    union { float f; unsigned u; } x; x.f = f;
    unsigned r = x.u + 0x7fffu + ((x.u >> 16) & 1u);
    return (unsigned short)(r >> 16);
}
__device__ __forceinline__ float b2f(unsigned short h) {
    union { unsigned u; float f; } x; x.u = (unsigned)h << 16; return x.f;
}

// ---------------- embedding ----------------
__global__ __launch_bounds__(256) void k_embed(const int* __restrict__ z,
                                               const float* __restrict__ emb,
                                               float* __restrict__ h) {
    int i = blockIdx.x * 256 + threadIdx.x;
    int n = i >> 8, d = i & 255;
    h[i] = emb[z[n] * DIM + d];
}

// ---------------- radial ----------------
__global__ __launch_bounds__(256) void k_radial(const float* __restrict__ pos,
                                                const int* __restrict__ ei,
                                                float* __restrict__ radial) {
    int e = blockIdx.x * 256 + threadIdx.x;
    if (e >= N_EDGES) return;
    int r = ei[e], c = ei[N_EDGES + e];
    float dx = pos[r*3+0] - pos[c*3+0];
    float dy = pos[r*3+1] - pos[c*3+1];
    float dz = pos[r*3+2] - pos[c*3+2];
    radial[e] = dx*dx + dy*dy + dz*dz;
}

// ---------------- edge counting sort (by row node) ----------------
__global__ __launch_bounds__(256) void k_hist(const int* __restrict__ ei, int* __restrict__ cnt) {
    int e = blockIdx.x * 256 + threadIdx.x;
    if (e < N_EDGES) atomicAdd(&cnt[ei[e]], 1);
}

__global__ __launch_bounds__(256) void k_scan(const int* __restrict__ cnt, int* __restrict__ pos) {
    __shared__ int s_w[4];
    int t = threadIdx.x, lane = t & 63, wv = t >> 6;
    int loc[16]; int s = 0;
    #pragma unroll
    for (int i = 0; i < 16; ++i) { loc[i] = s; s += cnt[t * 16 + i]; }
    int inc = s;
    #pragma unroll
    for (int off = 1; off < 64; off <<= 1) {
        int v = __shfl_up(inc, off, 64);
        if (lane >= off) inc += v;
    }
    if (lane == 63) s_w[wv] = inc;
    __syncthreads();
    int wbase = 0;
    for (int j = 0; j < wv; ++j) wbase += s_w[j];
    int base = wbase + inc - s;
    #pragma unroll
    for (int i = 0; i < 16; ++i) pos[t * 16 + i] = base + loc[i];
}

__global__ __launch_bounds__(256) void k_scatter(const int* __restrict__ ei,
                                                 const float* __restrict__ radial,
                                                 int* __restrict__ pos,
                                                 int* __restrict__ rows_s,
                                                 int* __restrict__ cols_s,
                                                 float* __restrict__ rad_s) {
    int e = blockIdx.x * 256 + threadIdx.x;
    if (e >= N_EDGES) return;
    int r = ei[e];
    int p = atomicAdd(&pos[r], 1);
    rows_s[p] = r;
    cols_s[p] = ei[N_EDGES + e];
    rad_s[p] = radial[e];
}

// ---------------- W2 -> bf16 MFMA-fragment-linear pack (edge GEMM2) ----------------
__global__ __launch_bounds__(256) void k_conv_w2(const float* __restrict__ ew2,
                                                 unsigned short* __restrict__ W2F) {
    int tid = blockIdx.x * 256 + threadIdx.x;
    int layer = tid >> 13;
    int r = tid & 8191;
    int ks = r >> 10, ntg = (r >> 6) & 15, lane = r & 63;
    const float* W = ew2 + (size_t)layer * 65536;
    unsigned short tmp[8];
    #pragma unroll
    for (int j = 0; j < 8; ++j) {
        int k = ks*32 + 4*(lane>>4) + (j&3) + 16*(j>>2);
        int n = ntg*16 + (lane&15);
        tmp[j] = f2b(W[k*256 + n]);
    }
    *(bf16x8*)&W2F[(size_t)layer*65536 + (size_t)r*8] = *(const bf16x8*)&tmp[0];
}

// ---------------- batched pack of ALL dense weights -> fragment-linear bf16 ----------------
__global__ __launch_bounds__(256) void k_pack_all(
    const float* __restrict__ ew1, const float* __restrict__ nw1, const float* __restrict__ nw2,
    const float* __restrict__ wq, const float* __restrict__ wk, const float* __restrict__ wv,
    const float* __restrict__ wo, const float* __restrict__ fw1, const float* __restrict__ fw2,
    unsigned short* __restrict__ dst)
{
    int f = blockIdx.x * 256 + threadIdx.x;
    int rem, panel, NTG, mode;
    if (f < 65536)       { rem = f;          panel = rem / 16384; rem &= 16383; NTG = 32; mode = 0; }
    else if (f < 131072) { rem = f - 65536;  panel = rem / 16384; rem &= 16383; NTG = 16; mode = 1; }
    else if (f < 163840) { rem = f - 131072; panel = rem / 8192;  rem &= 8191;  NTG = 16; mode = 2; }
    else if (f < 212992) { rem = f - 163840; panel = rem / 24576; rem %= 24576; NTG = 48; mode = 3; }
    else if (f < 229376) { rem = f - 212992; panel = rem / 8192;  rem &= 8191;  NTG = 16; mode = 4; }
    else if (f < 262144) { rem = f - 229376; panel = rem / 16384; rem &= 16383; NTG = 32; mode = 5; }
    else                 { rem = f - 262144; panel = rem / 16384; rem &= 16383; NTG = 16; mode = 6; }
    int ks   = rem / (NTG * 64);
    int ntg  = (rem >> 6) % NTG;
    int lane = rem & 63;
    unsigned short tmp[8];
    #pragma unroll
    for (int j = 0; j < 8; ++j) {
        int k = ks*32 + 4*(lane>>4) + (j&3) + 16*(j>>2);
        int n = ntg*16 + (lane&15);
        float val;
        switch (mode) {
            case 0: val = ew1[(size_t)panel*131328 + (n < 256 ? k*256 + n : (256 + k)*256 + (n - 256))]; break;
            case 1: val = nw1[(size_t)panel*131072 + k*256 + n]; break;
            case 2: val = nw2[(size_t)panel*65536 + k*256 + n]; break;
            case 3: { const float* b = (n < 256) ? wq : ((n < 512) ? wk : wv);
                      val = b[(size_t)panel*65536 + k*256 + (n & 255)]; } break;
            case 4: val = wo[(size_t)panel*65536 + k*256 + n]; break;
            case 5: val = fw1[(size_t)panel*131072 + k*512 + n]; break;
            default: val = fw2[(size_t)panel*131072 + k*256 + n]; break;
        }
        tmp[j] = f2b(val);
    }
    *(bf16x8*)&dst[(size_t)f * 8] = *(const bf16x8*)&tmp[0];
}

// ---------------- generic split-bf16 MFMA GEMM ----------------
// OUTMODE 0: fp32 C. OUTMODE 1 (QKV): q fp32 | kpk frag hi/lo | vpk frag V^T.
// AMODE 0: A from A0/A1. AMODE 1: A = merge of 4 attn partials (A0,A1,am2,am3 + aml).
template<int NCHUNK, int NC, int NSPLIT, int ACT, int RESID, int OUTMODE, int AMODE>
__global__ __launch_bounds__(256) void k_gemm(
    const float* __restrict__ A0, const float* __restrict__ A1, int lda,
    const unsigned short* __restrict__ Wp,
    const float* __restrict__ b0, const float* __restrict__ b1, const float* __restrict__ b2,
    const float* __restrict__ resid, float* __restrict__ C,
    unsigned short* __restrict__ kpk, unsigned short* __restrict__ vpk,
    const float* __restrict__ am2, const float* __restrict__ am3,
    const float* __restrict__ aml)
{
    constexpr int NT  = NC / (64 * NSPLIT);
    constexpr int NTG = NC / 16;
    __shared__ __align__(16) char s_hi[16 * 512];
    __shared__ __align__(16) char s_lo[16 * 512];
    const int t = threadIdx.x, l = t & 63, w = t >> 6;
    const int g = l >> 4, r = l & 15;
    const int mtile  = blockIdx.x % 256;
    const int nchunk = blockIdx.x / 256;
    const int r0 = mtile * 16;

    f32x4 acc[NT];
    #pragma unroll
    for (int nt = 0; nt < NT; ++nt) acc[nt] = (f32x4){0.f, 0.f, 0.f, 0.f};

    const bf16x8* Wf = (const bf16x8*)Wp;
    for (int c = 0; c < NCHUNK; ++c) {
        const float* Ac = (c == 0) ? A0 : A1;
        __syncthreads();
        const int c4 = l * 4;
        #pragma unroll
        for (int it = 0; it < 4; ++it) {
            int row = it * 4 + w;
            float4 v;
            if (AMODE == 0) {
                v = *(const float4*)&Ac[(size_t)(r0 + row) * lda + c4];
            } else {
                const int head = l >> 3;
                float m_[4], l_[4];
                #pragma unroll
                for (int s = 0; s < 4; ++s) {
                    const float* p = &aml[(((size_t)s * NHEAD + head) * N_NODES + (r0 + row)) * 2];
                    m_[s] = p[0]; l_[s] = p[1];
                }
                float mm = fmaxf(fmaxf(m_[0], m_[1]), fmaxf(m_[2], m_[3]));
                float e0 = __expf(m_[0] - mm), e1 = __expf(m_[1] - mm);
                float e2 = __expf(m_[2] - mm), e3 = __expf(m_[3] - mm);
                float inv = 1.f / (e0 * l_[0] + e1 * l_[1] + e2 * l_[2] + e3 * l_[3]);
                size_t off = (size_t)(r0 + row) * 256 + c4;
                float4 a0 = *(const float4*)&A0[off];
                float4 a1 = *(const float4*)&A1[off];
                float4 a2 = *(const float4*)&am2[off];
                float4 a3 = *(const float4*)&am3[off];
                v.x = (a0.x*e0 + a1.x*e1 + a2.x*e2 + a3.x*e3) * inv;
                v.y = (a0.y*e0 + a1.y*e1 + a2.y*e2 + a3.y*e3) * inv;
                v.z = (a0.z*e0 + a1.z*e1 + a2.z*e2 + a3.z*e3) * inv;
                v.w = (a0.w*e0 + a1.w*e1 + a2.w*e2 + a3.w*e3) * inv;
            }
            float vv[4] = {v.x, v.y, v.z, v.w};
            ushort4 h4, l4;
            unsigned short hh;
            hh = f2b(vv[0]); h4.x = hh; l4.x = f2b(vv[0] - b2f(hh));
            hh = f2b(vv[1]); h4.y = hh; l4.y = f2b(vv[1] - b2f(hh));
            hh = f2b(vv[2]); h4.z = hh; l4.z = f2b(vv[2] - b2f(hh));
            hh = f2b(vv[3]); h4.w = hh; l4.w = f2b(vv[3] - b2f(hh));
            int boff = (c4 * 2) ^ (row << 3);
            *(ushort4*)&s_hi[row * 512 + boff] = h4;
            *(ushort4*)&s_lo[row * 512 + boff] = l4;
        }
        __syncthreads();
        #pragma unroll
        for (int ks = 0; ks < 8; ++ks) {
            const int ksg = c * 8 + ks;
            const int x0 = (ks * 64 + 8 * g) ^ (r << 3);
            union { uint2 u[2]; bf16x8 v; } ah, al;
            ah.u[0] = *(const uint2*)&s_hi[r * 512 + x0];
            ah.u[1] = *(const uint2*)&s_hi[r * 512 + (x0 ^ 32)];
            al.u[0] = *(const uint2*)&s_lo[r * 512 + x0];
            al.u[1] = *(const uint2*)&s_lo[r * 512 + (x0 ^ 32)];
            #pragma unroll
            for (int nt = 0; nt < NT; ++nt) {
                int fb = (nchunk * 4 + w) * NT + nt;
                bf16x8 bf_ = Wf[(size_t)(ksg * NTG + fb) * 64 + l];
                acc[nt] = __builtin_amdgcn_mfma_f32_16x16x32_bf16(ah.v, bf_, acc[nt], 0, 0, 0);
                acc[nt] = __builtin_amdgcn_mfma_f32_16x16x32_bf16(al.v, bf_, acc[nt], 0, 0, 0);
            }
        }
    }
    #pragma unroll
    for (int nt = 0; nt < NT; ++nt) {
        int n = ((nchunk * 4 + w) * NT + nt) * 16 + r;
        float bias = 0.f;
        if (b0) {
            const float* bp = (n < 256) ? b0 : ((n < 512) ? b1 : b2);
            bias = bp[n & 255];
        }
        #pragma unroll
        for (int reg = 0; reg < 4; ++reg) {
            int row = r0 + g * 4 + reg;
            float v = acc[nt][reg] + bias;
            if (ACT == 1) v = siluf(v);
            if (RESID) v += resid[(size_t)row * 256 + n];
            if (OUTMODE == 0) {
                C[(size_t)row * NC + n] = v;
            } else {
                if (n < 256) {
                    C[(size_t)row * 256 + n] = v;             // q, fp32
                } else if (n < 512) {
                    int hd = (n - 256) >> 5, dm = (n - 256) & 31;
                    int dp = (dm & 3) | (((dm >> 4) & 1) << 2) | (((dm >> 2) & 3) << 3);
                    unsigned short hb = f2b(v);
                    size_t base = ((size_t)hd * N_NODES + row) * 64;
                    kpk[base + dp]      = hb;
                    kpk[base + 32 + dp] = f2b(v - b2f(hb));
                } else {
                    int hd = (n - 512) >> 5, dm = (n - 512) & 31;
                    int s = row & 31;
                    int sp = (s & 3) | (((s >> 4) & 1) << 2) | (((s >> 2) & 3) << 3);
                    int keyp = (row & ~31) | sp;
                    vpk[((size_t)hd * 32 + dm) * N_NODES + keyp] = f2b(v);
                }
            }
        }
    }
}

// ---------------- fused edge kernel (scalarized addressing, ballot flush mask) ----------------
__global__ __launch_bounds__(256) void k_edge_mfma(
    const float* __restrict__ P12,
    const int* __restrict__ rows_s, const int* __restrict__ cols_s,
    const float* __restrict__ rad_s,
    const float* __restrict__ w1r, const float* __restrict__ b1,
    const unsigned short* __restrict__ W2F, const float* __restrict__ b2,
    const float* __restrict__ aw, const float* __restrict__ ab,
    float* __restrict__ agg)
{
    __shared__ __align__(16) char s_a[20480];
    __shared__ int   s_row[TE2], s_cn[TE2];
    __shared__ float s_rad[TE2], s_gp[4][TE2], s_gate[TE2];
    __shared__ unsigned s_mask;
    const int t = threadIdx.x, l = t & 63, w = t >> 6;
    const int e0 = blockIdx.x * TE2;

    if (t < TE2) {
        s_row[t] = rows_s[e0 + t];
        s_cn[t]  = cols_s[e0 + t];
        s_rad[t] = rad_s[e0 + t];
    }
    __syncthreads();

    if (t < 64) {
        bool flag = (t < TE2) && ((t == TE2 - 1) || (s_row[t + 1] != s_row[t]));
        unsigned long long bm = __ballot(flag);
        if (t == 0) s_mask = (unsigned)bm;
    }

    const int c4 = l * 4;
    const float4 wr = *(const float4*)&w1r[c4];
    const float4 bb = *(const float4*)&b1[c4];
    #pragma unroll
    for (int it = 0; it < 8; ++it) {
        int e = it * 4 + w;
        int rowu = __builtin_amdgcn_readfirstlane(s_row[e]);
        int cnu  = __builtin_amdgcn_readfirstlane(s_cn[e]);
        float rad = __int_as_float(__builtin_amdgcn_readfirstlane(__float_as_int(s_rad[e])));
        float4 pa = *(const float4*)&P12[(size_t)rowu * 512 + c4];
        float4 pb = *(const float4*)&P12[(size_t)cnu * 512 + 256 + c4];
        ushort4 pk;
        pk.x = f2b(siluf(pa.x + pb.x + rad * wr.x + bb.x));
        pk.y = f2b(siluf(pa.y + pb.y + rad * wr.y + bb.y));
        pk.z = f2b(siluf(pa.z + pb.z + rad * wr.z + bb.z));
        pk.w = f2b(siluf(pa.w + pb.w + rad * wr.w + bb.w));
        *(ushort4*)&s_a[e * 512 + ((c4 * 2) ^ ((e & 15) << 3))] = pk;
    }
    __syncthreads();

    const int g = l >> 4, r = l & 15;
    f32x4 acc[2][4];
    #pragma unroll
    for (int mt = 0; mt < 2; ++mt)
        #pragma unroll
        for (int nt = 0; nt < 4; ++nt)
            acc[mt][nt] = (f32x4){0.f, 0.f, 0.f, 0.f};

    const bf16x8* Wf = (const bf16x8*)W2F;
    for (int ks = 0; ks < 8; ++ks) {
        bf16x8 af[2], bfr[4];
        #pragma unroll
        for (int mt = 0; mt < 2; ++mt) {
            int rowa = mt * 16 + r;
            int x0 = (ks * 64 + 8 * g) ^ (r << 3);
            uint2 lo = *(const uint2*)&s_a[rowa * 512 + x0];
            uint2 hi = *(const uint2*)&s_a[rowa * 512 + (x0 ^ 32)];
            union { uint2 u[2]; bf16x8 v; } ua;
            ua.u[0] = lo; ua.u[1] = hi;
            af[mt] = ua.v;
        }
        #pragma unroll
        for (int nt = 0; nt < 4; ++nt)
            bfr[nt] = Wf[(ks * 16 + w * 4 + nt) * 64 + l];
        #pragma unroll
        for (int mt = 0; mt < 2; ++mt)
            #pragma unroll
            for (int nt = 0; nt < 4; ++nt)
                acc[mt][nt] = __builtin_amdgcn_mfma_f32_16x16x32_bf16(af[mt], bfr[nt], acc[mt][nt], 0, 0, 0);
    }

    float b2v[4], awv[4];
    #pragma unroll
    for (int nt = 0; nt < 4; ++nt) {
        int col = w * 64 + nt * 16 + r;
        b2v[nt] = b2[col];
        awv[nt] = aw[col];
    }
    float pg[2][4];
    #pragma unroll
    for (int mt = 0; mt < 2; ++mt)
        #pragma unroll
        for (int reg = 0; reg < 4; ++reg) {
            float s = 0.f;
            #pragma unroll
            for (int nt = 0; nt < 4; ++nt) {
                float v = siluf(acc[mt][nt][reg] + b2v[nt]);
                acc[mt][nt][reg] = v;
                s += v * awv[nt];
            }
            pg[mt][reg] = s;
        }
    #pragma unroll
    for (int off = 1; off < 16; off <<= 1)
        #pragma unroll
        for (int mt = 0; mt < 2; ++mt)
            #pragma unroll
            for (int reg = 0; reg < 4; ++reg)
                pg[mt][reg] += __shfl_xor(pg[mt][reg], off, 64);
    if (r == 0) {
        #pragma unroll
        for (int mt = 0; mt < 2; ++mt)
            #pragma unroll
            for (int reg = 0; reg < 4; ++reg)
                s_gp[w][mt * 16 + g * 4 + reg] = pg[mt][reg];
    }
    __syncthreads();
    if (t < TE2)
        s_gate[t] = sigmf_(s_gp[0][t] + s_gp[1][t] + s_gp[2][t] + s_gp[3][t] + ab[0]);
    __syncthreads();

    unsigned short* s_out = (unsigned short*)s_a;
    #pragma unroll
    for (int mt = 0; mt < 2; ++mt) {
        float4 gt4 = *(const float4*)&s_gate[mt * 16 + g * 4];
        #pragma unroll
        for (int nt = 0; nt < 4; ++nt) {
            int col = w * 64 + nt * 16 + r;
            ushort4 o4;
            o4.x = f2b(acc[mt][nt][0] * gt4.x);
            o4.y = f2b(acc[mt][nt][1] * gt4.y);
            o4.z = f2b(acc[mt][nt][2] * gt4.z);
            o4.w = f2b(acc[mt][nt][3] * gt4.w);
            *(ushort4*)&s_out[col * 40 + mt * 16 + g * 4] = o4;
        }
    }
    __syncthreads();
    const unsigned fmask = s_mask;
    float cur = 0.f;
    #pragma unroll
    for (int c = 0; c < 4; ++c) {
        union { uint4 q; unsigned short s[8]; } ch;
        ch.q = *(const uint4*)&s_out[t * 40 + c * 8];
        #pragma unroll
        for (int j = 0; j < 8; ++j) {
            int e = c * 8 + j;
            cur += b2f(ch.s[j]);
            if ((fmask >> e) & 1u) {
                int rowu = __builtin_amdgcn_readfirstlane(s_row[e]);
                atomicAdd(&agg[(size_t)rowu * DIM + t], cur);
                cur = 0.f;
            }
        }
    }
}

// ---------------- tiny VALU MLP (readout head only, M=128) ----------------
template<int ACT>
__global__ __launch_bounds__(256) void k_mlp_small(
    const float* __restrict__ A1, const float* __restrict__ W,
    const float* __restrict__ bias, float* __restrict__ C)
{
    __shared__ float s_a[16][260];
    const int t  = threadIdx.x;
    const int r0 = blockIdx.x * 16;
    for (int r = 0; r < 16; ++r)
        s_a[r][t] = A1[(size_t)(r0 + r) * DIM + t];
    __syncthreads();
    const int er0 = (t >> 6) * 4;
    const int c0 = (t & 63) * 4;
    float acc[4][4];
    #pragma unroll
    for (int e = 0; e < 4; ++e)
        #pragma unroll
        for (int c = 0; c < 4; ++c) acc[e][c] = 0.f;
    #pragma unroll 2
    for (int k = 0; k < DIM; k += 4) {
        float4 w0 = *(const float4*)&W[(size_t)(k+0)*DIM + c0];
        float4 w1 = *(const float4*)&W[(size_t)(k+1)*DIM + c0];
        float4 w2 = *(const float4*)&W[(size_t)(k+2)*DIM + c0];
        float4 w3 = *(const float4*)&W[(size_t)(k+3)*DIM + c0];
        #pragma unroll
        for (int e = 0; e < 4; ++e) {
            float4 x = *(const float4*)&s_a[er0+e][k];
            acc[e][0] += x.x*w0.x + x.y*w1.x + x.z*w2.x + x.w*w3.x;
            acc[e][1] += x.x*w0.y + x.y*w1.y + x.z*w2.y + x.w*w3.y;
            acc[e][2] += x.x*w0.z + x.y*w1.z + x.z*w2.z + x.w*w3.z;
            acc[e][3] += x.x*w0.w + x.y*w1.w + x.z*w2.w + x.w*w3.w;
        }
    }
    float4 bb = *(const float4*)&bias[c0];
    #pragma unroll
    for (int e = 0; e < 4; ++e) {
        float v0 = acc[e][0] + bb.x, v1 = acc[e][1] + bb.y;
        float v2 = acc[e][2] + bb.z, v3 = acc[e][3] + bb.w;
        if (ACT == 1) { v0 = siluf(v0); v1 = siluf(v1); v2 = siluf(v2); v3 = siluf(v3); }
        float4 o; o.x = v0; o.y = v1; o.z = v2; o.w = v3;
        *(float4*)&C[(size_t)(r0 + er0 + e) * DIM + c0] = o;
    }
}

// ---------------- LayerNorm ----------------
__global__ __launch_bounds__(256) void k_ln(const float* __restrict__ x,
                                            const float* __restrict__ g,
                                            const float* __restrict__ b,
                                            float* __restrict__ out) {
    int t = threadIdx.x, lane = t & 63, w = t >> 6;
    int row = blockIdx.x * 4 + w;
    float4 v = *(const float4*)&x[(size_t)row * DIM + lane * 4];
    float s = v.x + v.y + v.z + v.w;
    #pragma unroll
    for (int off = 32; off; off >>= 1) s += __shfl_xor(s, off, 64);
    float mu = s * (1.f / 256.f);
    float dx = v.x - mu, dy = v.y - mu, dz = v.z - mu, dw = v.w - mu;
    float q = dx*dx + dy*dy + dz*dz + dw*dw;
    #pragma unroll
    for (int off = 32; off; off >>= 1) q += __shfl_xor(q, off, 64);
    float rs = rsqrtf(q * (1.f / 256.f) + 1e-5f);
    float4 gg = *(const float4*)&g[lane * 4];
    float4 bb = *(const float4*)&b[lane * 4];
    float4 o;
    o.x = dx * rs * gg.x + bb.x;
    o.y = dy * rs * gg.y + bb.y;
    o.z = dz * rs * gg.z + bb.z;
    o.w = dw * rs * gg.w + bb.w;
    *(float4*)&out[(size_t)row * DIM + lane * 4] = o;
}

// ---------------- MFMA flash attention: key-split x4, LDS dbuf, partial out ----------------
__global__ __launch_bounds__(256) void k_attn_mfma(
    const float* __restrict__ q,
    const unsigned short* __restrict__ kpk,
    const unsigned short* __restrict__ vpk,
    float* __restrict__ op0, float* __restrict__ op1,
    float* __restrict__ op2, float* __restrict__ op3,
    float* __restrict__ mlbuf)
{
    __shared__ __align__(16) char s_k[2][8192];
    __shared__ __align__(16) char s_v[2][4096];
    const int t = threadIdx.x, lane = t & 63, w = t >> 6;
    const int g = lane >> 4, r = lane & 15;
    const int head = blockIdx.y;
    const int split = blockIdx.z;
    const int q0 = blockIdx.x * 64;
    const float scale = 0.17677669529663687f;

    bf16x8 qh, ql;
    {
        const float* qp = &q[(size_t)(q0 + w*16 + r) * DIM + head*DKH + 4*g];
        float4 f0 = *(const float4*)qp;
        float4 f1 = *(const float4*)(qp + 16);
        float vv[8] = {f0.x, f0.y, f0.z, f0.w, f1.x, f1.y, f1.z, f1.w};
        union { unsigned short s[8]; bf16x8 v; } uh, ul;
        #pragma unroll
        for (int j = 0; j < 8; ++j) {
            float sv = vv[j] * scale;
            unsigned short hb = f2b(sv);
            uh.s[j] = hb;
            ul.s[j] = f2b(sv - b2f(hb));
        }
        qh = uh.v; ql = ul.v;
    }

    const char* kbase = (const char*)(kpk + (size_t)head * N_NODES * 64) + (size_t)split * 16 * 8192;
    const unsigned short* vbase = vpk + (size_t)head * 32 * N_NODES;
    const int koff = split * 1024;
    const int vrow = t >> 3, vch = t & 7;

    uint4 kr0, kr1, vr0;
    {
        const char* kt = kbase;
        kr0 = *(const uint4*)(kt + t * 16);
        kr1 = *(const uint4*)(kt + 4096 + t * 16);
        vr0 = *(const uint4*)(vbase + (size_t)vrow * N_NODES + koff + vch * 8);
        int key0 = t >> 3, sl0 = t & 7;
        *(uint4*)&s_k[0][key0 * 128 + ((sl0 ^ (key0 & 7)) << 4)] = kr0;
        int c1 = t + 256, key1 = c1 >> 3, sl1 = c1 & 7;
        *(uint4*)&s_k[0][key1 * 128 + ((sl1 ^ (key1 & 7)) << 4)] = kr1;
        *(uint4*)&s_v[0][vrow * 128 + ((vch ^ (vrow & 7)) << 4)] = vr0;
    }
    __syncthreads();

    float m = -1e30f, l = 0.f;
    f32x4 ot0 = (f32x4){0.f,0.f,0.f,0.f}, ot1 = (f32x4){0.f,0.f,0.f,0.f};

    for (int tile = 0; tile < 16; ++tile) {
        const int cur = tile & 1;
        if (tile < 15) {
            const char* kt = kbase + (size_t)(tile + 1) * 8192;
            kr0 = *(const uint4*)(kt + t * 16);
            kr1 = *(const uint4*)(kt + 4096 + t * 16);
            vr0 = *(const uint4*)(vbase + (size_t)vrow * N_NODES + koff + (tile + 1) * 64 + vch * 8);
        }
        bf16x8 kh[4], kl[4];
        #pragma unroll
        for (int kb = 0; kb < 4; ++kb) {
            int key = kb * 16 + r;
            kh[kb] = *(const bf16x8*)&s_k[cur][key * 128 + ((g ^ (r & 7)) << 4)];
            kl[kb] = *(const bf16x8*)&s_k[cur][key * 128 + (((4 + g) ^ (r & 7)) << 4)];
        }
        f32x4 sc[4];
        #pragma unroll
        for (int kb = 0; kb < 4; ++kb) {
            f32x4 a = (f32x4){0.f,0.f,0.f,0.f};
            a = __builtin_amdgcn_mfma_f32_16x16x32_bf16(kh[kb], qh, a, 0, 0, 0);
            a = __builtin_amdgcn_mfma_f32_16x16x32_bf16(kh[kb], ql, a, 0, 0, 0);
            a = __builtin_amdgcn_mfma_f32_16x16x32_bf16(kl[kb], qh, a, 0, 0, 0);
            sc[kb] = a;
        }
        float tm = -1e30f;
        #pragma unroll
        for (int kb = 0; kb < 4; ++kb)
            #pragma unroll
            for (int e = 0; e < 4; ++e) tm = fmaxf(tm, sc[kb][e]);
        tm = fmaxf(tm, __shfl_xor(tm, 16, 64));
        tm = fmaxf(tm, __shfl_xor(tm, 32, 64));
        float nm = fmaxf(m, tm);
        float scf = __expf(m - nm);
        m = nm;
        float p[16]; float ls = 0.f;
        #pragma unroll
        for (int kb = 0; kb < 4; ++kb)
            #pragma unroll
            for (int e = 0; e < 4; ++e) {
                float pe = __expf(sc[kb][e] - nm);
                p[kb*4+e] = pe; ls += pe;
            }
        ls += __shfl_xor(ls, 16, 64);
        ls += __shfl_xor(ls, 32, 64);
        l = l * scf + ls;
        ot0[0] *= scf; ot0[1] *= scf; ot0[2] *= scf; ot0[3] *= scf;
        ot1[0] *= scf; ot1[1] *= scf; ot1[2] *= scf; ot1[3] *= scf;
        union { unsigned short s[8]; bf16x8 v; } pk0, pk1;
        #pragma unroll
        for (int j = 0; j < 8; ++j) {
            pk0.s[j] = f2b(p[(j >> 2) * 4 + (j & 3)]);
            pk1.s[j] = f2b(p[(2 + (j >> 2)) * 4 + (j & 3)]);
        }
        bf16x8 vf00 = *(const bf16x8*)&s_v[cur][(0*16 + r) * 128 + (((0*4 + g) ^ (r & 7)) << 4)];
        bf16x8 vf01 = *(const bf16x8*)&s_v[cur][(0*16 + r) * 128 + (((1*4 + g) ^ (r & 7)) << 4)];
        bf16x8 vf10 = *(const bf16x8*)&s_v[cur][(1*16 + r) * 128 + (((0*4 + g) ^ (r & 7)) << 4)];
        bf16x8 vf11 = *(const bf16x8*)&s_v[cur][(1*16 + r) * 128 + (((1*4 + g) ^ (r & 7)) << 4)];
        ot0 = __builtin_amdgcn_mfma_f32_16x16x32_bf16(vf00, pk0.v, ot0, 0, 0, 0);
        ot0 = __builtin_amdgcn_mfma_f32_16x16x32_bf16(vf01, pk1.v, ot0, 0, 0, 0);
        ot1 = __builtin_amdgcn_mfma_f32_16x16x32_bf16(vf10, pk0.v, ot1, 0, 0, 0);
        ot1 = __builtin_amdgcn_mfma_f32_16x16x32_bf16(vf11, pk1.v, ot1, 0, 0, 0);

        __syncthreads();
        if (tile < 15) {
            int key0 = t >> 3, sl0 = t & 7;
            *(uint4*)&s_k[cur ^ 1][key0 * 128 + ((sl0 ^ (key0 & 7)) << 4)] = kr0;
            int c1 = t + 256, key1 = c1 >> 3, sl1 = c1 & 7;
            *(uint4*)&s_k[cur ^ 1][key1 * 128 + ((sl1 ^ (key1 & 7)) << 4)] = kr1;
            *(uint4*)&s_v[cur ^ 1][vrow * 128 + ((vch ^ (vrow & 7)) << 4)] = vr0;
        }
        __syncthreads();
    }

    float* opsel = (split == 0) ? op0 : (split == 1) ? op1 : (split == 2) ? op2 : op3;
    float* op = opsel + (size_t)(q0 + w*16 + r) * DIM + head*DKH;
    *(float4*)(op + 4*g)      = make_float4(ot0[0], ot0[1], ot0[2], ot0[3]);
    *(float4*)(op + 16 + 4*g) = make_float4(ot1[0], ot1[1], ot1[2], ot1[3]);
    if (g == 0) {
        float* mp = &mlbuf[(((size_t)split * NHEAD + head) * N_NODES + q0 + w*16 + r) * 2];
        mp[0] = m; mp[1] = l;
    }
}

// ---------------- graph readout ----------------
__global__ __launch_bounds__(256) void k_segsum(const float* __restrict__ h,
                                                const int* __restrict__ batch,
                                                float* __restrict__ gbuf) {
    int i = blockIdx.x * 256 + threadIdx.x;
    int n = i >> 8, d = i & 255;
    atomicAdd(&gbuf[batch[n] * DIM + d], h[i]);
}

__global__ __launch_bounds__(256) void k_head2(const float* __restrict__ gmid,
                                               const float* __restrict__ w2,
                                               const float* __restrict__ b2,
                                               float* __restrict__ out) {
    int t = threadIdx.x, lane = t & 63, w = t >> 6;
    int g = blockIdx.x * 4 + w;
    float4 x  = *(const float4*)&gmid[g * DIM + lane * 4];
    float4 ww = *(const float4*)&w2[lane * 4];
    float s = x.x * ww.x + x.y * ww.y + x.z * ww.z + x.w * ww.w;
    #pragma unroll
    for (int off = 32; off; off >>= 1) s += __shfl_xor(s, off, 64);
    if (lane == 0) out[g] = s + b2[0];
}

extern "C" void kernel_launch(void* const* d_in, const int* in_sizes, int n_in,
                              void* d_out, int out_size, void* d_ws, size_t ws_size,
                              hipStream_t stream)
{
    const int*   z     = (const int*)d_in[0];
    const float* pos   = (const float*)d_in[1];
    const int*   batch = (const int*)d_in[2];
    const int*   ei    = (const int*)d_in[3];
    const float* emb   = (const float*)d_in[4];
    const float* ew1   = (const float*)d_in[5];
    const float* eb1   = (const float*)d_in[6];
    const float* ew2   = (const float*)d_in[7];
    const float* eb2   = (const float*)d_in[8];
    const float* nw1   = (const float*)d_in[9];
    const float* nb1   = (const float*)d_in[10];
    const float* nw2   = (const float*)d_in[11];
    const float* nb2   = (const float*)d_in[12];
    const float* aw    = (const float*)d_in[13];
    const float* ab    = (const float*)d_in[14];
    const float* wq    = (const float*)d_in[15];
    const float* bq    = (const float*)d_in[16];
    const float* wk    = (const float*)d_in[17];
    const float* bk    = (const float*)d_in[18];
    const float* wv    = (const float*)d_in[19];
    const float* bv    = (const float*)d_in[20];
    const float* wo    = (const float*)d_in[21];
    const float* bo    = (const float*)d_in[22];
    const float* ln1g  = (const float*)d_in[23];
    const float* ln1b  = (const float*)d_in[24];
    const float* fw1   = (const float*)d_in[25];
    const float* fb1   = (const float*)d_in[26];
    const float* fw2   = (const float*)d_in[27];
    const float* fb2   = (const float*)d_in[28];
    const float* ln2g  = (const float*)d_in[29];
    const float* ln2b  = (const float*)d_in[30];
    const float* fcw1  = (const float*)d_in[31];
    const float* fcb1  = (const float*)d_in[32];
    const float* fcw2  = (const float*)d_in[33];
    const float* fcb2  = (const float*)d_in[34];
    float* out = (float*)d_out;

    float* ws = (float*)d_ws;
    const size_t ND = (size_t)N_NODES * DIM;
    float* h    = ws;
    float* agg  = ws + ND;            // EGNN agg / WO out
    float* A    = ws + 2 * ND;        // node-mid / attn op2
    float* U    = ws + 3 * ND;        // P12 fp32 [N,512] (EGNN) / q fp32 (enc)
    float* op0  = ws + 4 * ND;
    float* op1  = ws + 5 * ND;
    float* Bffn = ws + 6 * ND;        // ffn-mid [N,512]; kpk/vpk alias
    unsigned short* kpk = (unsigned short*)Bffn;
    unsigned short* vpk = kpk + (size_t)NHEAD * N_NODES * 64;
    float* radial = Bffn + (3 * ND) / 2;
    int*   cnt    = (int*)(radial + N_EDGES);
    int*   pcur   = cnt + N_NODES;
    float* gbuf   = ws + 8 * ND;
    float* gmid   = gbuf + (size_t)NG * DIM;
    float* rad_s  = gmid + (size_t)NG * DIM;
    int*   rows_s = (int*)(rad_s + N_EDGES);
    int*   cols_s = rows_s + N_EDGES;
    unsigned short* W2F   = (unsigned short*)(cols_s + N_EDGES);
    unsigned short* packs = W2F + (size_t)NL * 65536;
    float* mlbuf = rad_s;
    float* op3buf = (float*)(packs + 2359296);

    unsigned short* PK_W1   = packs;
    unsigned short* PK_NW1  = packs + 524288;
    unsigned short* PK_NW2  = packs + 1048576;
    unsigned short* PK_QKV  = packs + 1310720;
    unsigned short* PK_WO   = packs + 1703936;
    unsigned short* PK_FFN1 = packs + 1835008;
    unsigned short* PK_FFN2 = packs + 2097152;

    dim3 b256(256);

    k_embed<<<N_NODES * DIM / 256, b256, 0, stream>>>(z, emb, h);
    k_radial<<<N_EDGES / 256, b256, 0, stream>>>(pos, ei, radial);
    k_conv_w2<<<NL * 8192 / 256, b256, 0, stream>>>(ew2, W2F);
    k_pack_all<<<1152, b256, 0, stream>>>(ew1, nw1, nw2, wq, wk, wv, wo, fw1, fw2, packs);

    hipMemsetAsync(cnt, 0, N_NODES * sizeof(int), stream);
    k_hist<<<N_EDGES / 256, b256, 0, stream>>>(ei, cnt);
    k_scan<<<1, b256, 0, stream>>>(cnt, pcur);
    k_scatter<<<N_EDGES / 256, b256, 0, stream>>>(ei, radial, pcur, rows_s, cols_s, rad_s);

    for (int l = 0; l < NL; ++l) {
        hipMemsetAsync(agg, 0, ND * sizeof(float), stream);
        const float* W1l = ew1 + (size_t)l * 513 * DIM;
        k_gemm<1,512,4,0,0,0,0><<<1024, b256, 0, stream>>>(h, nullptr, DIM,
            PK_W1 + (size_t)l * 131072, nullptr, nullptr, nullptr, nullptr, U,
            nullptr, nullptr, nullptr, nullptr, nullptr);
        k_edge_mfma<<<N_EDGES / TE2, b256, 0, stream>>>(U, rows_s, cols_s, rad_s,
            W1l + (size_t)512 * DIM, eb1 + (size_t)l * DIM,
            W2F + (size_t)l * 65536, eb2 + (size_t)l * DIM,
            aw + (size_t)l * DIM, ab + l, agg);
        const float* nb1l = nb1 + (size_t)l * DIM;
        k_gemm<2,256,4,1,0,0,0><<<1024, b256, 0, stream>>>(h, agg, DIM,
            PK_NW1 + (size_t)l * 131072, nb1l, nb1l, nb1l, nullptr, A,
            nullptr, nullptr, nullptr, nullptr, nullptr);
        const float* nb2l = nb2 + (size_t)l * DIM;
        k_gemm<1,256,4,0,1,0,0><<<1024, b256, 0, stream>>>(A, nullptr, DIM,
            PK_NW2 + (size_t)l * 65536, nb2l, nb2l, nb2l, h, h,
            nullptr, nullptr, nullptr, nullptr, nullptr);
    }

    for (int i = 0; i < NENC; ++i) {
        k_gemm<1,768,6,0,0,1,0><<<1536, b256, 0, stream>>>(h, nullptr, DIM,
            PK_QKV + (size_t)i * 196608,
            bq + (size_t)i * DIM, bk + (size_t)i * DIM, bv + (size_t)i * DIM, nullptr, U,
            kpk, vpk, nullptr, nullptr, nullptr);
        dim3 ag(N_NODES / 64, NHEAD, NSPLIT_ATT);
        k_attn_mfma<<<ag, b256, 0, stream>>>(U, kpk, vpk, op0, op1, A, op3buf, mlbuf);
        const float* bol = bo + (size_t)i * DIM;
        k_gemm<1,256,4,0,1,0,1><<<1024, b256, 0, stream>>>(op0, op1, 256,
            PK_WO + (size_t)i * 65536, bol, bol, bol, h, agg,
            nullptr, nullptr, A, op3buf, mlbuf);
        k_ln<<<N_NODES / 4, b256, 0, stream>>>(agg, ln1g + (size_t)i * DIM, ln1b + (size_t)i * DIM, h);
        const float* fb1l = fb1 + (size_t)i * FFD;
        k_gemm<1,512,4,1,0,0,0><<<1024, b256, 0, stream>>>(h, nullptr, DIM,
            PK_FFN1 + (size_t)i * 131072, fb1l, fb1l + 256, nullptr, nullptr, Bffn,
            nullptr, nullptr, nullptr, nullptr, nullptr);
        const float* fb2l = fb2 + (size_t)i * DIM;
        k_gemm<2,256,4,0,1,0,0><<<1024, b256, 0, stream>>>(Bffn, Bffn + 256, FFD,
            PK_FFN2 + (size_t)i * 131072, fb2l, fb2l, fb2l, h, agg,
            nullptr, nullptr, nullptr, nullptr, nullptr);
        k_ln<<<N_NODES / 4, b256, 0, stream>>>(agg, ln2g + (size_t)i * DIM, ln2b + (size_t)i * DIM, h);
    }

    hipMemsetAsync(gbuf, 0, (size_t)NG * DIM * sizeof(float), stream);
    k_segsum<<<N_NODES * DIM / 256, b256, 0, stream>>>(h, batch, gbuf);
    k_mlp_small<1><<<NG / 16, b256, 0, stream>>>(gbuf, fcw1, fcb1, gmid);
    k_head2<<<NG / 4, b256, 0, stream>>>(gmid, fcw2, fcb2, out);
}